// Round 1
// baseline (746.646 us; speedup 1.0000x reference)
//
#include <hip/hip_runtime.h>
#include <cfloat>

#define B 4
#define NC 2048
#define NF 8192
#define CIN 128
#define CH 64
#define COUT 128
#define EC 16384
#define EF 65536

// ---------------------------------------------------------------- knn: top-3 nearest coarse nodes per fine node
__global__ __launch_bounds__(256) void knn_kernel(const float* __restrict__ pos,
                                                  const int* __restrict__ mask,
                                                  int* __restrict__ idx,
                                                  float* __restrict__ wn) {
    __shared__ float sx[NC], sy[NC], sz[NC];
    const int b = blockIdx.y;
    const int tid = threadIdx.x;
    for (int i = tid; i < NC; i += 256) {
        int m = mask[b * NC + i];
        const float* p = pos + ((size_t)b * NF + m) * 3;
        sx[i] = p[0]; sy[i] = p[1]; sz[i] = p[2];
    }
    __syncthreads();
    const int f = blockIdx.x * 256 + tid;
    const float* pf = pos + ((size_t)b * NF + f) * 3;
    const float fx = pf[0], fy = pf[1], fz = pf[2];
    float d0 = FLT_MAX, d1 = FLT_MAX, d2 = FLT_MAX;
    int i0 = 0, i1 = 0, i2 = 0;
    for (int c = 0; c < NC; ++c) {
        // match numpy: diff, square, sequential sum — no FMA contraction
        float dx = __fsub_rn(fx, sx[c]);
        float dy = __fsub_rn(fy, sy[c]);
        float dz = __fsub_rn(fz, sz[c]);
        float d = __fadd_rn(__fadd_rn(__fmul_rn(dx, dx), __fmul_rn(dy, dy)), __fmul_rn(dz, dz));
        if (d < d2) {
            if (d < d1) {
                d2 = d1; i2 = i1;
                if (d < d0) { d1 = d0; i1 = i0; d0 = d; i0 = c; }
                else        { d1 = d;  i1 = c; }
            } else { d2 = d; i2 = c; }
        }
    }
    float w0 = 1.0f / (d0 + 1e-16f);
    float w1 = 1.0f / (d1 + 1e-16f);
    float w2 = 1.0f / (d2 + 1e-16f);
    float inv = 1.0f / (w0 + w1 + w2);
    size_t o = ((size_t)b * NF + f) * 3;
    idx[o] = i0; idx[o + 1] = i1; idx[o + 2] = i2;
    wn[o] = w0 * inv; wn[o + 1] = w1 * inv; wn[o + 2] = w2 * inv;
}

// ---------------------------------------------------------------- weighted 3-NN gather
__global__ void interp_kernel(const float* __restrict__ xc, const int* __restrict__ idx,
                              const float* __restrict__ wn, float* __restrict__ out, int C) {
    const int b = blockIdx.y, f = blockIdx.x, c = threadIdx.x;
    size_t o = ((size_t)b * NF + f) * 3;
    int i0 = idx[o], i1 = idx[o + 1], i2 = idx[o + 2];
    float w0 = wn[o], w1 = wn[o + 1], w2 = wn[o + 2];
    const float* xb = xc + (size_t)b * NC * C;
    out[((size_t)b * NF + f) * C + c] =
        w0 * xb[(size_t)i0 * C + c] + w1 * xb[(size_t)i1 * C + c] + w2 * xb[(size_t)i2 * C + c];
}

// ---------------------------------------------------------------- generic f32 GEMM: act(A1@W[0:K1] + A2@W[K1:K1+K2] + bias)
// flags bit0: leaky-relu; bit1: += existing output
__global__ __launch_bounds__(256) void gemm_kernel(
    const float* __restrict__ A1, int K1, const float* __restrict__ A2, int K2,
    const float* __restrict__ W, const float* __restrict__ bias,
    float* __restrict__ Cmat, int M, int N, int flags,
    long sA1, long sA2, long sC) {
    __shared__ float As[16][64];
    __shared__ float Wsh[16][64];
    const int b = blockIdx.z;
    const int m0 = blockIdx.y * 64, n0 = blockIdx.x * 64;
    const int t = threadIdx.x;
    const int tx = t & 15, ty = t >> 4;
    float acc[4][4] = {};
    int kOff = 0;
    for (int s = 0; s < 2; ++s) {
        const float* A = (s == 0) ? A1 : A2;
        const int K = (s == 0) ? K1 : K2;
        const long sA = (s == 0) ? sA1 : sA2;
        if (A == nullptr || K == 0) continue;
        const float* Ab = A + (size_t)b * sA;
        const int lm = t >> 2;            // 0..63 row of A tile
        const int lk = (t & 3) << 2;      // 0,4,8,12
        const int wk = t >> 4;            // 0..15 row of W tile
        const int wng = (t & 15) << 2;    // 0..60
        for (int k0 = 0; k0 < K; k0 += 16) {
            float4 av = *(const float4*)&Ab[(size_t)(m0 + lm) * K + k0 + lk];
            As[lk + 0][lm] = av.x; As[lk + 1][lm] = av.y;
            As[lk + 2][lm] = av.z; As[lk + 3][lm] = av.w;
            float4 wv = *(const float4*)&W[(size_t)(kOff + k0 + wk) * N + n0 + wng];
            *(float4*)&Wsh[wk][wng] = wv;
            __syncthreads();
            #pragma unroll
            for (int k = 0; k < 16; ++k) {
                float4 a4 = *(const float4*)&As[k][ty << 2];
                float4 w4 = *(const float4*)&Wsh[k][tx << 2];
                float aa[4] = {a4.x, a4.y, a4.z, a4.w};
                float ww[4] = {w4.x, w4.y, w4.z, w4.w};
                #pragma unroll
                for (int i = 0; i < 4; ++i)
                    #pragma unroll
                    for (int j = 0; j < 4; ++j)
                        acc[i][j] = fmaf(aa[i], ww[j], acc[i][j]);
            }
            __syncthreads();
        }
        kOff += K;
    }
    float* Cb = Cmat + (size_t)b * sC;
    #pragma unroll
    for (int i = 0; i < 4; ++i) {
        int m = m0 + (ty << 2) + i;
        #pragma unroll
        for (int j = 0; j < 4; ++j) {
            int n = n0 + (tx << 2) + j;
            float v = acc[i][j];
            if (bias) v += bias[n];
            if (flags & 1) v = v > 0.0f ? v : 0.01f * v;
            float* cp = &Cb[(size_t)m * N + n];
            if (flags & 2) v += *cp;
            *cp = v;
        }
    }
}

// ---------------------------------------------------------------- per-edge message + scatter-add
__global__ void edge_scatter(const float* __restrict__ P, const float* __restrict__ Q,
                             const float* __restrict__ bias, const int* __restrict__ ei,
                             float* __restrict__ agg, int E, int cshift,
                             long sPQ, long sEi) {
    const int b = blockIdx.y;
    long g = (long)blockIdx.x * blockDim.x + threadIdx.x;
    const int C = 1 << cshift;
    long e = g >> cshift;
    int c = (int)(g & (C - 1));
    if (e >= E) return;
    const int* eb = ei + (size_t)b * sEi;
    int src = eb[e], dst = eb[E + e];
    const float* Pb = P + (size_t)b * sPQ;
    const float* Qb = Q + (size_t)b * sPQ;
    float m = Pb[(size_t)src * C + c] + Qb[(size_t)dst * C + c] + bias[c];
    m = m > 0.0f ? m : 0.01f * m;
    atomicAdd(agg + (size_t)b * sPQ + (size_t)dst * C + c, m);
}

// ---------------------------------------------------------------- batch-norm stats (sum, sumsq per channel)
__global__ void bn_stats(const float* __restrict__ xs, float* __restrict__ stats) {
    const int c = threadIdx.x;            // 0..127
    long r0 = (long)blockIdx.x * 256;
    float s = 0.0f, s2 = 0.0f;
    for (int r = 0; r < 256; ++r) {
        float v = xs[(r0 + r) * COUT + c];
        s += v;
        s2 = fmaf(v, v, s2);
    }
    atomicAdd(&stats[c], s);
    atomicAdd(&stats[COUT + c], s2);
}

__global__ void bn_final(float* __restrict__ xs, const float* __restrict__ stats,
                         const float* __restrict__ gamma, const float* __restrict__ beta) {
    long g = (long)blockIdx.x * 256 + threadIdx.x;
    int c = (int)(g & (COUT - 1));
    const float invN = 1.0f / (float)(B * NF);
    float mu = stats[c] * invN;
    float var = stats[COUT + c] * invN - mu * mu;
    float v = (xs[g] - mu) * rsqrtf(var + 1e-5f) * gamma[c] + beta[c];
    xs[g] = v > 0.0f ? v : 0.01f * v;
}

// ---------------------------------------------------------------- w_fine unpool
__global__ void wfine_zero(float* __restrict__ wf) {
    long g = (long)blockIdx.x * 256 + threadIdx.x;
    wf[g] = 0.0f;
}
__global__ void wfine_scatter(const float* __restrict__ wts, const int* __restrict__ mask,
                              float* __restrict__ wf) {
    int i = blockIdx.x * 256 + threadIdx.x;   // 0..B*NC
    int b = i / NC;
    wf[(size_t)b * NF + mask[i]] = wts[i];
}

extern "C" void kernel_launch(void* const* d_in, const int* in_sizes, int n_in,
                              void* d_out, int out_size, void* d_ws, size_t ws_size,
                              hipStream_t stream) {
    const float* x    = (const float*)d_in[0];
    const float* wts  = (const float*)d_in[1];
    const float* pos  = (const float*)d_in[2];
    const float* W1e  = (const float*)d_in[3];
    const float* b1e  = (const float*)d_in[4];
    const float* W1n  = (const float*)d_in[5];
    const float* b1n  = (const float*)d_in[6];
    const float* W2e  = (const float*)d_in[7];
    const float* b2e  = (const float*)d_in[8];
    const float* W2n  = (const float*)d_in[9];
    const float* b2n  = (const float*)d_in[10];
    const float* Wse  = (const float*)d_in[11];
    const float* bse  = (const float*)d_in[12];
    const float* Wsn  = (const float*)d_in[13];
    const float* bsn  = (const float*)d_in[14];
    const float* gamma= (const float*)d_in[15];
    const float* beta = (const float*)d_in[16];
    const int*   mask = (const int*)d_in[17];
    const int*   ec   = (const int*)d_in[18];
    const int*   ef   = (const int*)d_in[19];

    float* ws   = (float*)d_ws;
    int*   idxb = (int*)ws;                              // B*NF*3 ints
    float* wnb  = ws + 98304;                            // B*NF*3
    float* xup  = ws + 196608;                           // B*NF*CIN
    float* Pb   = xup + (size_t)B * NF * CIN;            // B*NF*COUT (reused)
    float* Qb   = Pb  + (size_t)B * NF * COUT;           // B*NF*COUT (reused)
    float* agg  = Qb  + (size_t)B * NF * COUT;           // B*NF*COUT (reused)
    float* x1   = agg + (size_t)B * NF * COUT;           // B*NC*CH
    float* x1up = x1  + (size_t)B * NC * CH;             // B*NF*CH
    float* stats= x1up+ (size_t)B * NF * CH;             // 256

    float* y  = (float*)d_out;                           // B*NF*COUT
    float* wf = y + (size_t)B * NF * COUT;               // B*NF

    // ---- knn (shared by both interpolations)
    knn_kernel<<<dim3(NF / 256, B), 256, 0, stream>>>(pos, mask, idxb, wnb);
    // ---- x_up = interp(x)   (needed for skip branch)
    interp_kernel<<<dim3(NF, B), CIN, 0, stream>>>(x, idxb, wnb, xup, CIN);

    // ---- main branch: mpl1 on coarse graph
    gemm_kernel<<<dim3(CH / 64, NC / 64, B), 256, 0, stream>>>(
        x, CIN, nullptr, 0, W1e, nullptr, Pb, NC, CH, 0, (long)NC * CIN, 0, (long)NC * CH);
    gemm_kernel<<<dim3(CH / 64, NC / 64, B), 256, 0, stream>>>(
        x, CIN, nullptr, 0, W1e + CIN * CH, nullptr, Qb, NC, CH, 0, (long)NC * CIN, 0, (long)NC * CH);
    hipMemsetAsync(agg, 0, (size_t)B * NC * CH * 4, stream);
    edge_scatter<<<dim3(EC * CH / 256, B), 256, 0, stream>>>(
        Pb, Qb, b1e, ec, agg, EC, 6, (long)NC * CH, (long)2 * EC);
    gemm_kernel<<<dim3(CH / 64, NC / 64, B), 256, 0, stream>>>(
        x, CIN, agg, CH, W1n, b1n, x1, NC, CH, 1, (long)NC * CIN, (long)NC * CH, (long)NC * CH);
    // ---- x1_up = interp(x1)
    interp_kernel<<<dim3(NF, B), CH, 0, stream>>>(x1, idxb, wnb, x1up, CH);
    // ---- mpl2 on fine graph
    gemm_kernel<<<dim3(COUT / 64, NF / 64, B), 256, 0, stream>>>(
        x1up, CH, nullptr, 0, W2e, nullptr, Pb, NF, COUT, 0, (long)NF * CH, 0, (long)NF * COUT);
    gemm_kernel<<<dim3(COUT / 64, NF / 64, B), 256, 0, stream>>>(
        x1up, CH, nullptr, 0, W2e + CH * COUT, nullptr, Qb, NF, COUT, 0, (long)NF * CH, 0, (long)NF * COUT);
    hipMemsetAsync(agg, 0, (size_t)B * NF * COUT * 4, stream);
    edge_scatter<<<dim3(EF * COUT / 256, B), 256, 0, stream>>>(
        Pb, Qb, b2e, ef, agg, EF, 7, (long)NF * COUT, (long)2 * EF);
    gemm_kernel<<<dim3(COUT / 64, NF / 64, B), 256, 0, stream>>>(
        x1up, CH, agg, COUT, W2n, b2n, y, NF, COUT, 1, (long)NF * CH, (long)NF * COUT, (long)NF * COUT);

    // ---- skip branch: mpl on fine graph from x_up, accumulated into y
    gemm_kernel<<<dim3(COUT / 64, NF / 64, B), 256, 0, stream>>>(
        xup, CIN, nullptr, 0, Wse, nullptr, Pb, NF, COUT, 0, (long)NF * CIN, 0, (long)NF * COUT);
    gemm_kernel<<<dim3(COUT / 64, NF / 64, B), 256, 0, stream>>>(
        xup, CIN, nullptr, 0, Wse + CIN * COUT, nullptr, Qb, NF, COUT, 0, (long)NF * CIN, 0, (long)NF * COUT);
    hipMemsetAsync(agg, 0, (size_t)B * NF * COUT * 4, stream);
    edge_scatter<<<dim3(EF * COUT / 256, B), 256, 0, stream>>>(
        Pb, Qb, bse, ef, agg, EF, 7, (long)NF * COUT, (long)2 * EF);
    gemm_kernel<<<dim3(COUT / 64, NF / 64, B), 256, 0, stream>>>(
        xup, CIN, agg, COUT, Wsn, bsn, y, NF, COUT, 3, (long)NF * CIN, (long)NF * COUT, (long)NF * COUT);

    // ---- batch norm + lrelu over all B*NF rows
    hipMemsetAsync(stats, 0, 256 * 4, stream);
    bn_stats<<<dim3((B * NF) / 256), COUT, 0, stream>>>(y, stats);
    bn_final<<<dim3((long)B * NF * COUT / 256), 256, 0, stream>>>(y, stats, gamma, beta);

    // ---- w_fine unpool
    wfine_zero<<<dim3(B * NF / 256), 256, 0, stream>>>(wf);
    wfine_scatter<<<dim3(B * NC / 256), 256, 0, stream>>>(wts, mask, wf);
}

// Round 2
// 522.878 us; speedup vs baseline: 1.4280x; 1.4280x over previous
//
#include <hip/hip_runtime.h>
#include <cfloat>

#define B 4
#define NC 2048
#define NF 8192
#define CIN 128
#define CH 64
#define COUT 128
#define EC 16384
#define EF 65536

// ---------------------------------------------------------------- knn: top-3 nearest coarse nodes per fine node
// 8 lanes per fine node scan strided candidates; shfl_xor butterfly merge.
__global__ __launch_bounds__(256) void knn_kernel(const float* __restrict__ pos,
                                                  const int* __restrict__ mask,
                                                  int* __restrict__ idx,
                                                  float* __restrict__ wn) {
    __shared__ float4 sp[NC];
    const int b = blockIdx.y;
    const int tid = threadIdx.x;
    for (int i = tid; i < NC; i += 256) {
        int m = mask[b * NC + i];
        const float* p = pos + ((size_t)b * NF + m) * 3;
        sp[i] = make_float4(p[0], p[1], p[2], 0.0f);
    }
    __syncthreads();
    const int f = blockIdx.x * 32 + (tid >> 3);
    const int lane = tid & 7;
    const float* pf = pos + ((size_t)b * NF + f) * 3;
    const float fx = pf[0], fy = pf[1], fz = pf[2];
    float d0 = FLT_MAX, d1 = FLT_MAX, d2 = FLT_MAX;
    int i0 = 0, i1 = 0, i2 = 0;
    #pragma unroll 4
    for (int c = lane; c < NC; c += 8) {
        float4 s = sp[c];
        // match numpy: diff, square, sequential sum — no FMA contraction
        float dx = __fsub_rn(fx, s.x);
        float dy = __fsub_rn(fy, s.y);
        float dz = __fsub_rn(fz, s.z);
        float d = __fadd_rn(__fadd_rn(__fmul_rn(dx, dx), __fmul_rn(dy, dy)), __fmul_rn(dz, dz));
        if (d < d2) {
            if (d < d1) {
                d2 = d1; i2 = i1;
                if (d < d0) { d1 = d0; i1 = i0; d0 = d; i0 = c; }
                else        { d1 = d;  i1 = c; }
            } else { d2 = d; i2 = c; }
        }
    }
    // butterfly merge across the 8 lanes of this fine node
    #pragma unroll
    for (int off = 1; off <= 4; off <<= 1) {
        float od[3]; int oi[3];
        od[0] = __shfl_xor(d0, off); oi[0] = __shfl_xor(i0, off);
        od[1] = __shfl_xor(d1, off); oi[1] = __shfl_xor(i1, off);
        od[2] = __shfl_xor(d2, off); oi[2] = __shfl_xor(i2, off);
        #pragma unroll
        for (int j = 0; j < 3; ++j) {
            float d = od[j]; int c = oi[j];
            if (d < d2) {
                if (d < d1) {
                    d2 = d1; i2 = i1;
                    if (d < d0) { d1 = d0; i1 = i0; d0 = d; i0 = c; }
                    else        { d1 = d;  i1 = c; }
                } else { d2 = d; i2 = c; }
            }
        }
    }
    if (lane == 0) {
        float w0 = 1.0f / (d0 + 1e-16f);
        float w1 = 1.0f / (d1 + 1e-16f);
        float w2 = 1.0f / (d2 + 1e-16f);
        float inv = 1.0f / (w0 + w1 + w2);
        size_t o = ((size_t)b * NF + f) * 3;
        idx[o] = i0; idx[o + 1] = i1; idx[o + 2] = i2;
        wn[o] = w0 * inv; wn[o + 1] = w1 * inv; wn[o + 2] = w2 * inv;
    }
}

// ---------------------------------------------------------------- weighted 3-NN gather
__global__ void interp_kernel(const float* __restrict__ xc, const int* __restrict__ idx,
                              const float* __restrict__ wn, float* __restrict__ out, int C) {
    const int b = blockIdx.y, f = blockIdx.x, c = threadIdx.x;
    size_t o = ((size_t)b * NF + f) * 3;
    int i0 = idx[o], i1 = idx[o + 1], i2 = idx[o + 2];
    float w0 = wn[o], w1 = wn[o + 1], w2 = wn[o + 2];
    const float* xb = xc + (size_t)b * NC * C;
    out[((size_t)b * NF + f) * C + c] =
        w0 * xb[(size_t)i0 * C + c] + w1 * xb[(size_t)i1 * C + c] + w2 * xb[(size_t)i2 * C + c];
}

// ---------------------------------------------------------------- generic f32 GEMM: act(A1@W[0:K1] + A2@W[K1:K1+K2] + bias)
// flags bit0: leaky-relu; bit1: += existing output
__global__ __launch_bounds__(256) void gemm_kernel(
    const float* __restrict__ A1, int K1, const float* __restrict__ A2, int K2,
    const float* __restrict__ W, const float* __restrict__ bias,
    float* __restrict__ Cmat, int M, int N, int flags,
    long sA1, long sA2, long sC) {
    __shared__ float As[16][64];
    __shared__ float Wsh[16][64];
    const int b = blockIdx.z;
    const int m0 = blockIdx.y * 64, n0 = blockIdx.x * 64;
    const int t = threadIdx.x;
    const int tx = t & 15, ty = t >> 4;
    float acc[4][4] = {};
    int kOff = 0;
    for (int s = 0; s < 2; ++s) {
        const float* A = (s == 0) ? A1 : A2;
        const int K = (s == 0) ? K1 : K2;
        const long sA = (s == 0) ? sA1 : sA2;
        if (A == nullptr || K == 0) continue;
        const float* Ab = A + (size_t)b * sA;
        const int lm = t >> 2;            // 0..63 row of A tile
        const int lk = (t & 3) << 2;      // 0,4,8,12
        const int wk = t >> 4;            // 0..15 row of W tile
        const int wng = (t & 15) << 2;    // 0..60
        for (int k0 = 0; k0 < K; k0 += 16) {
            float4 av = *(const float4*)&Ab[(size_t)(m0 + lm) * K + k0 + lk];
            As[lk + 0][lm] = av.x; As[lk + 1][lm] = av.y;
            As[lk + 2][lm] = av.z; As[lk + 3][lm] = av.w;
            float4 wv = *(const float4*)&W[(size_t)(kOff + k0 + wk) * N + n0 + wng];
            *(float4*)&Wsh[wk][wng] = wv;
            __syncthreads();
            #pragma unroll
            for (int k = 0; k < 16; ++k) {
                float4 a4 = *(const float4*)&As[k][ty << 2];
                float4 w4 = *(const float4*)&Wsh[k][tx << 2];
                float aa[4] = {a4.x, a4.y, a4.z, a4.w};
                float ww[4] = {w4.x, w4.y, w4.z, w4.w};
                #pragma unroll
                for (int i = 0; i < 4; ++i)
                    #pragma unroll
                    for (int j = 0; j < 4; ++j)
                        acc[i][j] = fmaf(aa[i], ww[j], acc[i][j]);
            }
            __syncthreads();
        }
        kOff += K;
    }
    float* Cb = Cmat + (size_t)b * sC;
    #pragma unroll
    for (int i = 0; i < 4; ++i) {
        int m = m0 + (ty << 2) + i;
        #pragma unroll
        for (int j = 0; j < 4; ++j) {
            int n = n0 + (tx << 2) + j;
            float v = acc[i][j];
            if (bias) v += bias[n];
            if (flags & 1) v = v > 0.0f ? v : 0.01f * v;
            float* cp = &Cb[(size_t)m * N + n];
            if (flags & 2) v += *cp;
            *cp = v;
        }
    }
}

// ---------------------------------------------------------------- per-edge message + scatter-add
__global__ void edge_scatter(const float* __restrict__ P, const float* __restrict__ Q,
                             const float* __restrict__ bias, const int* __restrict__ ei,
                             float* __restrict__ agg, int E, int cshift,
                             long sPQ, long sEi) {
    const int b = blockIdx.y;
    long g = (long)blockIdx.x * blockDim.x + threadIdx.x;
    const int C = 1 << cshift;
    long e = g >> cshift;
    int c = (int)(g & (C - 1));
    if (e >= E) return;
    const int* eb = ei + (size_t)b * sEi;
    int src = eb[e], dst = eb[E + e];
    const float* Pb = P + (size_t)b * sPQ;
    const float* Qb = Q + (size_t)b * sPQ;
    float m = Pb[(size_t)src * C + c] + Qb[(size_t)dst * C + c] + bias[c];
    m = m > 0.0f ? m : 0.01f * m;
    atomicAdd(agg + (size_t)b * sPQ + (size_t)dst * C + c, m);
}

// ---------------------------------------------------------------- batch-norm stats (sum, sumsq per channel)
__global__ void bn_stats(const float* __restrict__ xs, float* __restrict__ stats) {
    const int c = threadIdx.x;            // 0..127
    long r0 = (long)blockIdx.x * 256;
    float s = 0.0f, s2 = 0.0f;
    for (int r = 0; r < 256; ++r) {
        float v = xs[(r0 + r) * COUT + c];
        s += v;
        s2 = fmaf(v, v, s2);
    }
    atomicAdd(&stats[c], s);
    atomicAdd(&stats[COUT + c], s2);
}

__global__ void bn_final(float* __restrict__ xs, const float* __restrict__ stats,
                         const float* __restrict__ gamma, const float* __restrict__ beta) {
    long g = (long)blockIdx.x * 256 + threadIdx.x;
    int c = (int)(g & (COUT - 1));
    const float invN = 1.0f / (float)(B * NF);
    float mu = stats[c] * invN;
    float var = stats[COUT + c] * invN - mu * mu;
    float v = (xs[g] - mu) * rsqrtf(var + 1e-5f) * gamma[c] + beta[c];
    xs[g] = v > 0.0f ? v : 0.01f * v;
}

// ---------------------------------------------------------------- w_fine unpool
__global__ void wfine_zero(float* __restrict__ wf) {
    long g = (long)blockIdx.x * 256 + threadIdx.x;
    wf[g] = 0.0f;
}
__global__ void wfine_scatter(const float* __restrict__ wts, const int* __restrict__ mask,
                              float* __restrict__ wf) {
    int i = blockIdx.x * 256 + threadIdx.x;   // 0..B*NC
    int b = i / NC;
    wf[(size_t)b * NF + mask[i]] = wts[i];
}

extern "C" void kernel_launch(void* const* d_in, const int* in_sizes, int n_in,
                              void* d_out, int out_size, void* d_ws, size_t ws_size,
                              hipStream_t stream) {
    const float* x    = (const float*)d_in[0];
    const float* wts  = (const float*)d_in[1];
    const float* pos  = (const float*)d_in[2];
    const float* W1e  = (const float*)d_in[3];
    const float* b1e  = (const float*)d_in[4];
    const float* W1n  = (const float*)d_in[5];
    const float* b1n  = (const float*)d_in[6];
    const float* W2e  = (const float*)d_in[7];
    const float* b2e  = (const float*)d_in[8];
    const float* W2n  = (const float*)d_in[9];
    const float* b2n  = (const float*)d_in[10];
    const float* Wse  = (const float*)d_in[11];
    const float* bse  = (const float*)d_in[12];
    const float* Wsn  = (const float*)d_in[13];
    const float* bsn  = (const float*)d_in[14];
    const float* gamma= (const float*)d_in[15];
    const float* beta = (const float*)d_in[16];
    const int*   mask = (const int*)d_in[17];
    const int*   ec   = (const int*)d_in[18];
    const int*   ef   = (const int*)d_in[19];

    float* ws   = (float*)d_ws;
    int*   idxb = (int*)ws;                              // B*NF*3 ints
    float* wnb  = ws + 98304;                            // B*NF*3
    float* xup  = ws + 196608;                           // B*NF*CIN
    float* Pb   = xup + (size_t)B * NF * CIN;            // B*NF*COUT (reused)
    float* Qb   = Pb  + (size_t)B * NF * COUT;           // B*NF*COUT (reused)
    float* agg  = Qb  + (size_t)B * NF * COUT;           // B*NF*COUT (reused)
    float* x1   = agg + (size_t)B * NF * COUT;           // B*NC*CH
    float* x1up = x1  + (size_t)B * NC * CH;             // B*NF*CH
    float* stats= x1up+ (size_t)B * NF * CH;             // 256

    float* y  = (float*)d_out;                           // B*NF*COUT
    float* wf = y + (size_t)B * NF * COUT;               // B*NF

    // ---- knn (shared by both interpolations)
    knn_kernel<<<dim3(NF / 32, B), 256, 0, stream>>>(pos, mask, idxb, wnb);
    // ---- x_up = interp(x)   (needed for skip branch)
    interp_kernel<<<dim3(NF, B), CIN, 0, stream>>>(x, idxb, wnb, xup, CIN);

    // ---- main branch: mpl1 on coarse graph
    gemm_kernel<<<dim3(CH / 64, NC / 64, B), 256, 0, stream>>>(
        x, CIN, nullptr, 0, W1e, nullptr, Pb, NC, CH, 0, (long)NC * CIN, 0, (long)NC * CH);
    gemm_kernel<<<dim3(CH / 64, NC / 64, B), 256, 0, stream>>>(
        x, CIN, nullptr, 0, W1e + CIN * CH, nullptr, Qb, NC, CH, 0, (long)NC * CIN, 0, (long)NC * CH);
    hipMemsetAsync(agg, 0, (size_t)B * NC * CH * 4, stream);
    edge_scatter<<<dim3(EC * CH / 256, B), 256, 0, stream>>>(
        Pb, Qb, b1e, ec, agg, EC, 6, (long)NC * CH, (long)2 * EC);
    gemm_kernel<<<dim3(CH / 64, NC / 64, B), 256, 0, stream>>>(
        x, CIN, agg, CH, W1n, b1n, x1, NC, CH, 1, (long)NC * CIN, (long)NC * CH, (long)NC * CH);
    // ---- x1_up = interp(x1)
    interp_kernel<<<dim3(NF, B), CH, 0, stream>>>(x1, idxb, wnb, x1up, CH);
    // ---- mpl2 on fine graph
    gemm_kernel<<<dim3(COUT / 64, NF / 64, B), 256, 0, stream>>>(
        x1up, CH, nullptr, 0, W2e, nullptr, Pb, NF, COUT, 0, (long)NF * CH, 0, (long)NF * COUT);
    gemm_kernel<<<dim3(COUT / 64, NF / 64, B), 256, 0, stream>>>(
        x1up, CH, nullptr, 0, W2e + CH * COUT, nullptr, Qb, NF, COUT, 0, (long)NF * CH, 0, (long)NF * COUT);
    hipMemsetAsync(agg, 0, (size_t)B * NF * COUT * 4, stream);
    edge_scatter<<<dim3(EF * COUT / 256, B), 256, 0, stream>>>(
        Pb, Qb, b2e, ef, agg, EF, 7, (long)NF * COUT, (long)2 * EF);
    gemm_kernel<<<dim3(COUT / 64, NF / 64, B), 256, 0, stream>>>(
        x1up, CH, agg, COUT, W2n, b2n, y, NF, COUT, 1, (long)NF * CH, (long)NF * COUT, (long)NF * COUT);

    // ---- skip branch: mpl on fine graph from x_up, accumulated into y
    gemm_kernel<<<dim3(COUT / 64, NF / 64, B), 256, 0, stream>>>(
        xup, CIN, nullptr, 0, Wse, nullptr, Pb, NF, COUT, 0, (long)NF * CIN, 0, (long)NF * COUT);
    gemm_kernel<<<dim3(COUT / 64, NF / 64, B), 256, 0, stream>>>(
        xup, CIN, nullptr, 0, Wse + CIN * COUT, nullptr, Qb, NF, COUT, 0, (long)NF * CIN, 0, (long)NF * COUT);
    hipMemsetAsync(agg, 0, (size_t)B * NF * COUT * 4, stream);
    edge_scatter<<<dim3(EF * COUT / 256, B), 256, 0, stream>>>(
        Pb, Qb, bse, ef, agg, EF, 7, (long)NF * COUT, (long)2 * EF);
    gemm_kernel<<<dim3(COUT / 64, NF / 64, B), 256, 0, stream>>>(
        xup, CIN, agg, COUT, Wsn, bsn, y, NF, COUT, 3, (long)NF * CIN, (long)NF * COUT, (long)NF * COUT);

    // ---- batch norm + lrelu over all B*NF rows
    hipMemsetAsync(stats, 0, 256 * 4, stream);
    bn_stats<<<dim3((B * NF) / 256), COUT, 0, stream>>>(y, stats);
    bn_final<<<dim3((long)B * NF * COUT / 256), 256, 0, stream>>>(y, stats, gamma, beta);

    // ---- w_fine unpool
    wfine_zero<<<dim3(B * NF / 256), 256, 0, stream>>>(wf);
    wfine_scatter<<<dim3(B * NC / 256), 256, 0, stream>>>(wts, mask, wf);
}

// Round 3
// 402.399 us; speedup vs baseline: 1.8555x; 1.2994x over previous
//
#include <hip/hip_runtime.h>
#include <cfloat>

#define B 4
#define NC 2048
#define NF 8192
#define CIN 128
#define CH 64
#define COUT 128
#define EC 16384
#define EF 65536

// ---------------------------------------------------------------- knn: top-3 nearest coarse nodes per fine node
// 8 lanes per fine node scan strided candidates; shfl_xor butterfly merge.
__global__ __launch_bounds__(256) void knn_kernel(const float* __restrict__ pos,
                                                  const int* __restrict__ mask,
                                                  int* __restrict__ idx,
                                                  float* __restrict__ wn) {
    __shared__ float4 sp[NC];
    const int b = blockIdx.y;
    const int tid = threadIdx.x;
    for (int i = tid; i < NC; i += 256) {
        int m = mask[b * NC + i];
        const float* p = pos + ((size_t)b * NF + m) * 3;
        sp[i] = make_float4(p[0], p[1], p[2], 0.0f);
    }
    __syncthreads();
    const int f = blockIdx.x * 32 + (tid >> 3);
    const int lane = tid & 7;
    const float* pf = pos + ((size_t)b * NF + f) * 3;
    const float fx = pf[0], fy = pf[1], fz = pf[2];
    float d0 = FLT_MAX, d1 = FLT_MAX, d2 = FLT_MAX;
    int i0 = 0, i1 = 0, i2 = 0;
    #pragma unroll 4
    for (int c = lane; c < NC; c += 8) {
        float4 s = sp[c];
        float dx = __fsub_rn(fx, s.x);
        float dy = __fsub_rn(fy, s.y);
        float dz = __fsub_rn(fz, s.z);
        float d = __fadd_rn(__fadd_rn(__fmul_rn(dx, dx), __fmul_rn(dy, dy)), __fmul_rn(dz, dz));
        if (d < d2) {
            if (d < d1) {
                d2 = d1; i2 = i1;
                if (d < d0) { d1 = d0; i1 = i0; d0 = d; i0 = c; }
                else        { d1 = d;  i1 = c; }
            } else { d2 = d; i2 = c; }
        }
    }
    #pragma unroll
    for (int off = 1; off <= 4; off <<= 1) {
        float od[3]; int oi[3];
        od[0] = __shfl_xor(d0, off); oi[0] = __shfl_xor(i0, off);
        od[1] = __shfl_xor(d1, off); oi[1] = __shfl_xor(i1, off);
        od[2] = __shfl_xor(d2, off); oi[2] = __shfl_xor(i2, off);
        #pragma unroll
        for (int j = 0; j < 3; ++j) {
            float d = od[j]; int c = oi[j];
            if (d < d2) {
                if (d < d1) {
                    d2 = d1; i2 = i1;
                    if (d < d0) { d1 = d0; i1 = i0; d0 = d; i0 = c; }
                    else        { d1 = d;  i1 = c; }
                } else { d2 = d; i2 = c; }
            }
        }
    }
    if (lane == 0) {
        float w0 = 1.0f / (d0 + 1e-16f);
        float w1 = 1.0f / (d1 + 1e-16f);
        float w2 = 1.0f / (d2 + 1e-16f);
        float inv = 1.0f / (w0 + w1 + w2);
        size_t o = ((size_t)b * NF + f) * 3;
        idx[o] = i0; idx[o + 1] = i1; idx[o + 2] = i2;
        wn[o] = w0 * inv; wn[o + 1] = w1 * inv; wn[o + 2] = w2 * inv;
    }
}

// ---------------------------------------------------------------- weighted 3-NN gather
__global__ void interp_kernel(const float* __restrict__ xc, const int* __restrict__ idx,
                              const float* __restrict__ wn, float* __restrict__ out, int C) {
    const int b = blockIdx.y, f = blockIdx.x, c = threadIdx.x;
    size_t o = ((size_t)b * NF + f) * 3;
    int i0 = idx[o], i1 = idx[o + 1], i2 = idx[o + 2];
    float w0 = wn[o], w1 = wn[o + 1], w2 = wn[o + 2];
    const float* xb = xc + (size_t)b * NC * C;
    out[((size_t)b * NF + f) * C + c] =
        w0 * xb[(size_t)i0 * C + c] + w1 * xb[(size_t)i1 * C + c] + w2 * xb[(size_t)i2 * C + c];
}

// ---------------------------------------------------------------- generic f32 GEMM: act(A1@W[0:K1] + A2@W[K1:K1+K2] + bias)
// flags bit0: leaky-relu; bit1: += existing output
__global__ __launch_bounds__(256) void gemm_kernel(
    const float* __restrict__ A1, int K1, const float* __restrict__ A2, int K2,
    const float* __restrict__ W, const float* __restrict__ bias,
    float* __restrict__ Cmat, int M, int N, int flags,
    long sA1, long sA2, long sC) {
    __shared__ float As[16][64];
    __shared__ float Wsh[16][64];
    const int b = blockIdx.z;
    const int m0 = blockIdx.y * 64, n0 = blockIdx.x * 64;
    const int t = threadIdx.x;
    const int tx = t & 15, ty = t >> 4;
    float acc[4][4] = {};
    int kOff = 0;
    for (int s = 0; s < 2; ++s) {
        const float* A = (s == 0) ? A1 : A2;
        const int K = (s == 0) ? K1 : K2;
        const long sA = (s == 0) ? sA1 : sA2;
        if (A == nullptr || K == 0) continue;
        const float* Ab = A + (size_t)b * sA;
        const int lm = t >> 2;
        const int lk = (t & 3) << 2;
        const int wk = t >> 4;
        const int wng = (t & 15) << 2;
        for (int k0 = 0; k0 < K; k0 += 16) {
            float4 av = *(const float4*)&Ab[(size_t)(m0 + lm) * K + k0 + lk];
            As[lk + 0][lm] = av.x; As[lk + 1][lm] = av.y;
            As[lk + 2][lm] = av.z; As[lk + 3][lm] = av.w;
            float4 wv = *(const float4*)&W[(size_t)(kOff + k0 + wk) * N + n0 + wng];
            *(float4*)&Wsh[wk][wng] = wv;
            __syncthreads();
            #pragma unroll
            for (int k = 0; k < 16; ++k) {
                float4 a4 = *(const float4*)&As[k][ty << 2];
                float4 w4 = *(const float4*)&Wsh[k][tx << 2];
                float aa[4] = {a4.x, a4.y, a4.z, a4.w};
                float ww[4] = {w4.x, w4.y, w4.z, w4.w};
                #pragma unroll
                for (int i = 0; i < 4; ++i)
                    #pragma unroll
                    for (int j = 0; j < 4; ++j)
                        acc[i][j] = fmaf(aa[i], ww[j], acc[i][j]);
            }
            __syncthreads();
        }
        kOff += K;
    }
    float* Cb = Cmat + (size_t)b * sC;
    #pragma unroll
    for (int i = 0; i < 4; ++i) {
        int m = m0 + (ty << 2) + i;
        #pragma unroll
        for (int j = 0; j < 4; ++j) {
            int n = n0 + (tx << 2) + j;
            float v = acc[i][j];
            if (bias) v += bias[n];
            if (flags & 1) v = v > 0.0f ? v : 0.01f * v;
            float* cp = &Cb[(size_t)m * N + n];
            if (flags & 2) v += *cp;
            *cp = v;
        }
    }
}

// ---------------------------------------------------------------- CSR build: histogram of dst
__global__ void hist_kernel(const int* __restrict__ ei, int* __restrict__ counts,
                            int E, int N, long sEi) {
    const int b = blockIdx.y;
    int e = blockIdx.x * 256 + threadIdx.x;
    if (e >= E) return;
    int dst = ei[(size_t)b * sEi + E + e];
    atomicAdd(&counts[b * N + dst], 1);
}

// ---------------------------------------------------------------- CSR build: per-graph exclusive scan (1024 threads/block)
__global__ __launch_bounds__(1024) void scan_kernel(const int* __restrict__ counts,
                                                    int* __restrict__ offs,
                                                    int* __restrict__ cursor, int N) {
    __shared__ int part[1024];
    const int b = blockIdx.x;
    const int tid = threadIdx.x;
    const int per = N >> 10;                // N/1024 (2 or 8)
    int local[8];
    int s = 0;
    #pragma unroll
    for (int i = 0; i < 8; ++i) {
        if (i < per) { local[i] = s; s += counts[b * N + tid * per + i]; }
    }
    part[tid] = s;
    __syncthreads();
    for (int off = 1; off < 1024; off <<= 1) {
        int v = (tid >= off) ? part[tid - off] : 0;
        __syncthreads();
        part[tid] += v;
        __syncthreads();
    }
    int pre = (tid == 0) ? 0 : part[tid - 1];
    #pragma unroll
    for (int i = 0; i < 8; ++i) {
        if (i < per) {
            int o = pre + local[i];
            offs[b * N + tid * per + i] = o;
            cursor[b * N + tid * per + i] = o;
        }
    }
}

// ---------------------------------------------------------------- CSR build: scatter src ids into dst buckets
__global__ void fill_csr(const int* __restrict__ ei, int* __restrict__ cursor,
                         int* __restrict__ csr_src, int E, int N, long sEi) {
    const int b = blockIdx.y;
    int e = blockIdx.x * 256 + threadIdx.x;
    if (e >= E) return;
    const int* eb = ei + (size_t)b * sEi;
    int src = eb[e], dst = eb[E + e];
    int pos = atomicAdd(&cursor[b * N + dst], 1);
    csr_src[(size_t)b * E + pos] = src;
}

// ---------------------------------------------------------------- edge message + aggregate, one wave per dst node
__global__ __launch_bounds__(256) void agg_csr(const float* __restrict__ P,
                                               const float* __restrict__ Q,
                                               const float* __restrict__ bias,
                                               const int* __restrict__ offs,
                                               const int* __restrict__ counts,
                                               const int* __restrict__ csr_src,
                                               float* __restrict__ agg,
                                               int N, int E, int C, long sPQ) {
    const int b = blockIdx.y;
    const int dst = blockIdx.x * 4 + (threadIdx.x >> 6);
    const int lane = threadIdx.x & 63;
    if (dst >= N) return;
    const float* Pb = P + (size_t)b * sPQ;
    const float* Qb = Q + (size_t)b * sPQ;
    const int start = offs[b * N + dst];
    const int cnt = counts[b * N + dst];
    const int* sl = csr_src + (size_t)b * E + start;
    if (C == 128) {
        const int c0 = lane, c1 = lane + 64;
        const float q0 = Qb[(size_t)dst * 128 + c0] + bias[c0];
        const float q1 = Qb[(size_t)dst * 128 + c1] + bias[c1];
        float a0 = 0.0f, a1 = 0.0f;
        for (int i = 0; i < cnt; ++i) {
            int src = sl[i];
            float m0 = Pb[(size_t)src * 128 + c0] + q0; m0 = m0 > 0.0f ? m0 : 0.01f * m0;
            float m1 = Pb[(size_t)src * 128 + c1] + q1; m1 = m1 > 0.0f ? m1 : 0.01f * m1;
            a0 += m0; a1 += m1;
        }
        agg[(size_t)b * sPQ + (size_t)dst * 128 + c0] = a0;
        agg[(size_t)b * sPQ + (size_t)dst * 128 + c1] = a1;
    } else {  // C == 64
        const float q = Qb[(size_t)dst * 64 + lane] + bias[lane];
        float a = 0.0f;
        for (int i = 0; i < cnt; ++i) {
            int src = sl[i];
            float m = Pb[(size_t)src * 64 + lane] + q; m = m > 0.0f ? m : 0.01f * m;
            a += m;
        }
        agg[(size_t)b * sPQ + (size_t)dst * 64 + lane] = a;
    }
}

// ---------------------------------------------------------------- batch-norm stats (sum, sumsq per channel)
__global__ void bn_stats(const float* __restrict__ xs, float* __restrict__ stats) {
    const int c = threadIdx.x;
    long r0 = (long)blockIdx.x * 256;
    float s = 0.0f, s2 = 0.0f;
    for (int r = 0; r < 256; ++r) {
        float v = xs[(r0 + r) * COUT + c];
        s += v;
        s2 = fmaf(v, v, s2);
    }
    atomicAdd(&stats[c], s);
    atomicAdd(&stats[COUT + c], s2);
}

__global__ void bn_final(float* __restrict__ xs, const float* __restrict__ stats,
                         const float* __restrict__ gamma, const float* __restrict__ beta) {
    long g = (long)blockIdx.x * 256 + threadIdx.x;
    int c = (int)(g & (COUT - 1));
    const float invN = 1.0f / (float)(B * NF);
    float mu = stats[c] * invN;
    float var = stats[COUT + c] * invN - mu * mu;
    float v = (xs[g] - mu) * rsqrtf(var + 1e-5f) * gamma[c] + beta[c];
    xs[g] = v > 0.0f ? v : 0.01f * v;
}

// ---------------------------------------------------------------- w_fine unpool
__global__ void wfine_zero(float* __restrict__ wf) {
    long g = (long)blockIdx.x * 256 + threadIdx.x;
    wf[g] = 0.0f;
}
__global__ void wfine_scatter(const float* __restrict__ wts, const int* __restrict__ mask,
                              float* __restrict__ wf) {
    int i = blockIdx.x * 256 + threadIdx.x;
    int b = i / NC;
    wf[(size_t)b * NF + mask[i]] = wts[i];
}

extern "C" void kernel_launch(void* const* d_in, const int* in_sizes, int n_in,
                              void* d_out, int out_size, void* d_ws, size_t ws_size,
                              hipStream_t stream) {
    const float* x    = (const float*)d_in[0];
    const float* wts  = (const float*)d_in[1];
    const float* pos  = (const float*)d_in[2];
    const float* W1e  = (const float*)d_in[3];
    const float* b1e  = (const float*)d_in[4];
    const float* W1n  = (const float*)d_in[5];
    const float* b1n  = (const float*)d_in[6];
    const float* W2e  = (const float*)d_in[7];
    const float* b2e  = (const float*)d_in[8];
    const float* W2n  = (const float*)d_in[9];
    const float* b2n  = (const float*)d_in[10];
    const float* Wse  = (const float*)d_in[11];
    const float* bse  = (const float*)d_in[12];
    const float* Wsn  = (const float*)d_in[13];
    const float* bsn  = (const float*)d_in[14];
    const float* gamma= (const float*)d_in[15];
    const float* beta = (const float*)d_in[16];
    const int*   mask = (const int*)d_in[17];
    const int*   ec   = (const int*)d_in[18];
    const int*   ef   = (const int*)d_in[19];

    float* ws   = (float*)d_ws;
    int*   idxb = (int*)ws;                              // B*NF*3 ints
    float* wnb  = ws + 98304;                            // B*NF*3
    float* xup  = ws + 196608;                           // B*NF*CIN
    float* Pb   = xup + (size_t)B * NF * CIN;            // B*NF*COUT (reused)
    float* Qb   = Pb  + (size_t)B * NF * COUT;           // B*NF*COUT (reused)
    float* agg  = Qb  + (size_t)B * NF * COUT;           // B*NF*COUT (reused)
    float* x1   = agg + (size_t)B * NF * COUT;           // B*NC*CH
    float* x1up = x1  + (size_t)B * NC * CH;             // B*NF*CH
    float* stats= x1up+ (size_t)B * NF * CH;             // 256
    int* cntC   = (int*)(stats + 256);                   // B*NC
    int* offC   = cntC + B * NC;                         // B*NC
    int* curC   = offC + B * NC;                         // B*NC
    int* csrC   = curC + B * NC;                         // B*EC
    int* cntF   = csrC + B * EC;                         // B*NF
    int* offF   = cntF + B * NF;                         // B*NF
    int* curF   = offF + B * NF;                         // B*NF
    int* csrF   = curF + B * NF;                         // B*EF

    float* y  = (float*)d_out;                           // B*NF*COUT
    float* wf = y + (size_t)B * NF * COUT;               // B*NF

    // ---- knn (shared by both interpolations)
    knn_kernel<<<dim3(NF / 32, B), 256, 0, stream>>>(pos, mask, idxb, wnb);
    // ---- CSR builds (coarse and fine)
    hipMemsetAsync(cntC, 0, B * NC * 4, stream);
    hipMemsetAsync(cntF, 0, B * NF * 4, stream);
    hist_kernel<<<dim3(EC / 256, B), 256, 0, stream>>>(ec, cntC, EC, NC, (long)2 * EC);
    hist_kernel<<<dim3(EF / 256, B), 256, 0, stream>>>(ef, cntF, EF, NF, (long)2 * EF);
    scan_kernel<<<dim3(B), 1024, 0, stream>>>(cntC, offC, curC, NC);
    scan_kernel<<<dim3(B), 1024, 0, stream>>>(cntF, offF, curF, NF);
    fill_csr<<<dim3(EC / 256, B), 256, 0, stream>>>(ec, curC, csrC, EC, NC, (long)2 * EC);
    fill_csr<<<dim3(EF / 256, B), 256, 0, stream>>>(ef, curF, csrF, EF, NF, (long)2 * EF);

    // ---- x_up = interp(x)   (needed for skip branch)
    interp_kernel<<<dim3(NF, B), CIN, 0, stream>>>(x, idxb, wnb, xup, CIN);

    // ---- main branch: mpl1 on coarse graph
    gemm_kernel<<<dim3(CH / 64, NC / 64, B), 256, 0, stream>>>(
        x, CIN, nullptr, 0, W1e, nullptr, Pb, NC, CH, 0, (long)NC * CIN, 0, (long)NC * CH);
    gemm_kernel<<<dim3(CH / 64, NC / 64, B), 256, 0, stream>>>(
        x, CIN, nullptr, 0, W1e + CIN * CH, nullptr, Qb, NC, CH, 0, (long)NC * CIN, 0, (long)NC * CH);
    agg_csr<<<dim3(NC / 4, B), 256, 0, stream>>>(
        Pb, Qb, b1e, offC, cntC, csrC, agg, NC, EC, CH, (long)NC * CH);
    gemm_kernel<<<dim3(CH / 64, NC / 64, B), 256, 0, stream>>>(
        x, CIN, agg, CH, W1n, b1n, x1, NC, CH, 1, (long)NC * CIN, (long)NC * CH, (long)NC * CH);
    // ---- x1_up = interp(x1)
    interp_kernel<<<dim3(NF, B), CH, 0, stream>>>(x1, idxb, wnb, x1up, CH);
    // ---- mpl2 on fine graph
    gemm_kernel<<<dim3(COUT / 64, NF / 64, B), 256, 0, stream>>>(
        x1up, CH, nullptr, 0, W2e, nullptr, Pb, NF, COUT, 0, (long)NF * CH, 0, (long)NF * COUT);
    gemm_kernel<<<dim3(COUT / 64, NF / 64, B), 256, 0, stream>>>(
        x1up, CH, nullptr, 0, W2e + CH * COUT, nullptr, Qb, NF, COUT, 0, (long)NF * CH, 0, (long)NF * COUT);
    agg_csr<<<dim3(NF / 4, B), 256, 0, stream>>>(
        Pb, Qb, b2e, offF, cntF, csrF, agg, NF, EF, COUT, (long)NF * COUT);
    gemm_kernel<<<dim3(COUT / 64, NF / 64, B), 256, 0, stream>>>(
        x1up, CH, agg, COUT, W2n, b2n, y, NF, COUT, 1, (long)NF * CH, (long)NF * COUT, (long)NF * COUT);

    // ---- skip branch: mpl on fine graph from x_up, accumulated into y
    gemm_kernel<<<dim3(COUT / 64, NF / 64, B), 256, 0, stream>>>(
        xup, CIN, nullptr, 0, Wse, nullptr, Pb, NF, COUT, 0, (long)NF * CIN, 0, (long)NF * COUT);
    gemm_kernel<<<dim3(COUT / 64, NF / 64, B), 256, 0, stream>>>(
        xup, CIN, nullptr, 0, Wse + CIN * COUT, nullptr, Qb, NF, COUT, 0, (long)NF * CIN, 0, (long)NF * COUT);
    agg_csr<<<dim3(NF / 4, B), 256, 0, stream>>>(
        Pb, Qb, bse, offF, cntF, csrF, agg, NF, EF, COUT, (long)NF * COUT);
    gemm_kernel<<<dim3(COUT / 64, NF / 64, B), 256, 0, stream>>>(
        xup, CIN, agg, COUT, Wsn, bsn, y, NF, COUT, 3, (long)NF * CIN, (long)NF * COUT, (long)NF * COUT);

    // ---- batch norm + lrelu over all B*NF rows
    hipMemsetAsync(stats, 0, 256 * 4, stream);
    bn_stats<<<dim3((B * NF) / 256), COUT, 0, stream>>>(y, stats);
    bn_final<<<dim3((long)B * NF * COUT / 256), 256, 0, stream>>>(y, stats, gamma, beta);

    // ---- w_fine unpool
    wfine_zero<<<dim3(B * NF / 256), 256, 0, stream>>>(wf);
    wfine_scatter<<<dim3(B * NC / 256), 256, 0, stream>>>(wts, mask, wf);
}

// Round 4
// 316.078 us; speedup vs baseline: 2.3622x; 1.2731x over previous
//
#include <hip/hip_runtime.h>
#include <hip/hip_bf16.h>
#include <cfloat>

#define B 4
#define NC 2048
#define NF 8192
#define CIN 128
#define CH 64
#define COUT 128
#define EC 16384
#define EF 65536

typedef __attribute__((ext_vector_type(8))) short short8v;
typedef __attribute__((ext_vector_type(4))) float f32x4;

__device__ __forceinline__ ushort f2b(float v) {
    __hip_bfloat16 h = __float2bfloat16(v);
    return *reinterpret_cast<ushort*>(&h);
}
__device__ __forceinline__ float b2f(ushort u) {
    __hip_bfloat16 h = *reinterpret_cast<__hip_bfloat16*>(&u);
    return __bfloat162float(h);
}

// ---------------------------------------------------------------- knn: top-3 nearest coarse nodes per fine node
// 8 lanes per fine node scan strided candidates (branchless insert); shfl_xor butterfly merge.
__global__ __launch_bounds__(256) void knn_kernel(const float* __restrict__ pos,
                                                  const int* __restrict__ mask,
                                                  int* __restrict__ idx,
                                                  float* __restrict__ wn) {
    __shared__ float4 sp[NC];
    const int b = blockIdx.y;
    const int tid = threadIdx.x;
    for (int i = tid; i < NC; i += 256) {
        int m = mask[b * NC + i];
        const float* p = pos + ((size_t)b * NF + m) * 3;
        sp[i] = make_float4(p[0], p[1], p[2], 0.0f);
    }
    __syncthreads();
    const int f = blockIdx.x * 32 + (tid >> 3);
    const int lane = tid & 7;
    const float* pf = pos + ((size_t)b * NF + f) * 3;
    const float fx = pf[0], fy = pf[1], fz = pf[2];
    float d0 = FLT_MAX, d1 = FLT_MAX, d2 = FLT_MAX;
    int i0 = 0, i1 = 0, i2 = 0;
    #pragma unroll 8
    for (int c = lane; c < NC; c += 8) {
        float4 s = sp[c];
        float dx = __fsub_rn(fx, s.x);
        float dy = __fsub_rn(fy, s.y);
        float dz = __fsub_rn(fz, s.z);
        float d = __fadd_rn(__fadd_rn(__fmul_rn(dx, dx), __fmul_rn(dy, dy)), __fmul_rn(dz, dz));
        bool lt0 = d < d0, lt1 = d < d1, lt2 = d < d2;
        d2 = lt1 ? d1 : (lt2 ? d : d2);  i2 = lt1 ? i1 : (lt2 ? c : i2);
        d1 = lt0 ? d0 : (lt1 ? d : d1);  i1 = lt0 ? i0 : (lt1 ? c : i1);
        d0 = lt0 ? d  : d0;              i0 = lt0 ? c  : i0;
    }
    #pragma unroll
    for (int off = 1; off <= 4; off <<= 1) {
        float od[3]; int oi[3];
        od[0] = __shfl_xor(d0, off); oi[0] = __shfl_xor(i0, off);
        od[1] = __shfl_xor(d1, off); oi[1] = __shfl_xor(i1, off);
        od[2] = __shfl_xor(d2, off); oi[2] = __shfl_xor(i2, off);
        #pragma unroll
        for (int j = 0; j < 3; ++j) {
            float d = od[j]; int c = oi[j];
            bool lt0 = d < d0, lt1 = d < d1, lt2 = d < d2;
            d2 = lt1 ? d1 : (lt2 ? d : d2);  i2 = lt1 ? i1 : (lt2 ? c : i2);
            d1 = lt0 ? d0 : (lt1 ? d : d1);  i1 = lt0 ? i0 : (lt1 ? c : i1);
            d0 = lt0 ? d  : d0;              i0 = lt0 ? c  : i0;
        }
    }
    if (lane == 0) {
        float w0 = 1.0f / (d0 + 1e-16f);
        float w1 = 1.0f / (d1 + 1e-16f);
        float w2 = 1.0f / (d2 + 1e-16f);
        float inv = 1.0f / (w0 + w1 + w2);
        size_t o = ((size_t)b * NF + f) * 3;
        idx[o] = i0; idx[o + 1] = i1; idx[o + 2] = i2;
        wn[o] = w0 * inv; wn[o + 1] = w1 * inv; wn[o + 2] = w2 * inv;
    }
}

// ---------------------------------------------------------------- weighted 3-NN gather, bf16 out
__global__ void interp_b16(const float* __restrict__ xc, const int* __restrict__ idx,
                           const float* __restrict__ wn, ushort* __restrict__ out, int C) {
    const int b = blockIdx.y, f = blockIdx.x, c = threadIdx.x;
    size_t o = ((size_t)b * NF + f) * 3;
    int i0 = idx[o], i1 = idx[o + 1], i2 = idx[o + 2];
    float w0 = wn[o], w1 = wn[o + 1], w2 = wn[o + 2];
    const float* xb = xc + (size_t)b * NC * C;
    float v = w0 * xb[(size_t)i0 * C + c] + w1 * xb[(size_t)i1 * C + c] + w2 * xb[(size_t)i2 * C + c];
    out[((size_t)b * NF + f) * C + c] = f2b(v);
}

// ---------------------------------------------------------------- f32 GEMM (coarse path only)
__global__ __launch_bounds__(256) void gemm_kernel(
    const float* __restrict__ A1, int K1, const float* __restrict__ A2, int K2,
    const float* __restrict__ W, const float* __restrict__ bias,
    float* __restrict__ Cmat, int M, int N, int flags,
    long sA1, long sA2, long sC) {
    __shared__ float As[16][64];
    __shared__ float Wsh[16][64];
    const int b = blockIdx.z;
    const int m0 = blockIdx.y * 64, n0 = blockIdx.x * 64;
    const int t = threadIdx.x;
    const int tx = t & 15, ty = t >> 4;
    float acc[4][4] = {};
    int kOff = 0;
    for (int s = 0; s < 2; ++s) {
        const float* A = (s == 0) ? A1 : A2;
        const int K = (s == 0) ? K1 : K2;
        const long sA = (s == 0) ? sA1 : sA2;
        if (A == nullptr || K == 0) continue;
        const float* Ab = A + (size_t)b * sA;
        const int lm = t >> 2;
        const int lk = (t & 3) << 2;
        const int wk = t >> 4;
        const int wng = (t & 15) << 2;
        for (int k0 = 0; k0 < K; k0 += 16) {
            float4 av = *(const float4*)&Ab[(size_t)(m0 + lm) * K + k0 + lk];
            As[lk + 0][lm] = av.x; As[lk + 1][lm] = av.y;
            As[lk + 2][lm] = av.z; As[lk + 3][lm] = av.w;
            float4 wv = *(const float4*)&W[(size_t)(kOff + k0 + wk) * N + n0 + wng];
            *(float4*)&Wsh[wk][wng] = wv;
            __syncthreads();
            #pragma unroll
            for (int k = 0; k < 16; ++k) {
                float4 a4 = *(const float4*)&As[k][ty << 2];
                float4 w4 = *(const float4*)&Wsh[k][tx << 2];
                float aa[4] = {a4.x, a4.y, a4.z, a4.w};
                float ww[4] = {w4.x, w4.y, w4.z, w4.w};
                #pragma unroll
                for (int i = 0; i < 4; ++i)
                    #pragma unroll
                    for (int j = 0; j < 4; ++j)
                        acc[i][j] = fmaf(aa[i], ww[j], acc[i][j]);
            }
            __syncthreads();
        }
        kOff += K;
    }
    float* Cb = Cmat + (size_t)b * sC;
    #pragma unroll
    for (int i = 0; i < 4; ++i) {
        int m = m0 + (ty << 2) + i;
        #pragma unroll
        for (int j = 0; j < 4; ++j) {
            int n = n0 + (tx << 2) + j;
            float v = acc[i][j];
            if (bias) v += bias[n];
            if (flags & 1) v = v > 0.0f ? v : 0.01f * v;
            float* cp = &Cb[(size_t)m * N + n];
            if (flags & 2) v += *cp;
            *cp = v;
        }
    }
}

// ---------------------------------------------------------------- MFMA bf16 GEMM (fine path, N=128)
// grid: (M/128, 1, B*npq).  z -> (b, pq).  Wt is [128][ldW] bf16 (transposed weights);
// column window = pq*kPQ + segment offset.  flags: 1 lrelu, 2 +=C, 4 bf16 out.
#define LDK 40
__global__ __launch_bounds__(256) void mfma_gemm(
    const ushort* __restrict__ A1, int K1, const ushort* __restrict__ A2, int K2,
    const ushort* __restrict__ Wt, int ldW, int kPQ, int npq,
    const float* __restrict__ bias, void* __restrict__ C0v, void* __restrict__ C1v,
    int flags, long sA1, long sA2, long sC) {
    __shared__ ushort As[128 * LDK];
    __shared__ ushort Wsm[128 * LDK];
    const int t = threadIdx.x;
    const int lane = t & 63, wid = t >> 6;
    const int wr = wid >> 1, wc = wid & 1;
    const int fr = lane & 15, fq = lane >> 4;
    const int sr = t >> 2, sk = (t & 3) * 8;
    const int z = blockIdx.z;
    const int b = z / npq, pq = z - b * npq;
    const int m0 = blockIdx.x * 128;
    const int wbase = pq * kPQ;

    f32x4 acc[4][4];
    #pragma unroll
    for (int m = 0; m < 4; ++m)
        #pragma unroll
        for (int n = 0; n < 4; ++n)
            acc[m][n] = (f32x4){0.f, 0.f, 0.f, 0.f};

    int kOff = 0;
    for (int s = 0; s < 2; ++s) {
        const ushort* A = (s == 0) ? A1 : A2;
        const int K = (s == 0) ? K1 : K2;
        const long sA = (s == 0) ? sA1 : sA2;
        if (A == nullptr || K == 0) continue;
        const ushort* Ab = A + (size_t)b * sA;
        for (int k0 = 0; k0 < K; k0 += 32) {
            #pragma unroll
            for (int p = 0; p < 2; ++p) {
                int r = sr + p * 64;
                *reinterpret_cast<int4*>(&As[r * LDK + sk]) =
                    *reinterpret_cast<const int4*>(&Ab[(size_t)(m0 + r) * K + k0 + sk]);
                *reinterpret_cast<int4*>(&Wsm[r * LDK + sk]) =
                    *reinterpret_cast<const int4*>(&Wt[(size_t)r * ldW + wbase + kOff + k0 + sk]);
            }
            __syncthreads();
            short8v af[4], wf[4];
            #pragma unroll
            for (int m = 0; m < 4; ++m)
                af[m] = *reinterpret_cast<const short8v*>(&As[(wr * 64 + m * 16 + fr) * LDK + fq * 8]);
            #pragma unroll
            for (int n = 0; n < 4; ++n)
                wf[n] = *reinterpret_cast<const short8v*>(&Wsm[(wc * 64 + n * 16 + fr) * LDK + fq * 8]);
            #pragma unroll
            for (int m = 0; m < 4; ++m)
                #pragma unroll
                for (int n = 0; n < 4; ++n)
                    acc[m][n] = __builtin_amdgcn_mfma_f32_16x16x32_bf16(af[m], wf[n], acc[m][n], 0, 0, 0);
            __syncthreads();
        }
        kOff += K;
    }

    void* Cv = (pq == 0) ? C0v : C1v;
    if (flags & 4) {
        ushort* Cb = (ushort*)Cv + (size_t)b * sC;
        #pragma unroll
        for (int m = 0; m < 4; ++m)
            #pragma unroll
            for (int n = 0; n < 4; ++n) {
                int col = wc * 64 + n * 16 + fr;
                #pragma unroll
                for (int r = 0; r < 4; ++r) {
                    int row = m0 + wr * 64 + m * 16 + fq * 4 + r;
                    Cb[(size_t)row * 128 + col] = f2b(acc[m][n][r]);
                }
            }
    } else {
        float* Cb = (float*)Cv + (size_t)b * sC;
        #pragma unroll
        for (int m = 0; m < 4; ++m)
            #pragma unroll
            for (int n = 0; n < 4; ++n) {
                int col = wc * 64 + n * 16 + fr;
                float bv = bias ? bias[col] : 0.0f;
                #pragma unroll
                for (int r = 0; r < 4; ++r) {
                    int row = m0 + wr * 64 + m * 16 + fq * 4 + r;
                    float v = acc[m][n][r] + bv;
                    if (flags & 1) v = v > 0.0f ? v : 0.01f * v;
                    float* cp = &Cb[(size_t)row * 128 + col];
                    if (flags & 2) v += *cp;
                    *cp = v;
                }
            }
    }
}

// ---------------------------------------------------------------- fine weight transpose+bf16: Wt[n][k] = bf16(W[k][n])
__global__ void conv_wt(const float* __restrict__ W2e, const float* __restrict__ W2n,
                        const float* __restrict__ Wse, const float* __restrict__ Wsn,
                        ushort* __restrict__ W2eT, ushort* __restrict__ W2nT,
                        ushort* __restrict__ WseT, ushort* __restrict__ WsnT) {
    const float* src; ushort* dst; int K2;
    switch (blockIdx.y) {
        case 0: src = W2e; dst = W2eT; K2 = 128; break;
        case 1: src = W2n; dst = W2nT; K2 = 192; break;
        case 2: src = Wse; dst = WseT; K2 = 256; break;
        default: src = Wsn; dst = WsnT; K2 = 256; break;
    }
    int id = blockIdx.x * 256 + threadIdx.x;
    if (id >= K2 * 128) return;
    int n = id & 127, k = id >> 7;
    dst[(size_t)n * K2 + k] = f2b(src[id]);
}

// ---------------------------------------------------------------- CSR build
__global__ void hist_kernel(const int* __restrict__ ei, int* __restrict__ counts,
                            int E, int N, long sEi) {
    const int b = blockIdx.y;
    int e = blockIdx.x * 256 + threadIdx.x;
    if (e >= E) return;
    int dst = ei[(size_t)b * sEi + E + e];
    atomicAdd(&counts[b * N + dst], 1);
}

__global__ __launch_bounds__(1024) void scan_kernel(const int* __restrict__ counts,
                                                    int* __restrict__ offs,
                                                    int* __restrict__ cursor, int N) {
    __shared__ int part[1024];
    const int b = blockIdx.x;
    const int tid = threadIdx.x;
    const int per = N >> 10;
    int local[8];
    int s = 0;
    #pragma unroll
    for (int i = 0; i < 8; ++i) {
        if (i < per) { local[i] = s; s += counts[b * N + tid * per + i]; }
    }
    part[tid] = s;
    __syncthreads();
    for (int off = 1; off < 1024; off <<= 1) {
        int v = (tid >= off) ? part[tid - off] : 0;
        __syncthreads();
        part[tid] += v;
        __syncthreads();
    }
    int pre = (tid == 0) ? 0 : part[tid - 1];
    #pragma unroll
    for (int i = 0; i < 8; ++i) {
        if (i < per) {
            int o = pre + local[i];
            offs[b * N + tid * per + i] = o;
            cursor[b * N + tid * per + i] = o;
        }
    }
}

__global__ void fill_csr(const int* __restrict__ ei, int* __restrict__ cursor,
                         int* __restrict__ csr_src, int E, int N, long sEi) {
    const int b = blockIdx.y;
    int e = blockIdx.x * 256 + threadIdx.x;
    if (e >= E) return;
    const int* eb = ei + (size_t)b * sEi;
    int src = eb[e], dst = eb[E + e];
    int pos = atomicAdd(&cursor[b * N + dst], 1);
    csr_src[(size_t)b * E + pos] = src;
}

// ---------------------------------------------------------------- edge message + aggregate (coarse, f32, C=64)
__global__ __launch_bounds__(256) void agg_csr_f32(const float* __restrict__ P,
                                                   const float* __restrict__ Q,
                                                   const float* __restrict__ bias,
                                                   const int* __restrict__ offs,
                                                   const int* __restrict__ counts,
                                                   const int* __restrict__ csr_src,
                                                   float* __restrict__ agg,
                                                   int N, int E) {
    const int b = blockIdx.y;
    const int dst = blockIdx.x * 4 + (threadIdx.x >> 6);
    const int lane = threadIdx.x & 63;
    const float* Pb = P + (size_t)b * N * 64;
    const float* Qb = Q + (size_t)b * N * 64;
    const int start = offs[b * N + dst];
    const int cnt = counts[b * N + dst];
    const int* sl = csr_src + (size_t)b * E + start;
    const float q = Qb[(size_t)dst * 64 + lane] + bias[lane];
    float a = 0.0f;
    for (int i = 0; i < cnt; ++i) {
        int src = sl[i];
        float m = Pb[(size_t)src * 64 + lane] + q; m = m > 0.0f ? m : 0.01f * m;
        a += m;
    }
    agg[(size_t)b * N * 64 + (size_t)dst * 64 + lane] = a;
}

// ---------------------------------------------------------------- edge message + aggregate (fine, bf16 io, C=128)
__global__ __launch_bounds__(256) void agg_csr_b16(const ushort* __restrict__ P,
                                                   const ushort* __restrict__ Q,
                                                   const float* __restrict__ bias,
                                                   const int* __restrict__ offs,
                                                   const int* __restrict__ counts,
                                                   const int* __restrict__ csr_src,
                                                   ushort* __restrict__ agg,
                                                   int N, int E) {
    const int b = blockIdx.y;
    const int dst = blockIdx.x * 4 + (threadIdx.x >> 6);
    const int lane = threadIdx.x & 63;
    const ushort* Pb = P + (size_t)b * N * 128;
    const ushort* Qb = Q + (size_t)b * N * 128;
    const int start = offs[b * N + dst];
    const int cnt = counts[b * N + dst];
    const int* sl = csr_src + (size_t)b * E + start;
    const int c0 = lane, c1 = lane + 64;
    const float q0 = b2f(Qb[(size_t)dst * 128 + c0]) + bias[c0];
    const float q1 = b2f(Qb[(size_t)dst * 128 + c1]) + bias[c1];
    float a0 = 0.0f, a1 = 0.0f;
    for (int i = 0; i < cnt; ++i) {
        int src = sl[i];
        float m0 = b2f(Pb[(size_t)src * 128 + c0]) + q0; m0 = m0 > 0.0f ? m0 : 0.01f * m0;
        float m1 = b2f(Pb[(size_t)src * 128 + c1]) + q1; m1 = m1 > 0.0f ? m1 : 0.01f * m1;
        a0 += m0; a1 += m1;
    }
    agg[(size_t)b * N * 128 + (size_t)dst * 128 + c0] = f2b(a0);
    agg[(size_t)b * N * 128 + (size_t)dst * 128 + c1] = f2b(a1);
}

// ---------------------------------------------------------------- batch-norm
__global__ void bn_stats(const float* __restrict__ xs, float* __restrict__ stats) {
    const int c = threadIdx.x;
    long r0 = (long)blockIdx.x * 256;
    float s = 0.0f, s2 = 0.0f;
    for (int r = 0; r < 256; ++r) {
        float v = xs[(r0 + r) * COUT + c];
        s += v;
        s2 = fmaf(v, v, s2);
    }
    atomicAdd(&stats[c], s);
    atomicAdd(&stats[COUT + c], s2);
}

__global__ void bn_final(float* __restrict__ xs, const float* __restrict__ stats,
                         const float* __restrict__ gamma, const float* __restrict__ beta) {
    long g = (long)blockIdx.x * 256 + threadIdx.x;
    int c = (int)(g & (COUT - 1));
    const float invN = 1.0f / (float)(B * NF);
    float mu = stats[c] * invN;
    float var = stats[COUT + c] * invN - mu * mu;
    float v = (xs[g] - mu) * rsqrtf(var + 1e-5f) * gamma[c] + beta[c];
    xs[g] = v > 0.0f ? v : 0.01f * v;
}

// ---------------------------------------------------------------- w_fine unpool
__global__ void wfine_zero(float* __restrict__ wf) {
    long g = (long)blockIdx.x * 256 + threadIdx.x;
    wf[g] = 0.0f;
}
__global__ void wfine_scatter(const float* __restrict__ wts, const int* __restrict__ mask,
                              float* __restrict__ wf) {
    int i = blockIdx.x * 256 + threadIdx.x;
    int b = i / NC;
    wf[(size_t)b * NF + mask[i]] = wts[i];
}

extern "C" void kernel_launch(void* const* d_in, const int* in_sizes, int n_in,
                              void* d_out, int out_size, void* d_ws, size_t ws_size,
                              hipStream_t stream) {
    const float* x    = (const float*)d_in[0];
    const float* wts  = (const float*)d_in[1];
    const float* pos  = (const float*)d_in[2];
    const float* W1e  = (const float*)d_in[3];
    const float* b1e  = (const float*)d_in[4];
    const float* W1n  = (const float*)d_in[5];
    const float* b1n  = (const float*)d_in[6];
    const float* W2e  = (const float*)d_in[7];
    const float* b2e  = (const float*)d_in[8];
    const float* W2n  = (const float*)d_in[9];
    const float* b2n  = (const float*)d_in[10];
    const float* Wse  = (const float*)d_in[11];
    const float* bse  = (const float*)d_in[12];
    const float* Wsn  = (const float*)d_in[13];
    const float* bsn  = (const float*)d_in[14];
    const float* gamma= (const float*)d_in[15];
    const float* beta = (const float*)d_in[16];
    const int*   mask = (const int*)d_in[17];
    const int*   ec   = (const int*)d_in[18];
    const int*   ef   = (const int*)d_in[19];

    float* ws = (float*)d_ws;
    // ---- f32 / int region
    int*   idxb = (int*)ws;                               // B*NF*3
    float* wnb  = ws + 98304;                             // B*NF*3
    float* x1   = ws + 196608;                            // B*NC*64
    float* PbC  = x1  + (size_t)B * NC * CH;              // B*NC*64
    float* QbC  = PbC + (size_t)B * NC * CH;              // B*NC*64
    float* aggC = QbC + (size_t)B * NC * CH;              // B*NC*64
    float* stats= aggC+ (size_t)B * NC * CH;              // 256
    int* cntC   = (int*)(stats + 256);                    // B*NC
    int* offC   = cntC + B * NC;
    int* curC   = offC + B * NC;
    int* csrC   = curC + B * NC;                          // B*EC
    int* cntF   = csrC + B * EC;                          // B*NF
    int* offF   = cntF + B * NF;
    int* curF   = offF + B * NF;
    int* csrF   = curF + B * NF;                          // B*EF
    // ---- bf16 region (16B aligned: recompute from float offset)
    size_t foff = (size_t)(csrF + (size_t)B * EF - (int*)ws);
    foff = (foff + 7) & ~(size_t)7;                       // 32B align
    ushort* bfr   = (ushort*)(ws + foff);
    ushort* xupb  = bfr;                                   // B*NF*128
    ushort* x1upb = xupb  + (size_t)B * NF * 128;          // B*NF*64
    ushort* Pb    = x1upb + (size_t)B * NF * 64;           // B*NF*128
    ushort* Qb    = Pb    + (size_t)B * NF * 128;          // B*NF*128
    ushort* aggb  = Qb    + (size_t)B * NF * 128;          // B*NF*128
    ushort* W2eT  = aggb  + (size_t)B * NF * 128;          // 128*128
    ushort* W2nT  = W2eT  + 128 * 128;                     // 128*192
    ushort* WseT  = W2nT  + 128 * 192;                     // 128*256
    ushort* WsnT  = WseT  + 128 * 256;                     // 128*256

    float* y  = (float*)d_out;                             // B*NF*128
    float* wf = y + (size_t)B * NF * COUT;                 // B*NF

    // ---- weight transpose/convert + knn + CSR (independent prep)
    conv_wt<<<dim3(128, 4), 256, 0, stream>>>(W2e, W2n, Wse, Wsn, W2eT, W2nT, WseT, WsnT);
    knn_kernel<<<dim3(NF / 32, B), 256, 0, stream>>>(pos, mask, idxb, wnb);
    hipMemsetAsync(cntC, 0, B * NC * 4, stream);
    hipMemsetAsync(cntF, 0, B * NF * 4, stream);
    hist_kernel<<<dim3(EC / 256, B), 256, 0, stream>>>(ec, cntC, EC, NC, (long)2 * EC);
    hist_kernel<<<dim3(EF / 256, B), 256, 0, stream>>>(ef, cntF, EF, NF, (long)2 * EF);
    scan_kernel<<<dim3(B), 1024, 0, stream>>>(cntC, offC, curC, NC);
    scan_kernel<<<dim3(B), 1024, 0, stream>>>(cntF, offF, curF, NF);
    fill_csr<<<dim3(EC / 256, B), 256, 0, stream>>>(ec, curC, csrC, EC, NC, (long)2 * EC);
    fill_csr<<<dim3(EF / 256, B), 256, 0, stream>>>(ef, curF, csrF, EF, NF, (long)2 * EF);

    // ---- x_up = interp(x) -> bf16
    interp_b16<<<dim3(NF, B), CIN, 0, stream>>>(x, idxb, wnb, xupb, CIN);

    // ---- main branch: mpl1 on coarse graph (f32 path)
    gemm_kernel<<<dim3(1, NC / 64, B), 256, 0, stream>>>(
        x, CIN, nullptr, 0, W1e, nullptr, PbC, NC, CH, 0, (long)NC * CIN, 0, (long)NC * CH);
    gemm_kernel<<<dim3(1, NC / 64, B), 256, 0, stream>>>(
        x, CIN, nullptr, 0, W1e + CIN * CH, nullptr, QbC, NC, CH, 0, (long)NC * CIN, 0, (long)NC * CH);
    agg_csr_f32<<<dim3(NC / 4, B), 256, 0, stream>>>(
        PbC, QbC, b1e, offC, cntC, csrC, aggC, NC, EC);
    gemm_kernel<<<dim3(1, NC / 64, B), 256, 0, stream>>>(
        x, CIN, aggC, CH, W1n, b1n, x1, NC, CH, 1, (long)NC * CIN, (long)NC * CH, (long)NC * CH);

    // ---- x1_up = interp(x1) -> bf16
    interp_b16<<<dim3(NF, B), CH, 0, stream>>>(x1, idxb, wnb, x1upb, CH);

    // ---- mpl2 on fine graph (MFMA path)
    mfma_gemm<<<dim3(NF / 128, 1, B * 2), 256, 0, stream>>>(
        x1upb, CH, nullptr, 0, W2eT, 128, CH, 2, nullptr, Pb, Qb, 4,
        (long)NF * CH, 0, (long)NF * 128);
    agg_csr_b16<<<dim3(NF / 4, B), 256, 0, stream>>>(
        Pb, Qb, b2e, offF, cntF, csrF, aggb, NF, EF);
    mfma_gemm<<<dim3(NF / 128, 1, B), 256, 0, stream>>>(
        x1upb, CH, aggb, COUT, W2nT, 192, 0, 1, b2n, y, y, 1,
        (long)NF * CH, (long)NF * 128, (long)NF * 128);

    // ---- skip branch (MFMA path), accumulated into y
    mfma_gemm<<<dim3(NF / 128, 1, B * 2), 256, 0, stream>>>(
        xupb, CIN, nullptr, 0, WseT, 256, CIN, 2, nullptr, Pb, Qb, 4,
        (long)NF * CIN, 0, (long)NF * 128);
    agg_csr_b16<<<dim3(NF / 4, B), 256, 0, stream>>>(
        Pb, Qb, bse, offF, cntF, csrF, aggb, NF, EF);
    mfma_gemm<<<dim3(NF / 128, 1, B), 256, 0, stream>>>(
        xupb, CIN, aggb, COUT, WsnT, 256, 0, 1, bsn, y, y, 3,
        (long)NF * CIN, (long)NF * 128, (long)NF * 128);

    // ---- batch norm + lrelu
    hipMemsetAsync(stats, 0, 256 * 4, stream);
    bn_stats<<<dim3((B * NF) / 256), COUT, 0, stream>>>(y, stats);
    bn_final<<<dim3((long)B * NF * COUT / 256), 256, 0, stream>>>(y, stats, gamma, beta);

    // ---- w_fine unpool
    wfine_zero<<<dim3(B * NF / 256), 256, 0, stream>>>(wf);
    wfine_scatter<<<dim3(B * NC / 256), 256, 0, stream>>>(wts, mask, wf);
}

// Round 5
// 300.746 us; speedup vs baseline: 2.4826x; 1.0510x over previous
//
#include <hip/hip_runtime.h>
#include <hip/hip_bf16.h>
#include <cfloat>

#define B 4
#define NC 2048
#define NF 8192
#define CIN 128
#define CH 64
#define COUT 128
#define EC 16384
#define EF 65536

typedef __attribute__((ext_vector_type(8))) short short8v;
typedef __attribute__((ext_vector_type(4))) float f32x4;

__device__ __forceinline__ ushort f2b(float v) {
    __hip_bfloat16 h = __float2bfloat16(v);
    return *reinterpret_cast<ushort*>(&h);
}
__device__ __forceinline__ float b2f(ushort u) {
    __hip_bfloat16 h = *reinterpret_cast<__hip_bfloat16*>(&u);
    return __bfloat162float(h);
}

// ---------------------------------------------------------------- combined count: coarse hist / fine hist / bin count
__global__ void count_all(const int* __restrict__ ec, const int* __restrict__ ef,
                          const int* __restrict__ mask, const float* __restrict__ pos,
                          int* __restrict__ cntC, int* __restrict__ cntF, int* __restrict__ cntB) {
    const int b = blockIdx.y, z = blockIdx.z;
    const int i = blockIdx.x * 256 + threadIdx.x;
    if (z == 0) {
        if (i < EC) atomicAdd(&cntC[b * NC + ec[(size_t)b * 2 * EC + EC + i]], 1);
    } else if (z == 1) {
        if (i < EF) atomicAdd(&cntF[b * NF + ef[(size_t)b * 2 * EF + EF + i]], 1);
    } else {
        if (i < NC) {
            int m = mask[b * NC + i];
            const float* p = pos + ((size_t)b * NF + m) * 3;
            int cx = min(max((int)(p[0] * 8.0f), 0), 7);
            int cy = min(max((int)(p[1] * 8.0f), 0), 7);
            int cz = min(max((int)(p[2] * 8.0f), 0), 7);
            atomicAdd(&cntB[b * 512 + (cz * 8 + cy) * 8 + cx], 1);
        }
    }
}

// ---------------------------------------------------------------- combined exclusive scan (grid = 3*B blocks)
template<int N, int OSTR, bool EXTRA>
__device__ __forceinline__ void scan_body(const int* __restrict__ cnt, int* __restrict__ offs,
                                          int* __restrict__ cur, int b, int* part) {
    const int tid = threadIdx.x;
    constexpr int PER = (N + 1023) / 1024;
    int local[PER];
    int s = 0;
    #pragma unroll
    for (int i = 0; i < PER; ++i) {
        int id = tid * PER + i;
        local[i] = s;
        if (id < N) s += cnt[b * N + id];
    }
    part[tid] = s;
    __syncthreads();
    for (int off = 1; off < 1024; off <<= 1) {
        int v = (tid >= off) ? part[tid - off] : 0;
        __syncthreads();
        part[tid] += v;
        __syncthreads();
    }
    int pre = tid ? part[tid - 1] : 0;
    #pragma unroll
    for (int i = 0; i < PER; ++i) {
        int id = tid * PER + i;
        if (id < N) {
            int o = pre + local[i];
            offs[b * OSTR + id] = o;
            cur[b * OSTR + id] = o;
        }
    }
    if (EXTRA && tid == 1023) offs[b * OSTR + N] = part[1023];
}

__global__ __launch_bounds__(1024) void scan_all(
    const int* __restrict__ cntC, int* __restrict__ offC, int* __restrict__ curC,
    const int* __restrict__ cntF, int* __restrict__ offF, int* __restrict__ curF,
    const int* __restrict__ cntB, int* __restrict__ offB, int* __restrict__ curB) {
    __shared__ int part[1024];
    const int cfg = blockIdx.x >> 2;   // B == 4
    const int b = blockIdx.x & 3;
    if (cfg == 0)      scan_body<NC, NC, false>(cntC, offC, curC, b, part);
    else if (cfg == 1) scan_body<NF, NF, false>(cntF, offF, curF, b, part);
    else               scan_body<512, 513, true>(cntB, offB, curB, b, part);
}

// ---------------------------------------------------------------- combined fill: coarse CSR / fine CSR / bin positions
__global__ void fill_all(const int* __restrict__ ec, const int* __restrict__ ef,
                         const int* __restrict__ mask, const float* __restrict__ pos,
                         int* __restrict__ curC, int* __restrict__ curF, int* __restrict__ curB,
                         int* __restrict__ csrC, int* __restrict__ csrF,
                         float4* __restrict__ sposg) {
    const int b = blockIdx.y, z = blockIdx.z;
    const int i = blockIdx.x * 256 + threadIdx.x;
    if (z == 0) {
        if (i < EC) {
            const int* eb = ec + (size_t)b * 2 * EC;
            int src = eb[i], dst = eb[EC + i];
            int p = atomicAdd(&curC[b * NC + dst], 1);
            csrC[(size_t)b * EC + p] = src;
        }
    } else if (z == 1) {
        if (i < EF) {
            const int* eb = ef + (size_t)b * 2 * EF;
            int src = eb[i], dst = eb[EF + i];
            int p = atomicAdd(&curF[b * NF + dst], 1);
            csrF[(size_t)b * EF + p] = src;
        }
    } else {
        if (i < NC) {
            int m = mask[b * NC + i];
            const float* p = pos + ((size_t)b * NF + m) * 3;
            float px = p[0], py = p[1], pz = p[2];
            int cx = min(max((int)(px * 8.0f), 0), 7);
            int cy = min(max((int)(py * 8.0f), 0), 7);
            int cz = min(max((int)(pz * 8.0f), 0), 7);
            int slot = atomicAdd(&curB[b * 513 + (cz * 8 + cy) * 8 + cx], 1);
            sposg[(size_t)b * NC + slot] = make_float4(px, py, pz, __int_as_float(i));
        }
    }
}

// ---------------------------------------------------------------- knn via 8^3 grid, expanding-ring exact search
__global__ __launch_bounds__(256) void knn_ring(const float* __restrict__ pos,
                                                const float4* __restrict__ sposg,
                                                const int* __restrict__ offB,
                                                int* __restrict__ idx,
                                                float* __restrict__ wn) {
    __shared__ float4 sp[NC];
    __shared__ int cs[513];
    const int b = blockIdx.y;
    const int tid = threadIdx.x;
    for (int i = tid; i < NC; i += 256) sp[i] = sposg[(size_t)b * NC + i];
    for (int i = tid; i < 513; i += 256) cs[i] = offB[b * 513 + i];
    __syncthreads();
    const int f = blockIdx.x * 256 + tid;
    const float* pf = pos + ((size_t)b * NF + f) * 3;
    const float px = pf[0], py = pf[1], pz = pf[2];
    const int cx = min(max((int)(px * 8.0f), 0), 7);
    const int cy = min(max((int)(py * 8.0f), 0), 7);
    const int cz = min(max((int)(pz * 8.0f), 0), 7);
    float d0 = FLT_MAX, d1 = FLT_MAX, d2 = FLT_MAX;
    int i0 = 0, i1 = 0, i2 = 0;
    for (int r = 0; r < 9; ++r) {
        const int xlo = max(cx - r, 0), xhi = min(cx + r, 7);
        const int ylo = max(cy - r, 0), yhi = min(cy + r, 7);
        const int zlo = max(cz - r, 0), zhi = min(cz + r, 7);
        for (int zz = zlo; zz <= zhi; ++zz) {
            const int dzc = abs(zz - cz);
            for (int yy = ylo; yy <= yhi; ++yy) {
                const int dm = max(dzc, abs(yy - cy));
                int xa, xb, xstep;
                if (dm == r) { xa = xlo; xb = xhi; xstep = 1; }
                else         { xa = cx - r; xb = cx + r; xstep = 2 * r; }
                for (int xx = xa; xx <= xb; xx += xstep) {
                    if (xx < 0 || xx > 7) continue;
                    const int cell = (zz * 8 + yy) * 8 + xx;
                    const int j1 = cs[cell + 1];
                    for (int j = cs[cell]; j < j1; ++j) {
                        float4 s = sp[j];
                        // match numpy: diff, square, sequential sum — no FMA contraction
                        float ddx = __fsub_rn(px, s.x);
                        float ddy = __fsub_rn(py, s.y);
                        float ddz = __fsub_rn(pz, s.z);
                        float d = __fadd_rn(__fadd_rn(__fmul_rn(ddx, ddx), __fmul_rn(ddy, ddy)),
                                            __fmul_rn(ddz, ddz));
                        int ci = __float_as_int(s.w);
                        bool lt0 = d < d0, lt1 = d < d1, lt2 = d < d2;
                        d2 = lt1 ? d1 : (lt2 ? d : d2);  i2 = lt1 ? i1 : (lt2 ? ci : i2);
                        d1 = lt0 ? d0 : (lt1 ? d : d1);  i1 = lt0 ? i0 : (lt1 ? ci : i1);
                        d0 = lt0 ? d  : d0;              i0 = lt0 ? ci : i0;
                    }
                }
            }
        }
        // exact stop bound: nearest possible unsearched point is at >= bd
        float bd = 1e30f;
        if (cx - r > 0)     bd = fminf(bd, px - (float)(cx - r) * 0.125f);
        if (cx + r + 1 < 8) bd = fminf(bd, (float)(cx + r + 1) * 0.125f - px);
        if (cy - r > 0)     bd = fminf(bd, py - (float)(cy - r) * 0.125f);
        if (cy + r + 1 < 8) bd = fminf(bd, (float)(cy + r + 1) * 0.125f - py);
        if (cz - r > 0)     bd = fminf(bd, pz - (float)(cz - r) * 0.125f);
        if (cz + r + 1 < 8) bd = fminf(bd, (float)(cz + r + 1) * 0.125f - pz);
        bd *= 0.9999f;   // absorb f32 rounding in the bound
        if (d2 <= bd * bd) break;
    }
    float w0 = 1.0f / (d0 + 1e-16f);
    float w1 = 1.0f / (d1 + 1e-16f);
    float w2 = 1.0f / (d2 + 1e-16f);
    float inv = 1.0f / (w0 + w1 + w2);
    size_t o = ((size_t)b * NF + f) * 3;
    idx[o] = i0; idx[o + 1] = i1; idx[o + 2] = i2;
    wn[o] = w0 * inv; wn[o + 1] = w1 * inv; wn[o + 2] = w2 * inv;
}

// ---------------------------------------------------------------- weighted 3-NN gather, bf16 out
__global__ void interp_b16(const float* __restrict__ xc, const int* __restrict__ idx,
                           const float* __restrict__ wn, ushort* __restrict__ out, int C) {
    const int b = blockIdx.y, f = blockIdx.x, c = threadIdx.x;
    size_t o = ((size_t)b * NF + f) * 3;
    int i0 = idx[o], i1 = idx[o + 1], i2 = idx[o + 2];
    float w0 = wn[o], w1 = wn[o + 1], w2 = wn[o + 2];
    const float* xb = xc + (size_t)b * NC * C;
    float v = w0 * xb[(size_t)i0 * C + c] + w1 * xb[(size_t)i1 * C + c] + w2 * xb[(size_t)i2 * C + c];
    out[((size_t)b * NF + f) * C + c] = f2b(v);
}

// ---------------------------------------------------------------- f32 GEMM (coarse node MLP)
__global__ __launch_bounds__(256) void gemm_kernel(
    const float* __restrict__ A1, int K1, const float* __restrict__ A2, int K2,
    const float* __restrict__ W, const float* __restrict__ bias,
    float* __restrict__ Cmat, int M, int N, int flags,
    long sA1, long sA2, long sC) {
    __shared__ float As[16][64];
    __shared__ float Wsh[16][64];
    const int b = blockIdx.z;
    const int m0 = blockIdx.y * 64, n0 = blockIdx.x * 64;
    const int t = threadIdx.x;
    const int tx = t & 15, ty = t >> 4;
    float acc[4][4] = {};
    int kOff = 0;
    for (int s = 0; s < 2; ++s) {
        const float* A = (s == 0) ? A1 : A2;
        const int K = (s == 0) ? K1 : K2;
        const long sA = (s == 0) ? sA1 : sA2;
        if (A == nullptr || K == 0) continue;
        const float* Ab = A + (size_t)b * sA;
        const int lm = t >> 2;
        const int lk = (t & 3) << 2;
        const int wk = t >> 4;
        const int wng = (t & 15) << 2;
        for (int k0 = 0; k0 < K; k0 += 16) {
            float4 av = *(const float4*)&Ab[(size_t)(m0 + lm) * K + k0 + lk];
            As[lk + 0][lm] = av.x; As[lk + 1][lm] = av.y;
            As[lk + 2][lm] = av.z; As[lk + 3][lm] = av.w;
            float4 wv = *(const float4*)&W[(size_t)(kOff + k0 + wk) * N + n0 + wng];
            *(float4*)&Wsh[wk][wng] = wv;
            __syncthreads();
            #pragma unroll
            for (int k = 0; k < 16; ++k) {
                float4 a4 = *(const float4*)&As[k][ty << 2];
                float4 w4 = *(const float4*)&Wsh[k][tx << 2];
                float aa[4] = {a4.x, a4.y, a4.z, a4.w};
                float ww[4] = {w4.x, w4.y, w4.z, w4.w};
                #pragma unroll
                for (int i = 0; i < 4; ++i)
                    #pragma unroll
                    for (int j = 0; j < 4; ++j)
                        acc[i][j] = fmaf(aa[i], ww[j], acc[i][j]);
            }
            __syncthreads();
        }
        kOff += K;
    }
    float* Cb = Cmat + (size_t)b * sC;
    #pragma unroll
    for (int i = 0; i < 4; ++i) {
        int m = m0 + (ty << 2) + i;
        #pragma unroll
        for (int j = 0; j < 4; ++j) {
            int n = n0 + (tx << 2) + j;
            float v = acc[i][j];
            if (bias) v += bias[n];
            if (flags & 1) v = v > 0.0f ? v : 0.01f * v;
            float* cp = &Cb[(size_t)m * N + n];
            if (flags & 2) v += *cp;
            *cp = v;
        }
    }
}

// ---------------------------------------------------------------- coarse P/Q GEMM merged (M=NC, N=64, K=128)
__global__ __launch_bounds__(256) void gemm_pq64(const float* __restrict__ x,
                                                 const float* __restrict__ W1e,
                                                 float* __restrict__ Pb,
                                                 float* __restrict__ Qb) {
    __shared__ float As[16][64];
    __shared__ float Wsh[16][64];
    const int z = blockIdx.z;
    const int b = z >> 1, pq = z & 1;
    const int m0 = blockIdx.x * 64;
    const float* Ab = x + (size_t)b * NC * CIN;
    const float* W = W1e + pq * CIN * CH;
    float* Cb = (pq ? Qb : Pb) + (size_t)b * NC * CH;
    const int t = threadIdx.x;
    const int tx = t & 15, ty = t >> 4;
    const int lm = t >> 2, lk = (t & 3) << 2;
    const int wk = t >> 4, wng = (t & 15) << 2;
    float acc[4][4] = {};
    for (int k0 = 0; k0 < CIN; k0 += 16) {
        float4 av = *(const float4*)&Ab[(size_t)(m0 + lm) * CIN + k0 + lk];
        As[lk + 0][lm] = av.x; As[lk + 1][lm] = av.y;
        As[lk + 2][lm] = av.z; As[lk + 3][lm] = av.w;
        float4 wv = *(const float4*)&W[(size_t)(k0 + wk) * CH + wng];
        *(float4*)&Wsh[wk][wng] = wv;
        __syncthreads();
        #pragma unroll
        for (int k = 0; k < 16; ++k) {
            float4 a4 = *(const float4*)&As[k][ty << 2];
            float4 w4 = *(const float4*)&Wsh[k][tx << 2];
            float aa[4] = {a4.x, a4.y, a4.z, a4.w};
            float ww[4] = {w4.x, w4.y, w4.z, w4.w};
            #pragma unroll
            for (int i = 0; i < 4; ++i)
                #pragma unroll
                for (int j = 0; j < 4; ++j)
                    acc[i][j] = fmaf(aa[i], ww[j], acc[i][j]);
        }
        __syncthreads();
    }
    #pragma unroll
    for (int i = 0; i < 4; ++i) {
        int m = m0 + (ty << 2) + i;
        #pragma unroll
        for (int j = 0; j < 4; ++j)
            Cb[(size_t)m * CH + (tx << 2) + j] = acc[i][j];
    }
}

// ---------------------------------------------------------------- MFMA bf16 GEMM (fine path, N=128)
#define LDK 40
__global__ __launch_bounds__(256) void mfma_gemm(
    const ushort* __restrict__ A1, int K1, const ushort* __restrict__ A2, int K2,
    const ushort* __restrict__ Wt, int ldW, int kPQ, int npq,
    const float* __restrict__ bias, void* __restrict__ C0v, void* __restrict__ C1v,
    int flags, long sA1, long sA2, long sC) {
    __shared__ ushort As[128 * LDK];
    __shared__ ushort Wsm[128 * LDK];
    const int t = threadIdx.x;
    const int lane = t & 63, wid = t >> 6;
    const int wr = wid >> 1, wc = wid & 1;
    const int fr = lane & 15, fq = lane >> 4;
    const int sr = t >> 2, sk = (t & 3) * 8;
    const int z = blockIdx.z;
    const int b = z / npq, pq = z - b * npq;
    const int m0 = blockIdx.x * 128;
    const int wbase = pq * kPQ;

    f32x4 acc[4][4];
    #pragma unroll
    for (int m = 0; m < 4; ++m)
        #pragma unroll
        for (int n = 0; n < 4; ++n)
            acc[m][n] = (f32x4){0.f, 0.f, 0.f, 0.f};

    int kOff = 0;
    for (int s = 0; s < 2; ++s) {
        const ushort* A = (s == 0) ? A1 : A2;
        const int K = (s == 0) ? K1 : K2;
        const long sA = (s == 0) ? sA1 : sA2;
        if (A == nullptr || K == 0) continue;
        const ushort* Ab = A + (size_t)b * sA;
        for (int k0 = 0; k0 < K; k0 += 32) {
            #pragma unroll
            for (int p = 0; p < 2; ++p) {
                int r = sr + p * 64;
                *reinterpret_cast<int4*>(&As[r * LDK + sk]) =
                    *reinterpret_cast<const int4*>(&Ab[(size_t)(m0 + r) * K + k0 + sk]);
                *reinterpret_cast<int4*>(&Wsm[r * LDK + sk]) =
                    *reinterpret_cast<const int4*>(&Wt[(size_t)r * ldW + wbase + kOff + k0 + sk]);
            }
            __syncthreads();
            short8v af[4], wf[4];
            #pragma unroll
            for (int m = 0; m < 4; ++m)
                af[m] = *reinterpret_cast<const short8v*>(&As[(wr * 64 + m * 16 + fr) * LDK + fq * 8]);
            #pragma unroll
            for (int n = 0; n < 4; ++n)
                wf[n] = *reinterpret_cast<const short8v*>(&Wsm[(wc * 64 + n * 16 + fr) * LDK + fq * 8]);
            #pragma unroll
            for (int m = 0; m < 4; ++m)
                #pragma unroll
                for (int n = 0; n < 4; ++n)
                    acc[m][n] = __builtin_amdgcn_mfma_f32_16x16x32_bf16(af[m], wf[n], acc[m][n], 0, 0, 0);
            __syncthreads();
        }
        kOff += K;
    }

    void* Cv = (pq == 0) ? C0v : C1v;
    if (flags & 4) {
        ushort* Cb = (ushort*)Cv + (size_t)b * sC;
        #pragma unroll
        for (int m = 0; m < 4; ++m)
            #pragma unroll
            for (int n = 0; n < 4; ++n) {
                int col = wc * 64 + n * 16 + fr;
                #pragma unroll
                for (int r = 0; r < 4; ++r) {
                    int row = m0 + wr * 64 + m * 16 + fq * 4 + r;
                    Cb[(size_t)row * 128 + col] = f2b(acc[m][n][r]);
                }
            }
    } else {
        float* Cb = (float*)Cv + (size_t)b * sC;
        #pragma unroll
        for (int m = 0; m < 4; ++m)
            #pragma unroll
            for (int n = 0; n < 4; ++n) {
                int col = wc * 64 + n * 16 + fr;
                float bv = bias ? bias[col] : 0.0f;
                #pragma unroll
                for (int r = 0; r < 4; ++r) {
                    int row = m0 + wr * 64 + m * 16 + fq * 4 + r;
                    float v = acc[m][n][r] + bv;
                    if (flags & 1) v = v > 0.0f ? v : 0.01f * v;
                    float* cp = &Cb[(size_t)row * 128 + col];
                    if (flags & 2) v += *cp;
                    *cp = v;
                }
            }
    }
}

// ---------------------------------------------------------------- fine weight transpose+bf16: Wt[n][k] = bf16(W[k][n])
__global__ void conv_wt(const float* __restrict__ W2e, const float* __restrict__ W2n,
                        const float* __restrict__ Wse, const float* __restrict__ Wsn,
                        ushort* __restrict__ W2eT, ushort* __restrict__ W2nT,
                        ushort* __restrict__ WseT, ushort* __restrict__ WsnT) {
    const float* src; ushort* dst; int K2;
    switch (blockIdx.y) {
        case 0: src = W2e; dst = W2eT; K2 = 128; break;
        case 1: src = W2n; dst = W2nT; K2 = 192; break;
        case 2: src = Wse; dst = WseT; K2 = 256; break;
        default: src = Wsn; dst = WsnT; K2 = 256; break;
    }
    int id = blockIdx.x * 256 + threadIdx.x;
    if (id >= K2 * 128) return;
    int n = id & 127, k = id >> 7;
    dst[(size_t)n * K2 + k] = f2b(src[id]);
}

// ---------------------------------------------------------------- edge message + aggregate (coarse, f32, C=64)
__global__ __launch_bounds__(256) void agg_csr_f32(const float* __restrict__ P,
                                                   const float* __restrict__ Q,
                                                   const float* __restrict__ bias,
                                                   const int* __restrict__ offs,
                                                   const int* __restrict__ counts,
                                                   const int* __restrict__ csr_src,
                                                   float* __restrict__ agg,
                                                   int N, int E) {
    const int b = blockIdx.y;
    const int dst = blockIdx.x * 4 + (threadIdx.x >> 6);
    const int lane = threadIdx.x & 63;
    const float* Pb = P + (size_t)b * N * 64;
    const float* Qb = Q + (size_t)b * N * 64;
    const int start = offs[b * N + dst];
    const int cnt = counts[b * N + dst];
    const int* sl = csr_src + (size_t)b * E + start;
    const float q = Qb[(size_t)dst * 64 + lane] + bias[lane];
    float a = 0.0f;
    for (int i = 0; i < cnt; ++i) {
        int src = sl[i];
        float m = Pb[(size_t)src * 64 + lane] + q; m = m > 0.0f ? m : 0.01f * m;
        a += m;
    }
    agg[(size_t)b * N * 64 + (size_t)dst * 64 + lane] = a;
}

// ---------------------------------------------------------------- edge message + aggregate (fine, bf16 io, C=128)
__global__ __launch_bounds__(256) void agg_csr_b16(const ushort* __restrict__ P,
                                                   const ushort* __restrict__ Q,
                                                   const float* __restrict__ bias,
                                                   const int* __restrict__ offs,
                                                   const int* __restrict__ counts,
                                                   const int* __restrict__ csr_src,
                                                   ushort* __restrict__ agg,
                                                   int N, int E) {
    const int b = blockIdx.y;
    const int dst = blockIdx.x * 4 + (threadIdx.x >> 6);
    const int lane = threadIdx.x & 63;
    const ushort* Pb = P + (size_t)b * N * 128;
    const ushort* Qb = Q + (size_t)b * N * 128;
    const int start = offs[b * N + dst];
    const int cnt = counts[b * N + dst];
    const int* sl = csr_src + (size_t)b * E + start;
    const int c0 = lane, c1 = lane + 64;
    const float q0 = b2f(Qb[(size_t)dst * 128 + c0]) + bias[c0];
    const float q1 = b2f(Qb[(size_t)dst * 128 + c1]) + bias[c1];
    float a0 = 0.0f, a1 = 0.0f;
    for (int i = 0; i < cnt; ++i) {
        int src = sl[i];
        float m0 = b2f(Pb[(size_t)src * 128 + c0]) + q0; m0 = m0 > 0.0f ? m0 : 0.01f * m0;
        float m1 = b2f(Pb[(size_t)src * 128 + c1]) + q1; m1 = m1 > 0.0f ? m1 : 0.01f * m1;
        a0 += m0; a1 += m1;
    }
    agg[(size_t)b * N * 128 + (size_t)dst * 128 + c0] = f2b(a0);
    agg[(size_t)b * N * 128 + (size_t)dst * 128 + c1] = f2b(a1);
}

// ---------------------------------------------------------------- batch-norm
__global__ void bn_stats(const float* __restrict__ xs, float* __restrict__ stats) {
    const int c = threadIdx.x;
    long r0 = (long)blockIdx.x * 256;
    float s = 0.0f, s2 = 0.0f;
    for (int r = 0; r < 256; ++r) {
        float v = xs[(r0 + r) * COUT + c];
        s += v;
        s2 = fmaf(v, v, s2);
    }
    atomicAdd(&stats[c], s);
    atomicAdd(&stats[COUT + c], s2);
}

__global__ void bn_final(float* __restrict__ xs, const float* __restrict__ stats,
                         const float* __restrict__ gamma, const float* __restrict__ beta,
                         float* __restrict__ wf) {
    long g = (long)blockIdx.x * 256 + threadIdx.x;
    int c = (int)(g & (COUT - 1));
    const float invN = 1.0f / (float)(B * NF);
    float mu = stats[c] * invN;
    float var = stats[COUT + c] * invN - mu * mu;
    float v = (xs[g] - mu) * rsqrtf(var + 1e-5f) * gamma[c] + beta[c];
    xs[g] = v > 0.0f ? v : 0.01f * v;
    if (g < (long)B * NF) wf[g] = 0.0f;      // fold w_fine zeroing in
}

__global__ void wfine_scatter(const float* __restrict__ wts, const int* __restrict__ mask,
                              float* __restrict__ wf) {
    int i = blockIdx.x * 256 + threadIdx.x;
    int b = i / NC;
    wf[(size_t)b * NF + mask[i]] = wts[i];
}

extern "C" void kernel_launch(void* const* d_in, const int* in_sizes, int n_in,
                              void* d_out, int out_size, void* d_ws, size_t ws_size,
                              hipStream_t stream) {
    const float* x    = (const float*)d_in[0];
    const float* wts  = (const float*)d_in[1];
    const float* pos  = (const float*)d_in[2];
    const float* W1e  = (const float*)d_in[3];
    const float* b1e  = (const float*)d_in[4];
    const float* W1n  = (const float*)d_in[5];
    const float* b1n  = (const float*)d_in[6];
    const float* W2e  = (const float*)d_in[7];
    const float* b2e  = (const float*)d_in[8];
    const float* W2n  = (const float*)d_in[9];
    const float* b2n  = (const float*)d_in[10];
    const float* Wse  = (const float*)d_in[11];
    const float* bse  = (const float*)d_in[12];
    const float* Wsn  = (const float*)d_in[13];
    const float* bsn  = (const float*)d_in[14];
    const float* gamma= (const float*)d_in[15];
    const float* beta = (const float*)d_in[16];
    const int*   mask = (const int*)d_in[17];
    const int*   ec   = (const int*)d_in[18];
    const int*   ef   = (const int*)d_in[19];

    float* ws = (float*)d_ws;
    // ---- f32 region
    int*    idxb  = (int*)ws;                              // B*NF*3
    float*  wnb   = ws + 98304;                            // B*NF*3
    float4* sposg = (float4*)(ws + 196608);                // B*NC float4
    float*  x1    = ws + 196608 + 32768;                   // B*NC*CH
    float*  PbC   = x1  + (size_t)B * NC * CH;
    float*  QbC   = PbC + (size_t)B * NC * CH;
    float*  aggC  = QbC + (size_t)B * NC * CH;
    float*  stats = aggC+ (size_t)B * NC * CH;             // 256
    // ---- int region (counts contiguous for single memset)
    int* cntC = (int*)(stats + 256);                       // B*NC
    int* cntF = cntC + B * NC;                             // B*NF
    int* cntB = cntF + B * NF;                             // B*512
    int* offC = cntB + B * 512;                            // B*NC
    int* curC = offC + B * NC;
    int* offF = curC + B * NC;                             // B*NF
    int* curF = offF + B * NF;
    int* offB = curF + B * NF;                             // B*513
    int* curB = offB + B * 513;
    int* csrC = curB + B * 513;                            // B*EC
    int* csrF = csrC + B * EC;                             // B*EF
    // ---- bf16 region (32B aligned)
    size_t foff = (size_t)(csrF + (size_t)B * EF - (int*)ws);
    foff = (foff + 7) & ~(size_t)7;
    ushort* xupb  = (ushort*)(ws + foff);                  // B*NF*128
    ushort* x1upb = xupb  + (size_t)B * NF * 128;          // B*NF*64
    ushort* Pb    = x1upb + (size_t)B * NF * 64;           // B*NF*128
    ushort* Qb    = Pb    + (size_t)B * NF * 128;          // B*NF*128
    ushort* aggb  = Qb    + (size_t)B * NF * 128;          // B*NF*128
    ushort* W2eT  = aggb  + (size_t)B * NF * 128;          // 128*128
    ushort* W2nT  = W2eT  + 128 * 128;                     // 128*192
    ushort* WseT  = W2nT  + 128 * 192;                     // 128*256
    ushort* WsnT  = WseT  + 128 * 256;                     // 128*256

    float* y  = (float*)d_out;                             // B*NF*128
    float* wf = y + (size_t)B * NF * COUT;                 // B*NF

    // ---- prep: weights, counts (one memset), scans, fills
    conv_wt<<<dim3(128, 4), 256, 0, stream>>>(W2e, W2n, Wse, Wsn, W2eT, W2nT, WseT, WsnT);
    hipMemsetAsync(cntC, 0, (size_t)B * (NC + NF + 512) * 4, stream);
    count_all<<<dim3(EF / 256, B, 3), 256, 0, stream>>>(ec, ef, mask, pos, cntC, cntF, cntB);
    scan_all<<<dim3(3 * B), 1024, 0, stream>>>(cntC, offC, curC, cntF, offF, curF, cntB, offB, curB);
    fill_all<<<dim3(EF / 256, B, 3), 256, 0, stream>>>(ec, ef, mask, pos, curC, curF, curB,
                                                       csrC, csrF, sposg);

    // ---- knn (grid-binned exact ring search)
    knn_ring<<<dim3(NF / 256, B), 256, 0, stream>>>(pos, sposg, offB, idxb, wnb);

    // ---- x_up = interp(x) -> bf16
    interp_b16<<<dim3(NF, B), CIN, 0, stream>>>(x, idxb, wnb, xupb, CIN);

    // ---- main branch: mpl1 on coarse graph (f32 path)
    gemm_pq64<<<dim3(NC / 64, 1, B * 2), 256, 0, stream>>>(x, W1e, PbC, QbC);
    agg_csr_f32<<<dim3(NC / 4, B), 256, 0, stream>>>(
        PbC, QbC, b1e, offC, cntC, csrC, aggC, NC, EC);
    gemm_kernel<<<dim3(1, NC / 64, B), 256, 0, stream>>>(
        x, CIN, aggC, CH, W1n, b1n, x1, NC, CH, 1, (long)NC * CIN, (long)NC * CH, (long)NC * CH);

    // ---- x1_up = interp(x1) -> bf16
    interp_b16<<<dim3(NF, B), CH, 0, stream>>>(x1, idxb, wnb, x1upb, CH);

    // ---- mpl2 on fine graph (MFMA path)
    mfma_gemm<<<dim3(NF / 128, 1, B * 2), 256, 0, stream>>>(
        x1upb, CH, nullptr, 0, W2eT, 128, CH, 2, nullptr, Pb, Qb, 4,
        (long)NF * CH, 0, (long)NF * 128);
    agg_csr_b16<<<dim3(NF / 4, B), 256, 0, stream>>>(
        Pb, Qb, b2e, offF, cntF, csrF, aggb, NF, EF);
    mfma_gemm<<<dim3(NF / 128, 1, B), 256, 0, stream>>>(
        x1upb, CH, aggb, COUT, W2nT, 192, 0, 1, b2n, y, y, 1,
        (long)NF * CH, (long)NF * 128, (long)NF * 128);

    // ---- skip branch (MFMA path), accumulated into y
    mfma_gemm<<<dim3(NF / 128, 1, B * 2), 256, 0, stream>>>(
        xupb, CIN, nullptr, 0, WseT, 256, CIN, 2, nullptr, Pb, Qb, 4,
        (long)NF * CIN, 0, (long)NF * 128);
    agg_csr_b16<<<dim3(NF / 4, B), 256, 0, stream>>>(
        Pb, Qb, bse, offF, cntF, csrF, aggb, NF, EF);
    mfma_gemm<<<dim3(NF / 128, 1, B), 256, 0, stream>>>(
        xupb, CIN, aggb, COUT, WsnT, 256, 0, 1, bsn, y, y, 3,
        (long)NF * CIN, (long)NF * 128, (long)NF * 128);

    // ---- batch norm + lrelu (+ wf zero), then w_fine scatter
    hipMemsetAsync(stats, 0, 256 * 4, stream);
    bn_stats<<<dim3((B * NF) / 256), COUT, 0, stream>>>(y, stats);
    bn_final<<<dim3((long)B * NF * COUT / 256), 256, 0, stream>>>(y, stats, gamma, beta, wf);
    wfine_scatter<<<dim3(B * NC / 256), 256, 0, stream>>>(wts, mask, wf);
}

// Round 6
// 300.385 us; speedup vs baseline: 2.4856x; 1.0012x over previous
//
#include <hip/hip_runtime.h>
#include <hip/hip_bf16.h>
#include <cfloat>

#define B 4
#define NC 2048
#define NF 8192
#define CIN 128
#define CH 64
#define COUT 128
#define EC 16384
#define EF 65536

typedef __attribute__((ext_vector_type(8))) short short8v;
typedef __attribute__((ext_vector_type(4))) float f32x4;

__device__ __forceinline__ ushort f2b(float v) {
    __hip_bfloat16 h = __float2bfloat16(v);
    return *reinterpret_cast<ushort*>(&h);
}
__device__ __forceinline__ float b2f(ushort u) {
    __hip_bfloat16 h = *reinterpret_cast<__hip_bfloat16*>(&u);
    return __bfloat162float(h);
}

// ---------------------------------------------------------------- combined count: coarse hist / fine hist / coarse bins / fine bins
__global__ void count_all(const int* __restrict__ ec, const int* __restrict__ ef,
                          const int* __restrict__ mask, const float* __restrict__ pos,
                          int* __restrict__ cntC, int* __restrict__ cntF,
                          int* __restrict__ cntB, int* __restrict__ cntFB) {
    const int b = blockIdx.y, z = blockIdx.z;
    const int i = blockIdx.x * 256 + threadIdx.x;
    if (z == 0) {
        if (i < EC) atomicAdd(&cntC[b * NC + ec[(size_t)b * 2 * EC + EC + i]], 1);
    } else if (z == 1) {
        if (i < EF) atomicAdd(&cntF[b * NF + ef[(size_t)b * 2 * EF + EF + i]], 1);
    } else if (z == 2) {
        if (i < NC) {
            int m = mask[b * NC + i];
            const float* p = pos + ((size_t)b * NF + m) * 3;
            int cx = min(max((int)(p[0] * 8.0f), 0), 7);
            int cy = min(max((int)(p[1] * 8.0f), 0), 7);
            int cz = min(max((int)(p[2] * 8.0f), 0), 7);
            atomicAdd(&cntB[b * 512 + (cz * 8 + cy) * 8 + cx], 1);
        }
    } else {
        if (i < NF) {
            const float* p = pos + ((size_t)b * NF + i) * 3;
            int cx = min(max((int)(p[0] * 8.0f), 0), 7);
            int cy = min(max((int)(p[1] * 8.0f), 0), 7);
            int cz = min(max((int)(p[2] * 8.0f), 0), 7);
            atomicAdd(&cntFB[b * 512 + (cz * 8 + cy) * 8 + cx], 1);
        }
    }
}

// ---------------------------------------------------------------- combined exclusive scan (grid = 4*B blocks)
template<int N, int OSTR, bool EXTRA>
__device__ __forceinline__ void scan_body(const int* __restrict__ cnt, int* __restrict__ offs,
                                          int* __restrict__ cur, int b, int* part) {
    const int tid = threadIdx.x;
    constexpr int PER = (N + 1023) / 1024;
    int local[PER];
    int s = 0;
    #pragma unroll
    for (int i = 0; i < PER; ++i) {
        int id = tid * PER + i;
        local[i] = s;
        if (id < N) s += cnt[b * N + id];
    }
    part[tid] = s;
    __syncthreads();
    for (int off = 1; off < 1024; off <<= 1) {
        int v = (tid >= off) ? part[tid - off] : 0;
        __syncthreads();
        part[tid] += v;
        __syncthreads();
    }
    int pre = tid ? part[tid - 1] : 0;
    #pragma unroll
    for (int i = 0; i < PER; ++i) {
        int id = tid * PER + i;
        if (id < N) {
            int o = pre + local[i];
            offs[b * OSTR + id] = o;
            cur[b * OSTR + id] = o;
        }
    }
    if (EXTRA && tid == 1023) offs[b * OSTR + N] = part[1023];
}

__global__ __launch_bounds__(1024) void scan_all(
    const int* __restrict__ cntC, int* __restrict__ offC, int* __restrict__ curC,
    const int* __restrict__ cntF, int* __restrict__ offF, int* __restrict__ curF,
    const int* __restrict__ cntB, int* __restrict__ offB, int* __restrict__ curB,
    const int* __restrict__ cntFB, int* __restrict__ offFB, int* __restrict__ curFB) {
    __shared__ int part[1024];
    const int cfg = blockIdx.x >> 2;   // B == 4
    const int b = blockIdx.x & 3;
    if (cfg == 0)      scan_body<NC, NC, false>(cntC, offC, curC, b, part);
    else if (cfg == 1) scan_body<NF, NF, false>(cntF, offF, curF, b, part);
    else if (cfg == 2) scan_body<512, 513, true>(cntB, offB, curB, b, part);
    else               scan_body<512, 513, true>(cntFB, offFB, curFB, b, part);
}

// ---------------------------------------------------------------- combined fill: CSRs / coarse bin positions / fine bin ids
__global__ void fill_all(const int* __restrict__ ec, const int* __restrict__ ef,
                         const int* __restrict__ mask, const float* __restrict__ pos,
                         int* __restrict__ curC, int* __restrict__ curF,
                         int* __restrict__ curB, int* __restrict__ curFB,
                         int* __restrict__ csrC, int* __restrict__ csrF,
                         float4* __restrict__ sposg, int* __restrict__ binF) {
    const int b = blockIdx.y, z = blockIdx.z;
    const int i = blockIdx.x * 256 + threadIdx.x;
    if (z == 0) {
        if (i < EC) {
            const int* eb = ec + (size_t)b * 2 * EC;
            int src = eb[i], dst = eb[EC + i];
            int p = atomicAdd(&curC[b * NC + dst], 1);
            csrC[(size_t)b * EC + p] = src;
        }
    } else if (z == 1) {
        if (i < EF) {
            const int* eb = ef + (size_t)b * 2 * EF;
            int src = eb[i], dst = eb[EF + i];
            int p = atomicAdd(&curF[b * NF + dst], 1);
            csrF[(size_t)b * EF + p] = src;
        }
    } else if (z == 2) {
        if (i < NC) {
            int m = mask[b * NC + i];
            const float* p = pos + ((size_t)b * NF + m) * 3;
            float px = p[0], py = p[1], pz = p[2];
            int cx = min(max((int)(px * 8.0f), 0), 7);
            int cy = min(max((int)(py * 8.0f), 0), 7);
            int cz = min(max((int)(pz * 8.0f), 0), 7);
            int slot = atomicAdd(&curB[b * 513 + (cz * 8 + cy) * 8 + cx], 1);
            sposg[(size_t)b * NC + slot] = make_float4(px, py, pz, __int_as_float(i));
        }
    } else {
        if (i < NF) {
            const float* p = pos + ((size_t)b * NF + i) * 3;
            int cx = min(max((int)(p[0] * 8.0f), 0), 7);
            int cy = min(max((int)(p[1] * 8.0f), 0), 7);
            int cz = min(max((int)(p[2] * 8.0f), 0), 7);
            int slot = atomicAdd(&curFB[b * 513 + (cz * 8 + cy) * 8 + cx], 1);
            binF[(size_t)b * NF + slot] = i;
        }
    }
}

// ---------------------------------------------------------------- top-3 insert / 8-lane merge helpers
__device__ __forceinline__ void ins3(float d, int c, float& d0, float& d1, float& d2,
                                     int& i0, int& i1, int& i2) {
    bool lt0 = d < d0, lt1 = d < d1, lt2 = d < d2;
    d2 = lt1 ? d1 : (lt2 ? d : d2);  i2 = lt1 ? i1 : (lt2 ? c : i2);
    d1 = lt0 ? d0 : (lt1 ? d : d1);  i1 = lt0 ? i0 : (lt1 ? c : i1);
    d0 = lt0 ? d  : d0;              i0 = lt0 ? c  : i0;
}
__device__ __forceinline__ void merge8(float& d0, float& d1, float& d2,
                                       int& i0, int& i1, int& i2) {
    #pragma unroll
    for (int off = 1; off <= 4; off <<= 1) {
        float od[3]; int oi[3];
        od[0] = __shfl_xor(d0, off); oi[0] = __shfl_xor(i0, off);
        od[1] = __shfl_xor(d1, off); oi[1] = __shfl_xor(i1, off);
        od[2] = __shfl_xor(d2, off); oi[2] = __shfl_xor(i2, off);
        #pragma unroll
        for (int j = 0; j < 3; ++j) ins3(od[j], oi[j], d0, d1, d2, i0, i1, i2);
    }
}

// ---------------------------------------------------------------- knn: bin-sorted nodes, 8 lanes/node, 27-cell scan + exact bound
__global__ __launch_bounds__(256) void knn_cell8(const float* __restrict__ pos,
                                                 const float4* __restrict__ sposg,
                                                 const int* __restrict__ offB,
                                                 const int* __restrict__ binF,
                                                 int* __restrict__ idx,
                                                 float* __restrict__ wn) {
    const int b = blockIdx.y;
    const int tid = threadIdx.x;
    const int i = blockIdx.x * 32 + (tid >> 3);
    const int lane8 = tid & 7;
    const int f = binF[(size_t)b * NF + i];
    const float* pf = pos + ((size_t)b * NF + f) * 3;
    const float px = pf[0], py = pf[1], pz = pf[2];
    const int cx = min(max((int)(px * 8.0f), 0), 7);
    const int cy = min(max((int)(py * 8.0f), 0), 7);
    const int cz = min(max((int)(pz * 8.0f), 0), 7);
    const float4* sp = sposg + (size_t)b * NC;
    const int* cs = offB + b * 513;
    float d0 = FLT_MAX, d1 = FLT_MAX, d2 = FLT_MAX;
    int i0 = 0, i1 = 0, i2 = 0;
    for (int k = lane8; k < 27; k += 8) {
        int zz = cz + k / 9 - 1;
        int yy = cy + (k / 3) % 3 - 1;
        int xx = cx + k % 3 - 1;
        if ((unsigned)xx > 7u || (unsigned)yy > 7u || (unsigned)zz > 7u) continue;
        int cell = (zz * 8 + yy) * 8 + xx;
        int j1 = cs[cell + 1];
        for (int j = cs[cell]; j < j1; ++j) {
            float4 s = sp[j];
            // match numpy: diff, square, sequential sum — no FMA contraction
            float ddx = __fsub_rn(px, s.x);
            float ddy = __fsub_rn(py, s.y);
            float ddz = __fsub_rn(pz, s.z);
            float d = __fadd_rn(__fadd_rn(__fmul_rn(ddx, ddx), __fmul_rn(ddy, ddy)),
                                __fmul_rn(ddz, ddz));
            ins3(d, __float_as_int(s.w), d0, d1, d2, i0, i1, i2);
        }
    }
    merge8(d0, d1, d2, i0, i1, i2);
    // exact bound: nearest possible unsearched point (interior faces of the 3x3x3 box)
    float bd = 1e30f;
    if (cx - 1 > 0) bd = fminf(bd, px - (float)(cx - 1) * 0.125f);
    if (cx + 2 < 8) bd = fminf(bd, (float)(cx + 2) * 0.125f - px);
    if (cy - 1 > 0) bd = fminf(bd, py - (float)(cy - 1) * 0.125f);
    if (cy + 2 < 8) bd = fminf(bd, (float)(cy + 2) * 0.125f - py);
    if (cz - 1 > 0) bd = fminf(bd, pz - (float)(cz - 1) * 0.125f);
    if (cz + 2 < 8) bd = fminf(bd, (float)(cz + 2) * 0.125f - pz);
    bd *= 0.9999f;   // absorb f32 rounding in the bound
    if (__any(d2 > bd * bd)) {
        // rare: wave-coherent exact full rescan
        d0 = d1 = d2 = FLT_MAX; i0 = i1 = i2 = 0;
        for (int j = lane8; j < NC; j += 8) {
            float4 s = sp[j];
            float ddx = __fsub_rn(px, s.x);
            float ddy = __fsub_rn(py, s.y);
            float ddz = __fsub_rn(pz, s.z);
            float d = __fadd_rn(__fadd_rn(__fmul_rn(ddx, ddx), __fmul_rn(ddy, ddy)),
                                __fmul_rn(ddz, ddz));
            ins3(d, __float_as_int(s.w), d0, d1, d2, i0, i1, i2);
        }
        merge8(d0, d1, d2, i0, i1, i2);
    }
    if (lane8 == 0) {
        float w0 = 1.0f / (d0 + 1e-16f);
        float w1 = 1.0f / (d1 + 1e-16f);
        float w2 = 1.0f / (d2 + 1e-16f);
        float inv = 1.0f / (w0 + w1 + w2);
        size_t o = ((size_t)b * NF + f) * 3;
        idx[o] = i0; idx[o + 1] = i1; idx[o + 2] = i2;
        wn[o] = w0 * inv; wn[o + 1] = w1 * inv; wn[o + 2] = w2 * inv;
    }
}

// ---------------------------------------------------------------- weighted 3-NN gather, bf16 out
__global__ void interp_b16(const float* __restrict__ xc, const int* __restrict__ idx,
                           const float* __restrict__ wn, ushort* __restrict__ out, int C) {
    const int b = blockIdx.y, f = blockIdx.x, c = threadIdx.x;
    size_t o = ((size_t)b * NF + f) * 3;
    int i0 = idx[o], i1 = idx[o + 1], i2 = idx[o + 2];
    float w0 = wn[o], w1 = wn[o + 1], w2 = wn[o + 2];
    const float* xb = xc + (size_t)b * NC * C;
    float v = w0 * xb[(size_t)i0 * C + c] + w1 * xb[(size_t)i1 * C + c] + w2 * xb[(size_t)i2 * C + c];
    out[((size_t)b * NF + f) * C + c] = f2b(v);
}

// ---------------------------------------------------------------- f32 GEMM (coarse node MLP)
__global__ __launch_bounds__(256) void gemm_kernel(
    const float* __restrict__ A1, int K1, const float* __restrict__ A2, int K2,
    const float* __restrict__ W, const float* __restrict__ bias,
    float* __restrict__ Cmat, int M, int N, int flags,
    long sA1, long sA2, long sC) {
    __shared__ float As[16][64];
    __shared__ float Wsh[16][64];
    const int b = blockIdx.z;
    const int m0 = blockIdx.y * 64, n0 = blockIdx.x * 64;
    const int t = threadIdx.x;
    const int tx = t & 15, ty = t >> 4;
    float acc[4][4] = {};
    int kOff = 0;
    for (int s = 0; s < 2; ++s) {
        const float* A = (s == 0) ? A1 : A2;
        const int K = (s == 0) ? K1 : K2;
        const long sA = (s == 0) ? sA1 : sA2;
        if (A == nullptr || K == 0) continue;
        const float* Ab = A + (size_t)b * sA;
        const int lm = t >> 2;
        const int lk = (t & 3) << 2;
        const int wk = t >> 4;
        const int wng = (t & 15) << 2;
        for (int k0 = 0; k0 < K; k0 += 16) {
            float4 av = *(const float4*)&Ab[(size_t)(m0 + lm) * K + k0 + lk];
            As[lk + 0][lm] = av.x; As[lk + 1][lm] = av.y;
            As[lk + 2][lm] = av.z; As[lk + 3][lm] = av.w;
            float4 wv = *(const float4*)&W[(size_t)(kOff + k0 + wk) * N + n0 + wng];
            *(float4*)&Wsh[wk][wng] = wv;
            __syncthreads();
            #pragma unroll
            for (int k = 0; k < 16; ++k) {
                float4 a4 = *(const float4*)&As[k][ty << 2];
                float4 w4 = *(const float4*)&Wsh[k][tx << 2];
                float aa[4] = {a4.x, a4.y, a4.z, a4.w};
                float ww[4] = {w4.x, w4.y, w4.z, w4.w};
                #pragma unroll
                for (int i = 0; i < 4; ++i)
                    #pragma unroll
                    for (int j = 0; j < 4; ++j)
                        acc[i][j] = fmaf(aa[i], ww[j], acc[i][j]);
            }
            __syncthreads();
        }
        kOff += K;
    }
    float* Cb = Cmat + (size_t)b * sC;
    #pragma unroll
    for (int i = 0; i < 4; ++i) {
        int m = m0 + (ty << 2) + i;
        #pragma unroll
        for (int j = 0; j < 4; ++j) {
            int n = n0 + (tx << 2) + j;
            float v = acc[i][j];
            if (bias) v += bias[n];
            if (flags & 1) v = v > 0.0f ? v : 0.01f * v;
            float* cp = &Cb[(size_t)m * N + n];
            if (flags & 2) v += *cp;
            *cp = v;
        }
    }
}

// ---------------------------------------------------------------- coarse P/Q GEMM merged (M=NC, N=64, K=128)
__global__ __launch_bounds__(256) void gemm_pq64(const float* __restrict__ x,
                                                 const float* __restrict__ W1e,
                                                 float* __restrict__ Pb,
                                                 float* __restrict__ Qb) {
    __shared__ float As[16][64];
    __shared__ float Wsh[16][64];
    const int z = blockIdx.z;
    const int b = z >> 1, pq = z & 1;
    const int m0 = blockIdx.x * 64;
    const float* Ab = x + (size_t)b * NC * CIN;
    const float* W = W1e + pq * CIN * CH;
    float* Cb = (pq ? Qb : Pb) + (size_t)b * NC * CH;
    const int t = threadIdx.x;
    const int tx = t & 15, ty = t >> 4;
    const int lm = t >> 2, lk = (t & 3) << 2;
    const int wk = t >> 4, wng = (t & 15) << 2;
    float acc[4][4] = {};
    for (int k0 = 0; k0 < CIN; k0 += 16) {
        float4 av = *(const float4*)&Ab[(size_t)(m0 + lm) * CIN + k0 + lk];
        As[lk + 0][lm] = av.x; As[lk + 1][lm] = av.y;
        As[lk + 2][lm] = av.z; As[lk + 3][lm] = av.w;
        float4 wv = *(const float4*)&W[(size_t)(k0 + wk) * CH + wng];
        *(float4*)&Wsh[wk][wng] = wv;
        __syncthreads();
        #pragma unroll
        for (int k = 0; k < 16; ++k) {
            float4 a4 = *(const float4*)&As[k][ty << 2];
            float4 w4 = *(const float4*)&Wsh[k][tx << 2];
            float aa[4] = {a4.x, a4.y, a4.z, a4.w};
            float ww[4] = {w4.x, w4.y, w4.z, w4.w};
            #pragma unroll
            for (int i = 0; i < 4; ++i)
                #pragma unroll
                for (int j = 0; j < 4; ++j)
                    acc[i][j] = fmaf(aa[i], ww[j], acc[i][j]);
        }
        __syncthreads();
    }
    #pragma unroll
    for (int i = 0; i < 4; ++i) {
        int m = m0 + (ty << 2) + i;
        #pragma unroll
        for (int j = 0; j < 4; ++j)
            Cb[(size_t)m * CH + (tx << 2) + j] = acc[i][j];
    }
}

// ---------------------------------------------------------------- MFMA bf16 GEMM (fine path, N=128)
#define LDK 40
__global__ __launch_bounds__(256) void mfma_gemm(
    const ushort* __restrict__ A1, int K1, const ushort* __restrict__ A2, int K2,
    const ushort* __restrict__ Wt, int ldW, int kPQ, int npq,
    const float* __restrict__ bias, void* __restrict__ C0v, void* __restrict__ C1v,
    int flags, long sA1, long sA2, long sC) {
    __shared__ ushort As[128 * LDK];
    __shared__ ushort Wsm[128 * LDK];
    const int t = threadIdx.x;
    const int lane = t & 63, wid = t >> 6;
    const int wr = wid >> 1, wc = wid & 1;
    const int fr = lane & 15, fq = lane >> 4;
    const int sr = t >> 2, sk = (t & 3) * 8;
    const int z = blockIdx.z;
    const int b = z / npq, pq = z - b * npq;
    const int m0 = blockIdx.x * 128;
    const int wbase = pq * kPQ;

    f32x4 acc[4][4];
    #pragma unroll
    for (int m = 0; m < 4; ++m)
        #pragma unroll
        for (int n = 0; n < 4; ++n)
            acc[m][n] = (f32x4){0.f, 0.f, 0.f, 0.f};

    int kOff = 0;
    for (int s = 0; s < 2; ++s) {
        const ushort* A = (s == 0) ? A1 : A2;
        const int K = (s == 0) ? K1 : K2;
        const long sA = (s == 0) ? sA1 : sA2;
        if (A == nullptr || K == 0) continue;
        const ushort* Ab = A + (size_t)b * sA;
        for (int k0 = 0; k0 < K; k0 += 32) {
            #pragma unroll
            for (int p = 0; p < 2; ++p) {
                int r = sr + p * 64;
                *reinterpret_cast<int4*>(&As[r * LDK + sk]) =
                    *reinterpret_cast<const int4*>(&Ab[(size_t)(m0 + r) * K + k0 + sk]);
                *reinterpret_cast<int4*>(&Wsm[r * LDK + sk]) =
                    *reinterpret_cast<const int4*>(&Wt[(size_t)r * ldW + wbase + kOff + k0 + sk]);
            }
            __syncthreads();
            short8v af[4], wf[4];
            #pragma unroll
            for (int m = 0; m < 4; ++m)
                af[m] = *reinterpret_cast<const short8v*>(&As[(wr * 64 + m * 16 + fr) * LDK + fq * 8]);
            #pragma unroll
            for (int n = 0; n < 4; ++n)
                wf[n] = *reinterpret_cast<const short8v*>(&Wsm[(wc * 64 + n * 16 + fr) * LDK + fq * 8]);
            #pragma unroll
            for (int m = 0; m < 4; ++m)
                #pragma unroll
                for (int n = 0; n < 4; ++n)
                    acc[m][n] = __builtin_amdgcn_mfma_f32_16x16x32_bf16(af[m], wf[n], acc[m][n], 0, 0, 0);
            __syncthreads();
        }
        kOff += K;
    }

    void* Cv = (pq == 0) ? C0v : C1v;
    if (flags & 4) {
        ushort* Cb = (ushort*)Cv + (size_t)b * sC;
        #pragma unroll
        for (int m = 0; m < 4; ++m)
            #pragma unroll
            for (int n = 0; n < 4; ++n) {
                int col = wc * 64 + n * 16 + fr;
                #pragma unroll
                for (int r = 0; r < 4; ++r) {
                    int row = m0 + wr * 64 + m * 16 + fq * 4 + r;
                    Cb[(size_t)row * 128 + col] = f2b(acc[m][n][r]);
                }
            }
    } else {
        float* Cb = (float*)Cv + (size_t)b * sC;
        #pragma unroll
        for (int m = 0; m < 4; ++m)
            #pragma unroll
            for (int n = 0; n < 4; ++n) {
                int col = wc * 64 + n * 16 + fr;
                float bv = bias ? bias[col] : 0.0f;
                #pragma unroll
                for (int r = 0; r < 4; ++r) {
                    int row = m0 + wr * 64 + m * 16 + fq * 4 + r;
                    float v = acc[m][n][r] + bv;
                    if (flags & 1) v = v > 0.0f ? v : 0.01f * v;
                    float* cp = &Cb[(size_t)row * 128 + col];
                    if (flags & 2) v += *cp;
                    *cp = v;
                }
            }
    }
}

// ---------------------------------------------------------------- fine weight transpose+bf16: Wt[n][k] = bf16(W[k][n])
__global__ void conv_wt(const float* __restrict__ W2e, const float* __restrict__ W2n,
                        const float* __restrict__ Wse, const float* __restrict__ Wsn,
                        ushort* __restrict__ W2eT, ushort* __restrict__ W2nT,
                        ushort* __restrict__ WseT, ushort* __restrict__ WsnT) {
    const float* src; ushort* dst; int K2;
    switch (blockIdx.y) {
        case 0: src = W2e; dst = W2eT; K2 = 128; break;
        case 1: src = W2n; dst = W2nT; K2 = 192; break;
        case 2: src = Wse; dst = WseT; K2 = 256; break;
        default: src = Wsn; dst = WsnT; K2 = 256; break;
    }
    int id = blockIdx.x * 256 + threadIdx.x;
    if (id >= K2 * 128) return;
    int n = id & 127, k = id >> 7;
    dst[(size_t)n * K2 + k] = f2b(src[id]);
}

// ---------------------------------------------------------------- edge message + aggregate (coarse, f32, C=64)
__global__ __launch_bounds__(256) void agg_csr_f32(const float* __restrict__ P,
                                                   const float* __restrict__ Q,
                                                   const float* __restrict__ bias,
                                                   const int* __restrict__ offs,
                                                   const int* __restrict__ counts,
                                                   const int* __restrict__ csr_src,
                                                   float* __restrict__ agg,
                                                   int N, int E) {
    const int b = blockIdx.y;
    const int dst = blockIdx.x * 4 + (threadIdx.x >> 6);
    const int lane = threadIdx.x & 63;
    const float* Pb = P + (size_t)b * N * 64;
    const float* Qb = Q + (size_t)b * N * 64;
    const int start = offs[b * N + dst];
    const int cnt = counts[b * N + dst];
    const int* sl = csr_src + (size_t)b * E + start;
    const float q = Qb[(size_t)dst * 64 + lane] + bias[lane];
    float a = 0.0f;
    for (int i = 0; i < cnt; ++i) {
        int src = sl[i];
        float m = Pb[(size_t)src * 64 + lane] + q; m = m > 0.0f ? m : 0.01f * m;
        a += m;
    }
    agg[(size_t)b * N * 64 + (size_t)dst * 64 + lane] = a;
}

// ---------------------------------------------------------------- edge message + aggregate (fine, bf16 io, C=128)
__global__ __launch_bounds__(256) void agg_csr_b16(const ushort* __restrict__ P,
                                                   const ushort* __restrict__ Q,
                                                   const float* __restrict__ bias,
                                                   const int* __restrict__ offs,
                                                   const int* __restrict__ counts,
                                                   const int* __restrict__ csr_src,
                                                   ushort* __restrict__ agg,
                                                   int N, int E) {
    const int b = blockIdx.y;
    const int dst = blockIdx.x * 4 + (threadIdx.x >> 6);
    const int lane = threadIdx.x & 63;
    const ushort* Pb = P + (size_t)b * N * 128;
    const ushort* Qb = Q + (size_t)b * N * 128;
    const int start = offs[b * N + dst];
    const int cnt = counts[b * N + dst];
    const int* sl = csr_src + (size_t)b * E + start;
    const int c0 = lane, c1 = lane + 64;
    const float q0 = b2f(Qb[(size_t)dst * 128 + c0]) + bias[c0];
    const float q1 = b2f(Qb[(size_t)dst * 128 + c1]) + bias[c1];
    float a0 = 0.0f, a1 = 0.0f;
    for (int i = 0; i < cnt; ++i) {
        int src = sl[i];
        float m0 = b2f(Pb[(size_t)src * 128 + c0]) + q0; m0 = m0 > 0.0f ? m0 : 0.01f * m0;
        float m1 = b2f(Pb[(size_t)src * 128 + c1]) + q1; m1 = m1 > 0.0f ? m1 : 0.01f * m1;
        a0 += m0; a1 += m1;
    }
    agg[(size_t)b * N * 128 + (size_t)dst * 128 + c0] = f2b(a0);
    agg[(size_t)b * N * 128 + (size_t)dst * 128 + c1] = f2b(a1);
}

// ---------------------------------------------------------------- batch-norm
__global__ void bn_stats(const float* __restrict__ xs, float* __restrict__ stats) {
    const int c = threadIdx.x;
    long r0 = (long)blockIdx.x * 256;
    float s = 0.0f, s2 = 0.0f;
    for (int r = 0; r < 256; ++r) {
        float v = xs[(r0 + r) * COUT + c];
        s += v;
        s2 = fmaf(v, v, s2);
    }
    atomicAdd(&stats[c], s);
    atomicAdd(&stats[COUT + c], s2);
}

__global__ void bn_final(float* __restrict__ xs, const float* __restrict__ stats,
                         const float* __restrict__ gamma, const float* __restrict__ beta,
                         float* __restrict__ wf) {
    long g = (long)blockIdx.x * 256 + threadIdx.x;
    int c = (int)(g & (COUT - 1));
    const float invN = 1.0f / (float)(B * NF);
    float mu = stats[c] * invN;
    float var = stats[COUT + c] * invN - mu * mu;
    float v = (xs[g] - mu) * rsqrtf(var + 1e-5f) * gamma[c] + beta[c];
    xs[g] = v > 0.0f ? v : 0.01f * v;
    if (g < (long)B * NF) wf[g] = 0.0f;      // fold w_fine zeroing in
}

__global__ void wfine_scatter(const float* __restrict__ wts, const int* __restrict__ mask,
                              float* __restrict__ wf) {
    int i = blockIdx.x * 256 + threadIdx.x;
    int b = i / NC;
    wf[(size_t)b * NF + mask[i]] = wts[i];
}

extern "C" void kernel_launch(void* const* d_in, const int* in_sizes, int n_in,
                              void* d_out, int out_size, void* d_ws, size_t ws_size,
                              hipStream_t stream) {
    const float* x    = (const float*)d_in[0];
    const float* wts  = (const float*)d_in[1];
    const float* pos  = (const float*)d_in[2];
    const float* W1e  = (const float*)d_in[3];
    const float* b1e  = (const float*)d_in[4];
    const float* W1n  = (const float*)d_in[5];
    const float* b1n  = (const float*)d_in[6];
    const float* W2e  = (const float*)d_in[7];
    const float* b2e  = (const float*)d_in[8];
    const float* W2n  = (const float*)d_in[9];
    const float* b2n  = (const float*)d_in[10];
    const float* Wse  = (const float*)d_in[11];
    const float* bse  = (const float*)d_in[12];
    const float* Wsn  = (const float*)d_in[13];
    const float* bsn  = (const float*)d_in[14];
    const float* gamma= (const float*)d_in[15];
    const float* beta = (const float*)d_in[16];
    const int*   mask = (const int*)d_in[17];
    const int*   ec   = (const int*)d_in[18];
    const int*   ef   = (const int*)d_in[19];

    float* ws = (float*)d_ws;
    // ---- f32 region
    int*    idxb  = (int*)ws;                              // B*NF*3
    float*  wnb   = ws + 98304;                            // B*NF*3
    float4* sposg = (float4*)(ws + 196608);                // B*NC float4
    float*  x1    = ws + 196608 + 32768;                   // B*NC*CH
    float*  PbC   = x1  + (size_t)B * NC * CH;
    float*  QbC   = PbC + (size_t)B * NC * CH;
    float*  aggC  = QbC + (size_t)B * NC * CH;
    float*  stats = aggC+ (size_t)B * NC * CH;             // 256
    // ---- int region (counts contiguous for single memset)
    int* cntC  = (int*)(stats + 256);                      // B*NC
    int* cntF  = cntC + B * NC;                            // B*NF
    int* cntB  = cntF + B * NF;                            // B*512
    int* cntFB = cntB + B * 512;                           // B*512
    int* offC  = cntFB + B * 512;                          // B*NC
    int* curC  = offC + B * NC;
    int* offF  = curC + B * NC;                            // B*NF
    int* curF  = offF + B * NF;
    int* offB  = curF + B * NF;                            // B*513
    int* curB  = offB + B * 513;
    int* offFB = curB + B * 513;                           // B*513
    int* curFB = offFB + B * 513;
    int* csrC  = curFB + B * 513;                          // B*EC
    int* csrF  = csrC + B * EC;                            // B*EF
    int* binF  = csrF + B * EF;                            // B*NF
    // ---- bf16 region (32B aligned)
    size_t foff = (size_t)(binF + (size_t)B * NF - (int*)ws);
    foff = (foff + 7) & ~(size_t)7;
    ushort* xupb  = (ushort*)(ws + foff);                  // B*NF*128
    ushort* x1upb = xupb  + (size_t)B * NF * 128;          // B*NF*64
    ushort* Pb    = x1upb + (size_t)B * NF * 64;           // B*NF*128
    ushort* Qb    = Pb    + (size_t)B * NF * 128;          // B*NF*128
    ushort* aggb  = Qb    + (size_t)B * NF * 128;          // B*NF*128
    ushort* W2eT  = aggb  + (size_t)B * NF * 128;          // 128*128
    ushort* W2nT  = W2eT  + 128 * 128;                     // 128*192
    ushort* WseT  = W2nT  + 128 * 192;                     // 128*256
    ushort* WsnT  = WseT  + 128 * 256;                     // 128*256

    float* y  = (float*)d_out;                             // B*NF*128
    float* wf = y + (size_t)B * NF * COUT;                 // B*NF

    // ---- prep: weights, counts (one memset), scans, fills
    conv_wt<<<dim3(128, 4), 256, 0, stream>>>(W2e, W2n, Wse, Wsn, W2eT, W2nT, WseT, WsnT);
    hipMemsetAsync(cntC, 0, (size_t)B * (NC + NF + 512 + 512) * 4, stream);
    count_all<<<dim3(EF / 256, B, 4), 256, 0, stream>>>(ec, ef, mask, pos, cntC, cntF, cntB, cntFB);
    scan_all<<<dim3(4 * B), 1024, 0, stream>>>(cntC, offC, curC, cntF, offF, curF,
                                               cntB, offB, curB, cntFB, offFB, curFB);
    fill_all<<<dim3(EF / 256, B, 4), 256, 0, stream>>>(ec, ef, mask, pos, curC, curF, curB, curFB,
                                                       csrC, csrF, sposg, binF);

    // ---- knn (bin-sorted, 8 lanes/node, exact)
    knn_cell8<<<dim3(NF / 32, B), 256, 0, stream>>>(pos, sposg, offB, binF, idxb, wnb);

    // ---- x_up = interp(x) -> bf16
    interp_b16<<<dim3(NF, B), CIN, 0, stream>>>(x, idxb, wnb, xupb, CIN);

    // ---- main branch: mpl1 on coarse graph (f32 path)
    gemm_pq64<<<dim3(NC / 64, 1, B * 2), 256, 0, stream>>>(x, W1e, PbC, QbC);
    agg_csr_f32<<<dim3(NC / 4, B), 256, 0, stream>>>(
        PbC, QbC, b1e, offC, cntC, csrC, aggC, NC, EC);
    gemm_kernel<<<dim3(1, NC / 64, B), 256, 0, stream>>>(
        x, CIN, aggC, CH, W1n, b1n, x1, NC, CH, 1, (long)NC * CIN, (long)NC * CH, (long)NC * CH);

    // ---- x1_up = interp(x1) -> bf16
    interp_b16<<<dim3(NF, B), CH, 0, stream>>>(x1, idxb, wnb, x1upb, CH);

    // ---- mpl2 on fine graph (MFMA path)
    mfma_gemm<<<dim3(NF / 128, 1, B * 2), 256, 0, stream>>>(
        x1upb, CH, nullptr, 0, W2eT, 128, CH, 2, nullptr, Pb, Qb, 4,
        (long)NF * CH, 0, (long)NF * 128);
    agg_csr_b16<<<dim3(NF / 4, B), 256, 0, stream>>>(
        Pb, Qb, b2e, offF, cntF, csrF, aggb, NF, EF);
    mfma_gemm<<<dim3(NF / 128, 1, B), 256, 0, stream>>>(
        x1upb, CH, aggb, COUT, W2nT, 192, 0, 1, b2n, y, y, 1,
        (long)NF * CH, (long)NF * 128, (long)NF * 128);

    // ---- skip branch (MFMA path), accumulated into y
    mfma_gemm<<<dim3(NF / 128, 1, B * 2), 256, 0, stream>>>(
        xupb, CIN, nullptr, 0, WseT, 256, CIN, 2, nullptr, Pb, Qb, 4,
        (long)NF * CIN, 0, (long)NF * 128);
    agg_csr_b16<<<dim3(NF / 4, B), 256, 0, stream>>>(
        Pb, Qb, bse, offF, cntF, csrF, aggb, NF, EF);
    mfma_gemm<<<dim3(NF / 128, 1, B), 256, 0, stream>>>(
        xupb, CIN, aggb, COUT, WsnT, 256, 0, 1, bsn, y, y, 3,
        (long)NF * CIN, (long)NF * 128, (long)NF * 128);

    // ---- batch norm + lrelu (+ wf zero), then w_fine scatter
    hipMemsetAsync(stats, 0, 256 * 4, stream);
    bn_stats<<<dim3((B * NF) / 256), COUT, 0, stream>>>(y, stats);
    bn_final<<<dim3((long)B * NF * COUT / 256), 256, 0, stream>>>(y, stats, gamma, beta, wf);
    wfine_scatter<<<dim3(B * NC / 256), 256, 0, stream>>>(wts, mask, wf);
}

// Round 7
// 280.592 us; speedup vs baseline: 2.6610x; 1.0705x over previous
//
#include <hip/hip_runtime.h>
#include <hip/hip_bf16.h>
#include <cfloat>

#define B 4
#define NC 2048
#define NF 8192
#define CIN 128
#define CH 64
#define COUT 128
#define EC 16384
#define EF 65536

typedef __attribute__((ext_vector_type(8))) short short8v;
typedef __attribute__((ext_vector_type(4))) float f32x4;

__device__ __forceinline__ ushort f2b(float v) {
    __hip_bfloat16 h = __float2bfloat16(v);
    return *reinterpret_cast<ushort*>(&h);
}
__device__ __forceinline__ float b2f(ushort u) {
    __hip_bfloat16 h = *reinterpret_cast<__hip_bfloat16*>(&u);
    return __bfloat162float(h);
}

// ---------------------------------------------------------------- combined count: coarse hist / fine hist
__global__ void count_all(const int* __restrict__ ec, const int* __restrict__ ef,
                          int* __restrict__ cntC, int* __restrict__ cntF) {
    const int b = blockIdx.y, z = blockIdx.z;
    const int i = blockIdx.x * 256 + threadIdx.x;
    if (z == 0) {
        if (i < EC) atomicAdd(&cntC[b * NC + ec[(size_t)b * 2 * EC + EC + i]], 1);
    } else {
        if (i < EF) atomicAdd(&cntF[b * NF + ef[(size_t)b * 2 * EF + EF + i]], 1);
    }
}

// ---------------------------------------------------------------- combined exclusive scan (grid = 2*B blocks)
template<int N>
__device__ __forceinline__ void scan_body(const int* __restrict__ cnt, int* __restrict__ offs,
                                          int* __restrict__ cur, int b, int* part) {
    const int tid = threadIdx.x;
    constexpr int PER = (N + 1023) / 1024;
    int local[PER];
    int s = 0;
    #pragma unroll
    for (int i = 0; i < PER; ++i) {
        int id = tid * PER + i;
        local[i] = s;
        if (id < N) s += cnt[b * N + id];
    }
    part[tid] = s;
    __syncthreads();
    for (int off = 1; off < 1024; off <<= 1) {
        int v = (tid >= off) ? part[tid - off] : 0;
        __syncthreads();
        part[tid] += v;
        __syncthreads();
    }
    int pre = tid ? part[tid - 1] : 0;
    #pragma unroll
    for (int i = 0; i < PER; ++i) {
        int id = tid * PER + i;
        if (id < N) {
            int o = pre + local[i];
            offs[b * N + id] = o;
            cur[b * N + id] = o;
        }
    }
}

__global__ __launch_bounds__(1024) void scan_all(
    const int* __restrict__ cntC, int* __restrict__ offC, int* __restrict__ curC,
    const int* __restrict__ cntF, int* __restrict__ offF, int* __restrict__ curF) {
    __shared__ int part[1024];
    const int cfg = blockIdx.x >> 2;   // B == 4
    const int b = blockIdx.x & 3;
    if (cfg == 0) scan_body<NC>(cntC, offC, curC, b, part);
    else          scan_body<NF>(cntF, offF, curF, b, part);
}

// ---------------------------------------------------------------- combined fill: CSRs / coarse position gather
__global__ void fill_all(const int* __restrict__ ec, const int* __restrict__ ef,
                         const int* __restrict__ mask, const float* __restrict__ pos,
                         int* __restrict__ curC, int* __restrict__ curF,
                         int* __restrict__ csrC, int* __restrict__ csrF,
                         float4* __restrict__ sposg) {
    const int b = blockIdx.y, z = blockIdx.z;
    const int i = blockIdx.x * 256 + threadIdx.x;
    if (z == 0) {
        if (i < EC) {
            const int* eb = ec + (size_t)b * 2 * EC;
            int src = eb[i], dst = eb[EC + i];
            int p = atomicAdd(&curC[b * NC + dst], 1);
            csrC[(size_t)b * EC + p] = src;
        }
    } else if (z == 1) {
        if (i < EF) {
            const int* eb = ef + (size_t)b * 2 * EF;
            int src = eb[i], dst = eb[EF + i];
            int p = atomicAdd(&curF[b * NF + dst], 1);
            csrF[(size_t)b * EF + p] = src;
        }
    } else {
        if (i < NC) {
            int m = mask[b * NC + i];
            const float* p = pos + ((size_t)b * NF + m) * 3;
            sposg[(size_t)b * NC + i] = make_float4(p[0], p[1], p[2], __int_as_float(i));
        }
    }
}

// ---------------------------------------------------------------- top-3 insert / lane-group merge helpers
__device__ __forceinline__ void ins3(float d, int c, float& d0, float& d1, float& d2,
                                     int& i0, int& i1, int& i2) {
    bool lt0 = d < d0, lt1 = d < d1, lt2 = d < d2;
    d2 = lt1 ? d1 : (lt2 ? d : d2);  i2 = lt1 ? i1 : (lt2 ? c : i2);
    d1 = lt0 ? d0 : (lt1 ? d : d1);  i1 = lt0 ? i0 : (lt1 ? c : i1);
    d0 = lt0 ? d  : d0;              i0 = lt0 ? c  : i0;
}

// ---------------------------------------------------------------- knn brute force: 8 nodes/block, 32 lanes/node, coalesced
__global__ __launch_bounds__(256) void knn_bf(const float* __restrict__ pos,
                                              const float4* __restrict__ sposg,
                                              int* __restrict__ idx,
                                              float* __restrict__ wn) {
    const int b = blockIdx.y;
    const int tid = threadIdx.x;
    const int node = blockIdx.x * 8 + (tid >> 5);
    const int lane = tid & 31;
    const float* pf = pos + ((size_t)b * NF + node) * 3;
    const float px = pf[0], py = pf[1], pz = pf[2];
    const float4* sp = sposg + (size_t)b * NC;
    float d0 = FLT_MAX, d1 = FLT_MAX, d2 = FLT_MAX;
    int i0 = 0, i1 = 0, i2 = 0;
    #pragma unroll 4
    for (int j = lane; j < NC; j += 32) {
        float4 s = sp[j];                       // coalesced: consecutive lanes, consecutive float4
        // match numpy: diff, square, sequential sum — no FMA contraction
        float ddx = __fsub_rn(px, s.x);
        float ddy = __fsub_rn(py, s.y);
        float ddz = __fsub_rn(pz, s.z);
        float d = __fadd_rn(__fadd_rn(__fmul_rn(ddx, ddx), __fmul_rn(ddy, ddy)),
                            __fmul_rn(ddz, ddz));
        ins3(d, __float_as_int(s.w), d0, d1, d2, i0, i1, i2);
    }
    #pragma unroll
    for (int off = 1; off <= 16; off <<= 1) {
        float od[3]; int oi[3];
        od[0] = __shfl_xor(d0, off); oi[0] = __shfl_xor(i0, off);
        od[1] = __shfl_xor(d1, off); oi[1] = __shfl_xor(i1, off);
        od[2] = __shfl_xor(d2, off); oi[2] = __shfl_xor(i2, off);
        #pragma unroll
        for (int j = 0; j < 3; ++j) ins3(od[j], oi[j], d0, d1, d2, i0, i1, i2);
    }
    if (lane == 0) {
        float w0 = 1.0f / (d0 + 1e-16f);
        float w1 = 1.0f / (d1 + 1e-16f);
        float w2 = 1.0f / (d2 + 1e-16f);
        float inv = 1.0f / (w0 + w1 + w2);
        size_t o = ((size_t)b * NF + node) * 3;
        idx[o] = i0; idx[o + 1] = i1; idx[o + 2] = i2;
        wn[o] = w0 * inv; wn[o + 1] = w1 * inv; wn[o + 2] = w2 * inv;
    }
}

// ---------------------------------------------------------------- weighted 3-NN gather, bf16 out (vectorized)
// 1<<S lanes per node, C = 4<<S channels
template<int S>
__global__ __launch_bounds__(256) void interp_b16(const float* __restrict__ xc,
                                                  const int* __restrict__ idx,
                                                  const float* __restrict__ wn,
                                                  ushort* __restrict__ out) {
    constexpr int C = 4 << S;
    const int b = blockIdx.y;
    const int node = blockIdx.x * (256 >> S) + (threadIdx.x >> S);
    const int lane = threadIdx.x & ((1 << S) - 1);
    size_t o = ((size_t)b * NF + node) * 3;
    int i0 = idx[o], i1 = idx[o + 1], i2 = idx[o + 2];
    float w0 = wn[o], w1 = wn[o + 1], w2 = wn[o + 2];
    const float* xb = xc + (size_t)b * NC * C;
    float4 a = *(const float4*)&xb[(size_t)i0 * C + lane * 4];
    float4 bb = *(const float4*)&xb[(size_t)i1 * C + lane * 4];
    float4 cc = *(const float4*)&xb[(size_t)i2 * C + lane * 4];
    ushort4 u;
    u.x = f2b(w0 * a.x + w1 * bb.x + w2 * cc.x);
    u.y = f2b(w0 * a.y + w1 * bb.y + w2 * cc.y);
    u.z = f2b(w0 * a.z + w1 * bb.z + w2 * cc.z);
    u.w = f2b(w0 * a.w + w1 * bb.w + w2 * cc.w);
    *(ushort4*)&out[((size_t)b * NF + node) * C + lane * 4] = u;
}

// ---------------------------------------------------------------- f32 GEMM (coarse node MLP)
__global__ __launch_bounds__(256) void gemm_kernel(
    const float* __restrict__ A1, int K1, const float* __restrict__ A2, int K2,
    const float* __restrict__ W, const float* __restrict__ bias,
    float* __restrict__ Cmat, int M, int N, int flags,
    long sA1, long sA2, long sC) {
    __shared__ float As[16][64];
    __shared__ float Wsh[16][64];
    const int b = blockIdx.z;
    const int m0 = blockIdx.y * 64, n0 = blockIdx.x * 64;
    const int t = threadIdx.x;
    const int tx = t & 15, ty = t >> 4;
    float acc[4][4] = {};
    int kOff = 0;
    for (int s = 0; s < 2; ++s) {
        const float* A = (s == 0) ? A1 : A2;
        const int K = (s == 0) ? K1 : K2;
        const long sA = (s == 0) ? sA1 : sA2;
        if (A == nullptr || K == 0) continue;
        const float* Ab = A + (size_t)b * sA;
        const int lm = t >> 2;
        const int lk = (t & 3) << 2;
        const int wk = t >> 4;
        const int wng = (t & 15) << 2;
        for (int k0 = 0; k0 < K; k0 += 16) {
            float4 av = *(const float4*)&Ab[(size_t)(m0 + lm) * K + k0 + lk];
            As[lk + 0][lm] = av.x; As[lk + 1][lm] = av.y;
            As[lk + 2][lm] = av.z; As[lk + 3][lm] = av.w;
            float4 wv = *(const float4*)&W[(size_t)(kOff + k0 + wk) * N + n0 + wng];
            *(float4*)&Wsh[wk][wng] = wv;
            __syncthreads();
            #pragma unroll
            for (int k = 0; k < 16; ++k) {
                float4 a4 = *(const float4*)&As[k][ty << 2];
                float4 w4 = *(const float4*)&Wsh[k][tx << 2];
                float aa[4] = {a4.x, a4.y, a4.z, a4.w};
                float ww[4] = {w4.x, w4.y, w4.z, w4.w};
                #pragma unroll
                for (int i = 0; i < 4; ++i)
                    #pragma unroll
                    for (int j = 0; j < 4; ++j)
                        acc[i][j] = fmaf(aa[i], ww[j], acc[i][j]);
            }
            __syncthreads();
        }
        kOff += K;
    }
    float* Cb = Cmat + (size_t)b * sC;
    #pragma unroll
    for (int i = 0; i < 4; ++i) {
        int m = m0 + (ty << 2) + i;
        #pragma unroll
        for (int j = 0; j < 4; ++j) {
            int n = n0 + (tx << 2) + j;
            float v = acc[i][j];
            if (bias) v += bias[n];
            if (flags & 1) v = v > 0.0f ? v : 0.01f * v;
            float* cp = &Cb[(size_t)m * N + n];
            if (flags & 2) v += *cp;
            *cp = v;
        }
    }
}

// ---------------------------------------------------------------- coarse P/Q GEMM merged (M=NC, N=64, K=128)
__global__ __launch_bounds__(256) void gemm_pq64(const float* __restrict__ x,
                                                 const float* __restrict__ W1e,
                                                 float* __restrict__ Pb,
                                                 float* __restrict__ Qb) {
    __shared__ float As[16][64];
    __shared__ float Wsh[16][64];
    const int z = blockIdx.z;
    const int b = z >> 1, pq = z & 1;
    const int m0 = blockIdx.x * 64;
    const float* Ab = x + (size_t)b * NC * CIN;
    const float* W = W1e + pq * CIN * CH;
    float* Cb = (pq ? Qb : Pb) + (size_t)b * NC * CH;
    const int t = threadIdx.x;
    const int tx = t & 15, ty = t >> 4;
    const int lm = t >> 2, lk = (t & 3) << 2;
    const int wk = t >> 4, wng = (t & 15) << 2;
    float acc[4][4] = {};
    for (int k0 = 0; k0 < CIN; k0 += 16) {
        float4 av = *(const float4*)&Ab[(size_t)(m0 + lm) * CIN + k0 + lk];
        As[lk + 0][lm] = av.x; As[lk + 1][lm] = av.y;
        As[lk + 2][lm] = av.z; As[lk + 3][lm] = av.w;
        float4 wv = *(const float4*)&W[(size_t)(k0 + wk) * CH + wng];
        *(float4*)&Wsh[wk][wng] = wv;
        __syncthreads();
        #pragma unroll
        for (int k = 0; k < 16; ++k) {
            float4 a4 = *(const float4*)&As[k][ty << 2];
            float4 w4 = *(const float4*)&Wsh[k][tx << 2];
            float aa[4] = {a4.x, a4.y, a4.z, a4.w};
            float ww[4] = {w4.x, w4.y, w4.z, w4.w};
            #pragma unroll
            for (int i = 0; i < 4; ++i)
                #pragma unroll
                for (int j = 0; j < 4; ++j)
                    acc[i][j] = fmaf(aa[i], ww[j], acc[i][j]);
        }
        __syncthreads();
    }
    #pragma unroll
    for (int i = 0; i < 4; ++i) {
        int m = m0 + (ty << 2) + i;
        #pragma unroll
        for (int j = 0; j < 4; ++j)
            Cb[(size_t)m * CH + (tx << 2) + j] = acc[i][j];
    }
}

// ---------------------------------------------------------------- MFMA bf16 GEMM (fine path, N=128)
#define LDK 40
__global__ __launch_bounds__(256) void mfma_gemm(
    const ushort* __restrict__ A1, int K1, const ushort* __restrict__ A2, int K2,
    const ushort* __restrict__ Wt, int ldW, int kPQ, int npq,
    const float* __restrict__ bias, void* __restrict__ C0v, void* __restrict__ C1v,
    int flags, long sA1, long sA2, long sC) {
    __shared__ ushort As[128 * LDK];
    __shared__ ushort Wsm[128 * LDK];
    const int t = threadIdx.x;
    const int lane = t & 63, wid = t >> 6;
    const int wr = wid >> 1, wc = wid & 1;
    const int fr = lane & 15, fq = lane >> 4;
    const int sr = t >> 2, sk = (t & 3) * 8;
    const int z = blockIdx.z;
    const int b = z / npq, pq = z - b * npq;
    const int m0 = blockIdx.x * 128;
    const int wbase = pq * kPQ;

    f32x4 acc[4][4];
    #pragma unroll
    for (int m = 0; m < 4; ++m)
        #pragma unroll
        for (int n = 0; n < 4; ++n)
            acc[m][n] = (f32x4){0.f, 0.f, 0.f, 0.f};

    int kOff = 0;
    for (int s = 0; s < 2; ++s) {
        const ushort* A = (s == 0) ? A1 : A2;
        const int K = (s == 0) ? K1 : K2;
        const long sA = (s == 0) ? sA1 : sA2;
        if (A == nullptr || K == 0) continue;
        const ushort* Ab = A + (size_t)b * sA;
        for (int k0 = 0; k0 < K; k0 += 32) {
            #pragma unroll
            for (int p = 0; p < 2; ++p) {
                int r = sr + p * 64;
                *reinterpret_cast<int4*>(&As[r * LDK + sk]) =
                    *reinterpret_cast<const int4*>(&Ab[(size_t)(m0 + r) * K + k0 + sk]);
                *reinterpret_cast<int4*>(&Wsm[r * LDK + sk]) =
                    *reinterpret_cast<const int4*>(&Wt[(size_t)r * ldW + wbase + kOff + k0 + sk]);
            }
            __syncthreads();
            short8v af[4], wf[4];
            #pragma unroll
            for (int m = 0; m < 4; ++m)
                af[m] = *reinterpret_cast<const short8v*>(&As[(wr * 64 + m * 16 + fr) * LDK + fq * 8]);
            #pragma unroll
            for (int n = 0; n < 4; ++n)
                wf[n] = *reinterpret_cast<const short8v*>(&Wsm[(wc * 64 + n * 16 + fr) * LDK + fq * 8]);
            #pragma unroll
            for (int m = 0; m < 4; ++m)
                #pragma unroll
                for (int n = 0; n < 4; ++n)
                    acc[m][n] = __builtin_amdgcn_mfma_f32_16x16x32_bf16(af[m], wf[n], acc[m][n], 0, 0, 0);
            __syncthreads();
        }
        kOff += K;
    }

    void* Cv = (pq == 0) ? C0v : C1v;
    if (flags & 4) {
        ushort* Cb = (ushort*)Cv + (size_t)b * sC;
        #pragma unroll
        for (int m = 0; m < 4; ++m)
            #pragma unroll
            for (int n = 0; n < 4; ++n) {
                int col = wc * 64 + n * 16 + fr;
                #pragma unroll
                for (int r = 0; r < 4; ++r) {
                    int row = m0 + wr * 64 + m * 16 + fq * 4 + r;
                    Cb[(size_t)row * 128 + col] = f2b(acc[m][n][r]);
                }
            }
    } else {
        float* Cb = (float*)Cv + (size_t)b * sC;
        #pragma unroll
        for (int m = 0; m < 4; ++m)
            #pragma unroll
            for (int n = 0; n < 4; ++n) {
                int col = wc * 64 + n * 16 + fr;
                float bv = bias ? bias[col] : 0.0f;
                #pragma unroll
                for (int r = 0; r < 4; ++r) {
                    int row = m0 + wr * 64 + m * 16 + fq * 4 + r;
                    float v = acc[m][n][r] + bv;
                    if (flags & 1) v = v > 0.0f ? v : 0.01f * v;
                    float* cp = &Cb[(size_t)row * 128 + col];
                    if (flags & 2) v += *cp;
                    *cp = v;
                }
            }
    }
}

// ---------------------------------------------------------------- fine weight transpose+bf16: Wt[n][k] = bf16(W[k][n])
__global__ void conv_wt(const float* __restrict__ W2e, const float* __restrict__ W2n,
                        const float* __restrict__ Wse, const float* __restrict__ Wsn,
                        ushort* __restrict__ W2eT, ushort* __restrict__ W2nT,
                        ushort* __restrict__ WseT, ushort* __restrict__ WsnT) {
    const float* src; ushort* dst; int K2;
    switch (blockIdx.y) {
        case 0: src = W2e; dst = W2eT; K2 = 128; break;
        case 1: src = W2n; dst = W2nT; K2 = 192; break;
        case 2: src = Wse; dst = WseT; K2 = 256; break;
        default: src = Wsn; dst = WsnT; K2 = 256; break;
    }
    int id = blockIdx.x * 256 + threadIdx.x;
    if (id >= K2 * 128) return;
    int n = id & 127, k = id >> 7;
    dst[(size_t)n * K2 + k] = f2b(src[id]);
}

// ---------------------------------------------------------------- edge message + aggregate (coarse, f32, C=64)
__global__ __launch_bounds__(256) void agg_csr_f32(const float* __restrict__ P,
                                                   const float* __restrict__ Q,
                                                   const float* __restrict__ bias,
                                                   const int* __restrict__ offs,
                                                   const int* __restrict__ counts,
                                                   const int* __restrict__ csr_src,
                                                   float* __restrict__ agg,
                                                   int N, int E) {
    const int b = blockIdx.y;
    const int dst = blockIdx.x * 4 + (threadIdx.x >> 6);
    const int lane = threadIdx.x & 63;
    const float* Pb = P + (size_t)b * N * 64;
    const float* Qb = Q + (size_t)b * N * 64;
    const int start = offs[b * N + dst];
    const int cnt = counts[b * N + dst];
    const int* sl = csr_src + (size_t)b * E + start;
    const float q = Qb[(size_t)dst * 64 + lane] + bias[lane];
    float a = 0.0f;
    for (int i = 0; i < cnt; ++i) {
        int src = sl[i];
        float m = Pb[(size_t)src * 64 + lane] + q; m = m > 0.0f ? m : 0.01f * m;
        a += m;
    }
    agg[(size_t)b * N * 64 + (size_t)dst * 64 + lane] = a;
}

// ---------------------------------------------------------------- edge message + aggregate (fine, bf16 io, C=128)
__global__ __launch_bounds__(256) void agg_csr_b16(const ushort* __restrict__ P,
                                                   const ushort* __restrict__ Q,
                                                   const float* __restrict__ bias,
                                                   const int* __restrict__ offs,
                                                   const int* __restrict__ counts,
                                                   const int* __restrict__ csr_src,
                                                   ushort* __restrict__ agg,
                                                   int N, int E) {
    const int b = blockIdx.y;
    const int dst = blockIdx.x * 4 + (threadIdx.x >> 6);
    const int lane = threadIdx.x & 63;
    const ushort* Pb = P + (size_t)b * N * 128;
    const ushort* Qb = Q + (size_t)b * N * 128;
    const int start = offs[b * N + dst];
    const int cnt = counts[b * N + dst];
    const int* sl = csr_src + (size_t)b * E + start;
    const int c0 = lane, c1 = lane + 64;
    const float q0 = b2f(Qb[(size_t)dst * 128 + c0]) + bias[c0];
    const float q1 = b2f(Qb[(size_t)dst * 128 + c1]) + bias[c1];
    float a0 = 0.0f, a1 = 0.0f;
    for (int i = 0; i < cnt; ++i) {
        int src = sl[i];
        float m0 = b2f(Pb[(size_t)src * 128 + c0]) + q0; m0 = m0 > 0.0f ? m0 : 0.01f * m0;
        float m1 = b2f(Pb[(size_t)src * 128 + c1]) + q1; m1 = m1 > 0.0f ? m1 : 0.01f * m1;
        a0 += m0; a1 += m1;
    }
    agg[(size_t)b * N * 128 + (size_t)dst * 128 + c0] = f2b(a0);
    agg[(size_t)b * N * 128 + (size_t)dst * 128 + c1] = f2b(a1);
}

// ---------------------------------------------------------------- batch-norm
__global__ void bn_stats(const float* __restrict__ xs, float* __restrict__ stats) {
    const int c = threadIdx.x;
    long r0 = (long)blockIdx.x * 256;
    float s = 0.0f, s2 = 0.0f;
    for (int r = 0; r < 256; ++r) {
        float v = xs[(r0 + r) * COUT + c];
        s += v;
        s2 = fmaf(v, v, s2);
    }
    atomicAdd(&stats[c], s);
    atomicAdd(&stats[COUT + c], s2);
}

__global__ void bn_final(float* __restrict__ xs, const float* __restrict__ stats,
                         const float* __restrict__ gamma, const float* __restrict__ beta,
                         float* __restrict__ wf) {
    long g = (long)blockIdx.x * 256 + threadIdx.x;
    int c = (int)(g & (COUT - 1));
    const float invN = 1.0f / (float)(B * NF);
    float mu = stats[c] * invN;
    float var = stats[COUT + c] * invN - mu * mu;
    float v = (xs[g] - mu) * rsqrtf(var + 1e-5f) * gamma[c] + beta[c];
    xs[g] = v > 0.0f ? v : 0.01f * v;
    if (g < (long)B * NF) wf[g] = 0.0f;      // fold w_fine zeroing in
}

__global__ void wfine_scatter(const float* __restrict__ wts, const int* __restrict__ mask,
                              float* __restrict__ wf) {
    int i = blockIdx.x * 256 + threadIdx.x;
    int b = i / NC;
    wf[(size_t)b * NF + mask[i]] = wts[i];
}

extern "C" void kernel_launch(void* const* d_in, const int* in_sizes, int n_in,
                              void* d_out, int out_size, void* d_ws, size_t ws_size,
                              hipStream_t stream) {
    const float* x    = (const float*)d_in[0];
    const float* wts  = (const float*)d_in[1];
    const float* pos  = (const float*)d_in[2];
    const float* W1e  = (const float*)d_in[3];
    const float* b1e  = (const float*)d_in[4];
    const float* W1n  = (const float*)d_in[5];
    const float* b1n  = (const float*)d_in[6];
    const float* W2e  = (const float*)d_in[7];
    const float* b2e  = (const float*)d_in[8];
    const float* W2n  = (const float*)d_in[9];
    const float* b2n  = (const float*)d_in[10];
    const float* Wse  = (const float*)d_in[11];
    const float* bse  = (const float*)d_in[12];
    const float* Wsn  = (const float*)d_in[13];
    const float* bsn  = (const float*)d_in[14];
    const float* gamma= (const float*)d_in[15];
    const float* beta = (const float*)d_in[16];
    const int*   mask = (const int*)d_in[17];
    const int*   ec   = (const int*)d_in[18];
    const int*   ef   = (const int*)d_in[19];

    float* ws = (float*)d_ws;
    // ---- f32 region
    int*    idxb  = (int*)ws;                              // B*NF*3
    float*  wnb   = ws + 98304;                            // B*NF*3
    float4* sposg = (float4*)(ws + 196608);                // B*NC float4
    float*  x1    = ws + 196608 + 32768;                   // B*NC*CH
    float*  PbC   = x1  + (size_t)B * NC * CH;
    float*  QbC   = PbC + (size_t)B * NC * CH;
    float*  aggC  = QbC + (size_t)B * NC * CH;
    float*  stats = aggC+ (size_t)B * NC * CH;             // 256
    // ---- int region (counts contiguous for single memset)
    int* cntC  = (int*)(stats + 256);                      // B*NC
    int* cntF  = cntC + B * NC;                            // B*NF
    int* offC  = cntF + B * NF;                            // B*NC
    int* curC  = offC + B * NC;
    int* offF  = curC + B * NC;                            // B*NF
    int* curF  = offF + B * NF;
    int* csrC  = curF + B * NF;                            // B*EC
    int* csrF  = csrC + B * EC;                            // B*EF
    // ---- bf16 region (32B aligned)
    size_t foff = (size_t)(csrF + (size_t)B * EF - (int*)ws);
    foff = (foff + 7) & ~(size_t)7;
    ushort* xupb  = (ushort*)(ws + foff);                  // B*NF*128
    ushort* x1upb = xupb  + (size_t)B * NF * 128;          // B*NF*64
    ushort* Pb    = x1upb + (size_t)B * NF * 64;           // B*NF*128
    ushort* Qb    = Pb    + (size_t)B * NF * 128;          // B*NF*128
    ushort* aggb  = Qb    + (size_t)B * NF * 128;          // B*NF*128
    ushort* W2eT  = aggb  + (size_t)B * NF * 128;          // 128*128
    ushort* W2nT  = W2eT  + 128 * 128;                     // 128*192
    ushort* WseT  = W2nT  + 128 * 192;                     // 128*256
    ushort* WsnT  = WseT  + 128 * 256;                     // 128*256

    float* y  = (float*)d_out;                             // B*NF*128
    float* wf = y + (size_t)B * NF * COUT;                 // B*NF

    // ---- prep: weights, counts (one memset), scans, fills
    conv_wt<<<dim3(128, 4), 256, 0, stream>>>(W2e, W2n, Wse, Wsn, W2eT, W2nT, WseT, WsnT);
    hipMemsetAsync(cntC, 0, (size_t)B * (NC + NF) * 4, stream);
    count_all<<<dim3(EF / 256, B, 2), 256, 0, stream>>>(ec, ef, cntC, cntF);
    scan_all<<<dim3(2 * B), 1024, 0, stream>>>(cntC, offC, curC, cntF, offF, curF);
    fill_all<<<dim3(EF / 256, B, 3), 256, 0, stream>>>(ec, ef, mask, pos, curC, curF,
                                                       csrC, csrF, sposg);

    // ---- knn (coalesced brute force, full occupancy)
    knn_bf<<<dim3(NF / 8, B), 256, 0, stream>>>(pos, sposg, idxb, wnb);

    // ---- x_up = interp(x) -> bf16  (C=128: 32 lanes/node)
    interp_b16<5><<<dim3(NF / 8, B), 256, 0, stream>>>(x, idxb, wnb, xupb);

    // ---- main branch: mpl1 on coarse graph (f32 path)
    gemm_pq64<<<dim3(NC / 64, 1, B * 2), 256, 0, stream>>>(x, W1e, PbC, QbC);
    agg_csr_f32<<<dim3(NC / 4, B), 256, 0, stream>>>(
        PbC, QbC, b1e, offC, cntC, csrC, aggC, NC, EC);
    gemm_kernel<<<dim3(1, NC / 64, B), 256, 0, stream>>>(
        x, CIN, aggC, CH, W1n, b1n, x1, NC, CH, 1, (long)NC * CIN, (long)NC * CH, (long)NC * CH);

    // ---- x1_up = interp(x1) -> bf16  (C=64: 16 lanes/node)
    interp_b16<4><<<dim3(NF / 16, B), 256, 0, stream>>>(x1, idxb, wnb, x1upb);

    // ---- mpl2 on fine graph (MFMA path)
    mfma_gemm<<<dim3(NF / 128, 1, B * 2), 256, 0, stream>>>(
        x1upb, CH, nullptr, 0, W2eT, 128, CH, 2, nullptr, Pb, Qb, 4,
        (long)NF * CH, 0, (long)NF * 128);
    agg_csr_b16<<<dim3(NF / 4, B), 256, 0, stream>>>(
        Pb, Qb, b2e, offF, cntF, csrF, aggb, NF, EF);
    mfma_gemm<<<dim3(NF / 128, 1, B), 256, 0, stream>>>(
        x1upb, CH, aggb, COUT, W2nT, 192, 0, 1, b2n, y, y, 1,
        (long)NF * CH, (long)NF * 128, (long)NF * 128);

    // ---- skip branch (MFMA path), accumulated into y
    mfma_gemm<<<dim3(NF / 128, 1, B * 2), 256, 0, stream>>>(
        xupb, CIN, nullptr, 0, WseT, 256, CIN, 2, nullptr, Pb, Qb, 4,
        (long)NF * CIN, 0, (long)NF * 128);
    agg_csr_b16<<<dim3(NF / 4, B), 256, 0, stream>>>(
        Pb, Qb, bse, offF, cntF, csrF, aggb, NF, EF);
    mfma_gemm<<<dim3(NF / 128, 1, B), 256, 0, stream>>>(
        xupb, CIN, aggb, COUT, WsnT, 256, 0, 1, bsn, y, y, 3,
        (long)NF * CIN, (long)NF * 128, (long)NF * 128);

    // ---- batch norm + lrelu (+ wf zero), then w_fine scatter
    hipMemsetAsync(stats, 0, 256 * 4, stream);
    bn_stats<<<dim3((B * NF) / 256), COUT, 0, stream>>>(y, stats);
    bn_final<<<dim3((long)B * NF * COUT / 256), 256, 0, stream>>>(y, stats, gamma, beta, wf);
    wfine_scatter<<<dim3(B * NC / 256), 256, 0, stream>>>(wts, mask, wf);
}

// Round 8
// 249.008 us; speedup vs baseline: 2.9985x; 1.1268x over previous
//
#include <hip/hip_runtime.h>
#include <hip/hip_bf16.h>
#include <cfloat>

#define B 4
#define NC 2048
#define NF 8192
#define CIN 128
#define CH 64
#define COUT 128
#define EC 16384
#define EF 65536
#define ZB 256          // z-sort bins

typedef __attribute__((ext_vector_type(8))) short short8v;
typedef __attribute__((ext_vector_type(4))) float f32x4;

__device__ __forceinline__ ushort f2b(float v) {
    __hip_bfloat16 h = __float2bfloat16(v);
    return *reinterpret_cast<ushort*>(&h);
}
__device__ __forceinline__ float b2f(ushort u) {
    __hip_bfloat16 h = *reinterpret_cast<__hip_bfloat16*>(&u);
    return __bfloat162float(h);
}

// ---------------------------------------------------------------- combined count: coarse hist / fine hist / z-bin hist
__global__ void count_all(const int* __restrict__ ec, const int* __restrict__ ef,
                          const int* __restrict__ mask, const float* __restrict__ pos,
                          int* __restrict__ cntC, int* __restrict__ cntF, int* __restrict__ cntZ) {
    const int b = blockIdx.y, z = blockIdx.z;
    const int i = blockIdx.x * 256 + threadIdx.x;
    if (z == 0) {
        if (i < EC) atomicAdd(&cntC[b * NC + ec[(size_t)b * 2 * EC + EC + i]], 1);
    } else if (z == 1) {
        if (i < EF) atomicAdd(&cntF[b * NF + ef[(size_t)b * 2 * EF + EF + i]], 1);
    } else {
        if (i < NC) {
            int m = mask[b * NC + i];
            float pz = pos[((size_t)b * NF + m) * 3 + 2];
            int zb = min(max((int)(pz * (float)ZB), 0), ZB - 1);
            atomicAdd(&cntZ[b * ZB + zb], 1);
        }
    }
}

// ---------------------------------------------------------------- combined exclusive scan (grid = 3*B blocks)
template<int N, int OSTR, bool EXTRA>
__device__ __forceinline__ void scan_body(const int* __restrict__ cnt, int* __restrict__ offs,
                                          int* __restrict__ cur, int b, int* part) {
    const int tid = threadIdx.x;
    constexpr int PER = (N + 1023) / 1024;
    int local[PER];
    int s = 0;
    #pragma unroll
    for (int i = 0; i < PER; ++i) {
        int id = tid * PER + i;
        local[i] = s;
        if (id < N) s += cnt[b * N + id];
    }
    part[tid] = s;
    __syncthreads();
    for (int off = 1; off < 1024; off <<= 1) {
        int v = (tid >= off) ? part[tid - off] : 0;
        __syncthreads();
        part[tid] += v;
        __syncthreads();
    }
    int pre = tid ? part[tid - 1] : 0;
    #pragma unroll
    for (int i = 0; i < PER; ++i) {
        int id = tid * PER + i;
        if (id < N) {
            int o = pre + local[i];
            offs[b * OSTR + id] = o;
            cur[b * OSTR + id] = o;
        }
    }
    if (EXTRA && tid == 1023) offs[b * OSTR + N] = part[1023];
}

__global__ __launch_bounds__(1024) void scan_all(
    const int* __restrict__ cntC, int* __restrict__ offC, int* __restrict__ curC,
    const int* __restrict__ cntF, int* __restrict__ offF, int* __restrict__ curF,
    const int* __restrict__ cntZ, int* __restrict__ offZ, int* __restrict__ curZ) {
    __shared__ int part[1024];
    const int cfg = blockIdx.x >> 2;   // B == 4
    const int b = blockIdx.x & 3;
    if (cfg == 0)      scan_body<NC, NC, false>(cntC, offC, curC, b, part);
    else if (cfg == 1) scan_body<NF, NF, false>(cntF, offF, curF, b, part);
    else               scan_body<ZB, ZB + 1, true>(cntZ, offZ, curZ, b, part);
}

// ---------------------------------------------------------------- combined fill: CSRs / z-sorted coarse positions
__global__ void fill_all(const int* __restrict__ ec, const int* __restrict__ ef,
                         const int* __restrict__ mask, const float* __restrict__ pos,
                         int* __restrict__ curC, int* __restrict__ curF, int* __restrict__ curZ,
                         int* __restrict__ csrC, int* __restrict__ csrF,
                         float4* __restrict__ sposg) {
    const int b = blockIdx.y, z = blockIdx.z;
    const int i = blockIdx.x * 256 + threadIdx.x;
    if (z == 0) {
        if (i < EC) {
            const int* eb = ec + (size_t)b * 2 * EC;
            int src = eb[i], dst = eb[EC + i];
            int p = atomicAdd(&curC[b * NC + dst], 1);
            csrC[(size_t)b * EC + p] = src;
        }
    } else if (z == 1) {
        if (i < EF) {
            const int* eb = ef + (size_t)b * 2 * EF;
            int src = eb[i], dst = eb[EF + i];
            int p = atomicAdd(&curF[b * NF + dst], 1);
            csrF[(size_t)b * EF + p] = src;
        }
    } else {
        if (i < NC) {
            int m = mask[b * NC + i];
            const float* p = pos + ((size_t)b * NF + m) * 3;
            float px = p[0], py = p[1], pz = p[2];
            int zb = min(max((int)(pz * (float)ZB), 0), ZB - 1);
            int slot = atomicAdd(&curZ[b * (ZB + 1) + zb], 1);
            sposg[(size_t)b * NC + slot] = make_float4(px, py, pz, __int_as_float(i));
        }
    }
}

// ---------------------------------------------------------------- top-3 insert helper
__device__ __forceinline__ void ins3(float d, int c, float& d0, float& d1, float& d2,
                                     int& i0, int& i1, int& i2) {
    bool lt0 = d < d0, lt1 = d < d1, lt2 = d < d2;
    d2 = lt1 ? d1 : (lt2 ? d : d2);  i2 = lt1 ? i1 : (lt2 ? c : i2);
    d1 = lt0 ? d0 : (lt1 ? d : d1);  i1 = lt0 ? i0 : (lt1 ? c : i1);
    d0 = lt0 ? d  : d0;              i0 = lt0 ? c  : i0;
}
__device__ __forceinline__ void merge32(float& d0, float& d1, float& d2,
                                        int& i0, int& i1, int& i2) {
    #pragma unroll
    for (int off = 1; off <= 16; off <<= 1) {
        float od[3]; int oi[3];
        od[0] = __shfl_xor(d0, off); oi[0] = __shfl_xor(i0, off);
        od[1] = __shfl_xor(d1, off); oi[1] = __shfl_xor(i1, off);
        od[2] = __shfl_xor(d2, off); oi[2] = __shfl_xor(i2, off);
        #pragma unroll
        for (int j = 0; j < 3; ++j) ins3(od[j], oi[j], d0, d1, d2, i0, i1, i2);
    }
}

// ---------------------------------------------------------------- knn: z-window brute force, 8 nodes/block, 32 lanes/node
__global__ __launch_bounds__(256) void knn_bf(const float* __restrict__ pos,
                                              const float4* __restrict__ sposg,
                                              const int* __restrict__ offZ,
                                              int* __restrict__ idx,
                                              float* __restrict__ wn) {
    const int b = blockIdx.y;
    const int tid = threadIdx.x;
    const int node = blockIdx.x * 8 + (tid >> 5);
    const int lane = tid & 31;
    const float* pf = pos + ((size_t)b * NF + node) * 3;
    const float px = pf[0], py = pf[1], pz = pf[2];
    const float4* sp = sposg + (size_t)b * NC;
    const int zb = min(max((int)(pz * (float)ZB), 0), ZB - 1);
    const int zlo = max(zb - 32, 0), zhi = min(zb + 32, ZB - 1);
    const int j0 = offZ[b * (ZB + 1) + zlo];
    const int j1 = offZ[b * (ZB + 1) + zhi + 1];
    float d0 = FLT_MAX, d1 = FLT_MAX, d2 = FLT_MAX;
    int i0 = 0, i1 = 0, i2 = 0;
    for (int j = j0 + lane; j < j1; j += 32) {
        float4 s = sp[j];
        // match numpy: diff, square, sequential sum — no FMA contraction
        float ddx = __fsub_rn(px, s.x);
        float ddy = __fsub_rn(py, s.y);
        float ddz = __fsub_rn(pz, s.z);
        float d = __fadd_rn(__fadd_rn(__fmul_rn(ddx, ddx), __fmul_rn(ddy, ddy)),
                            __fmul_rn(ddz, ddz));
        ins3(d, __float_as_int(s.w), d0, d1, d2, i0, i1, i2);
    }
    merge32(d0, d1, d2, i0, i1, i2);
    // exact bound vs. the unsearched z-slabs
    float bd = 1e30f;
    if (zlo > 0)      bd = fminf(bd, px - px + pz - (float)zlo * (1.0f / ZB));   // pz - plane
    if (zhi < ZB - 1) bd = fminf(bd, (float)(zhi + 1) * (1.0f / ZB) - pz);
    bd *= 0.9999f;
    if (__any(d2 > bd * bd)) {
        // rare: full exact rescan (wave-coherent)
        d0 = d1 = d2 = FLT_MAX; i0 = i1 = i2 = 0;
        for (int j = lane; j < NC; j += 32) {
            float4 s = sp[j];
            float ddx = __fsub_rn(px, s.x);
            float ddy = __fsub_rn(py, s.y);
            float ddz = __fsub_rn(pz, s.z);
            float d = __fadd_rn(__fadd_rn(__fmul_rn(ddx, ddx), __fmul_rn(ddy, ddy)),
                                __fmul_rn(ddz, ddz));
            ins3(d, __float_as_int(s.w), d0, d1, d2, i0, i1, i2);
        }
        merge32(d0, d1, d2, i0, i1, i2);
    }
    if (lane == 0) {
        float w0 = 1.0f / (d0 + 1e-16f);
        float w1 = 1.0f / (d1 + 1e-16f);
        float w2 = 1.0f / (d2 + 1e-16f);
        float inv = 1.0f / (w0 + w1 + w2);
        size_t o = ((size_t)b * NF + node) * 3;
        idx[o] = i0; idx[o + 1] = i1; idx[o + 2] = i2;
        wn[o] = w0 * inv; wn[o + 1] = w1 * inv; wn[o + 2] = w2 * inv;
    }
}

// ---------------------------------------------------------------- weighted 3-NN gather, bf16 out (vectorized)
template<int S>
__global__ __launch_bounds__(256) void interp_b16(const float* __restrict__ xc,
                                                  const int* __restrict__ idx,
                                                  const float* __restrict__ wn,
                                                  ushort* __restrict__ out) {
    constexpr int C = 4 << S;
    const int b = blockIdx.y;
    const int node = blockIdx.x * (256 >> S) + (threadIdx.x >> S);
    const int lane = threadIdx.x & ((1 << S) - 1);
    size_t o = ((size_t)b * NF + node) * 3;
    int i0 = idx[o], i1 = idx[o + 1], i2 = idx[o + 2];
    float w0 = wn[o], w1 = wn[o + 1], w2 = wn[o + 2];
    const float* xb = xc + (size_t)b * NC * C;
    float4 a = *(const float4*)&xb[(size_t)i0 * C + lane * 4];
    float4 bb = *(const float4*)&xb[(size_t)i1 * C + lane * 4];
    float4 cc = *(const float4*)&xb[(size_t)i2 * C + lane * 4];
    ushort4 u;
    u.x = f2b(w0 * a.x + w1 * bb.x + w2 * cc.x);
    u.y = f2b(w0 * a.y + w1 * bb.y + w2 * cc.y);
    u.z = f2b(w0 * a.z + w1 * bb.z + w2 * cc.z);
    u.w = f2b(w0 * a.w + w1 * bb.w + w2 * cc.w);
    *(ushort4*)&out[((size_t)b * NF + node) * C + lane * 4] = u;
}

// ---------------------------------------------------------------- f32 GEMM (coarse node MLP)
__global__ __launch_bounds__(256) void gemm_kernel(
    const float* __restrict__ A1, int K1, const float* __restrict__ A2, int K2,
    const float* __restrict__ W, const float* __restrict__ bias,
    float* __restrict__ Cmat, int M, int N, int flags,
    long sA1, long sA2, long sC) {
    __shared__ float As[16][64];
    __shared__ float Wsh[16][64];
    const int b = blockIdx.z;
    const int m0 = blockIdx.y * 64, n0 = blockIdx.x * 64;
    const int t = threadIdx.x;
    const int tx = t & 15, ty = t >> 4;
    float acc[4][4] = {};
    int kOff = 0;
    for (int s = 0; s < 2; ++s) {
        const float* A = (s == 0) ? A1 : A2;
        const int K = (s == 0) ? K1 : K2;
        const long sA = (s == 0) ? sA1 : sA2;
        if (A == nullptr || K == 0) continue;
        const float* Ab = A + (size_t)b * sA;
        const int lm = t >> 2;
        const int lk = (t & 3) << 2;
        const int wk = t >> 4;
        const int wng = (t & 15) << 2;
        for (int k0 = 0; k0 < K; k0 += 16) {
            float4 av = *(const float4*)&Ab[(size_t)(m0 + lm) * K + k0 + lk];
            As[lk + 0][lm] = av.x; As[lk + 1][lm] = av.y;
            As[lk + 2][lm] = av.z; As[lk + 3][lm] = av.w;
            float4 wv = *(const float4*)&W[(size_t)(kOff + k0 + wk) * N + n0 + wng];
            *(float4*)&Wsh[wk][wng] = wv;
            __syncthreads();
            #pragma unroll
            for (int k = 0; k < 16; ++k) {
                float4 a4 = *(const float4*)&As[k][ty << 2];
                float4 w4 = *(const float4*)&Wsh[k][tx << 2];
                float aa[4] = {a4.x, a4.y, a4.z, a4.w};
                float ww[4] = {w4.x, w4.y, w4.z, w4.w};
                #pragma unroll
                for (int i = 0; i < 4; ++i)
                    #pragma unroll
                    for (int j = 0; j < 4; ++j)
                        acc[i][j] = fmaf(aa[i], ww[j], acc[i][j]);
            }
            __syncthreads();
        }
        kOff += K;
    }
    float* Cb = Cmat + (size_t)b * sC;
    #pragma unroll
    for (int i = 0; i < 4; ++i) {
        int m = m0 + (ty << 2) + i;
        #pragma unroll
        for (int j = 0; j < 4; ++j) {
            int n = n0 + (tx << 2) + j;
            float v = acc[i][j];
            if (bias) v += bias[n];
            if (flags & 1) v = v > 0.0f ? v : 0.01f * v;
            float* cp = &Cb[(size_t)m * N + n];
            if (flags & 2) v += *cp;
            *cp = v;
        }
    }
}

// ---------------------------------------------------------------- coarse P/Q GEMM merged (M=NC, N=64, K=128)
__global__ __launch_bounds__(256) void gemm_pq64(const float* __restrict__ x,
                                                 const float* __restrict__ W1e,
                                                 float* __restrict__ Pb,
                                                 float* __restrict__ Qb) {
    __shared__ float As[16][64];
    __shared__ float Wsh[16][64];
    const int z = blockIdx.z;
    const int b = z >> 1, pq = z & 1;
    const int m0 = blockIdx.x * 64;
    const float* Ab = x + (size_t)b * NC * CIN;
    const float* W = W1e + pq * CIN * CH;
    float* Cb = (pq ? Qb : Pb) + (size_t)b * NC * CH;
    const int t = threadIdx.x;
    const int tx = t & 15, ty = t >> 4;
    const int lm = t >> 2, lk = (t & 3) << 2;
    const int wk = t >> 4, wng = (t & 15) << 2;
    float acc[4][4] = {};
    for (int k0 = 0; k0 < CIN; k0 += 16) {
        float4 av = *(const float4*)&Ab[(size_t)(m0 + lm) * CIN + k0 + lk];
        As[lk + 0][lm] = av.x; As[lk + 1][lm] = av.y;
        As[lk + 2][lm] = av.z; As[lk + 3][lm] = av.w;
        float4 wv = *(const float4*)&W[(size_t)(k0 + wk) * CH + wng];
        *(float4*)&Wsh[wk][wng] = wv;
        __syncthreads();
        #pragma unroll
        for (int k = 0; k < 16; ++k) {
            float4 a4 = *(const float4*)&As[k][ty << 2];
            float4 w4 = *(const float4*)&Wsh[k][tx << 2];
            float aa[4] = {a4.x, a4.y, a4.z, a4.w};
            float ww[4] = {w4.x, w4.y, w4.z, w4.w};
            #pragma unroll
            for (int i = 0; i < 4; ++i)
                #pragma unroll
                for (int j = 0; j < 4; ++j)
                    acc[i][j] = fmaf(aa[i], ww[j], acc[i][j]);
        }
        __syncthreads();
    }
    #pragma unroll
    for (int i = 0; i < 4; ++i) {
        int m = m0 + (ty << 2) + i;
        #pragma unroll
        for (int j = 0; j < 4; ++j)
            Cb[(size_t)m * CH + (tx << 2) + j] = acc[i][j];
    }
}

// ---------------------------------------------------------------- MFMA staged-segment inner loop (shared by PQ + node kernels)
#define LDK 40
__device__ __forceinline__ void mfma_seg(const ushort* __restrict__ Ab, int K, int m0,
                                         const ushort* __restrict__ Wt, int ldW, int wcol0,
                                         ushort* As, ushort* Wsm,
                                         int t, int wr, int wc, int fr, int fq,
                                         f32x4 (&acc)[4][4]) {
    const int sr = t >> 2, sk = (t & 3) * 8;
    for (int k0 = 0; k0 < K; k0 += 32) {
        #pragma unroll
        for (int p = 0; p < 2; ++p) {
            int r = sr + p * 64;
            *reinterpret_cast<int4*>(&As[r * LDK + sk]) =
                *reinterpret_cast<const int4*>(&Ab[(size_t)(m0 + r) * K + k0 + sk]);
            *reinterpret_cast<int4*>(&Wsm[r * LDK + sk]) =
                *reinterpret_cast<const int4*>(&Wt[(size_t)r * ldW + wcol0 + k0 + sk]);
        }
        __syncthreads();
        short8v af[4], wf[4];
        #pragma unroll
        for (int m = 0; m < 4; ++m)
            af[m] = *reinterpret_cast<const short8v*>(&As[(wr * 64 + m * 16 + fr) * LDK + fq * 8]);
        #pragma unroll
        for (int n = 0; n < 4; ++n)
            wf[n] = *reinterpret_cast<const short8v*>(&Wsm[(wc * 64 + n * 16 + fr) * LDK + fq * 8]);
        #pragma unroll
        for (int m = 0; m < 4; ++m)
            #pragma unroll
            for (int n = 0; n < 4; ++n)
                acc[m][n] = __builtin_amdgcn_mfma_f32_16x16x32_bf16(af[m], wf[n], acc[m][n], 0, 0, 0);
        __syncthreads();
    }
}

// ---------------------------------------------------------------- MFMA PQ GEMM (fine, bf16 out, N=128)
__global__ __launch_bounds__(256) void mfma_pq(
    const ushort* __restrict__ A1, int K1, const ushort* __restrict__ Wt, int ldW, int kPQ,
    ushort* __restrict__ P, ushort* __restrict__ Q, long sA1) {
    __shared__ ushort As[128 * LDK];
    __shared__ ushort Wsm[128 * LDK];
    const int t = threadIdx.x;
    const int lane = t & 63, wid = t >> 6;
    const int wr = wid >> 1, wc = wid & 1;
    const int fr = lane & 15, fq = lane >> 4;
    const int z = blockIdx.z;
    const int b = z >> 1, pq = z & 1;
    const int m0 = blockIdx.x * 128;
    f32x4 acc[4][4];
    #pragma unroll
    for (int m = 0; m < 4; ++m)
        #pragma unroll
        for (int n = 0; n < 4; ++n) acc[m][n] = (f32x4){0.f, 0.f, 0.f, 0.f};
    mfma_seg(A1 + (size_t)b * sA1, K1, m0, Wt, ldW, pq * kPQ, As, Wsm, t, wr, wc, fr, fq, acc);
    ushort* Cb = (pq ? Q : P) + (size_t)b * NF * 128;
    #pragma unroll
    for (int m = 0; m < 4; ++m)
        #pragma unroll
        for (int n = 0; n < 4; ++n) {
            int col = wc * 64 + n * 16 + fr;
            #pragma unroll
            for (int r = 0; r < 4; ++r) {
                int row = m0 + wr * 64 + m * 16 + fq * 4 + r;
                Cb[(size_t)row * 128 + col] = f2b(acc[m][n][r]);
            }
        }
}

// ---------------------------------------------------------------- fused dual-branch node GEMM:
// y = lrelu([x1up|agg2]@W2n + b2n) + lrelu([xup|aggS]@Wsn + bsn)
__global__ __launch_bounds__(256) void mfma_node2(
    const ushort* __restrict__ A1, const ushort* __restrict__ A2,
    const ushort* __restrict__ Wt1, const float* __restrict__ bias1,
    const ushort* __restrict__ A3, const ushort* __restrict__ A4,
    const ushort* __restrict__ Wt2, const float* __restrict__ bias2,
    float* __restrict__ y) {
    __shared__ ushort As[128 * LDK];
    __shared__ ushort Wsm[128 * LDK];
    const int t = threadIdx.x;
    const int lane = t & 63, wid = t >> 6;
    const int wr = wid >> 1, wc = wid & 1;
    const int fr = lane & 15, fq = lane >> 4;
    const int b = blockIdx.z;
    const int m0 = blockIdx.x * 128;
    f32x4 acc1[4][4], acc2[4][4];
    #pragma unroll
    for (int m = 0; m < 4; ++m)
        #pragma unroll
        for (int n = 0; n < 4; ++n) {
            acc1[m][n] = (f32x4){0.f, 0.f, 0.f, 0.f};
            acc2[m][n] = (f32x4){0.f, 0.f, 0.f, 0.f};
        }
    // branch 1: K = 64 (x1up) + 128 (agg2), ldW1 = 192
    mfma_seg(A1 + (size_t)b * NF * 64,  64,  m0, Wt1, 192, 0,   As, Wsm, t, wr, wc, fr, fq, acc1);
    mfma_seg(A2 + (size_t)b * NF * 128, 128, m0, Wt1, 192, 64,  As, Wsm, t, wr, wc, fr, fq, acc1);
    // branch 2: K = 128 (xup) + 128 (aggS), ldW2 = 256
    mfma_seg(A3 + (size_t)b * NF * 128, 128, m0, Wt2, 256, 0,   As, Wsm, t, wr, wc, fr, fq, acc2);
    mfma_seg(A4 + (size_t)b * NF * 128, 128, m0, Wt2, 256, 128, As, Wsm, t, wr, wc, fr, fq, acc2);
    float* Yb = y + (size_t)b * NF * 128;
    #pragma unroll
    for (int m = 0; m < 4; ++m)
        #pragma unroll
        for (int n = 0; n < 4; ++n) {
            int col = wc * 64 + n * 16 + fr;
            float bv1 = bias1[col], bv2 = bias2[col];
            #pragma unroll
            for (int r = 0; r < 4; ++r) {
                int row = m0 + wr * 64 + m * 16 + fq * 4 + r;
                float v1 = acc1[m][n][r] + bv1; v1 = v1 > 0.0f ? v1 : 0.01f * v1;
                float v2 = acc2[m][n][r] + bv2; v2 = v2 > 0.0f ? v2 : 0.01f * v2;
                Yb[(size_t)row * 128 + col] = v1 + v2;
            }
        }
}

// ---------------------------------------------------------------- fine weight transpose+bf16: Wt[n][k] = bf16(W[k][n])
__global__ void conv_wt(const float* __restrict__ W2e, const float* __restrict__ W2n,
                        const float* __restrict__ Wse, const float* __restrict__ Wsn,
                        ushort* __restrict__ W2eT, ushort* __restrict__ W2nT,
                        ushort* __restrict__ WseT, ushort* __restrict__ WsnT) {
    const float* src; ushort* dst; int K2;
    switch (blockIdx.y) {
        case 0: src = W2e; dst = W2eT; K2 = 128; break;
        case 1: src = W2n; dst = W2nT; K2 = 192; break;
        case 2: src = Wse; dst = WseT; K2 = 256; break;
        default: src = Wsn; dst = WsnT; K2 = 256; break;
    }
    int id = blockIdx.x * 256 + threadIdx.x;
    if (id >= K2 * 128) return;
    int n = id & 127, k = id >> 7;
    dst[(size_t)n * K2 + k] = f2b(src[id]);
}

// ---------------------------------------------------------------- edge message + aggregate (coarse, f32, C=64)
__global__ __launch_bounds__(256) void agg_csr_f32(const float* __restrict__ P,
                                                   const float* __restrict__ Q,
                                                   const float* __restrict__ bias,
                                                   const int* __restrict__ offs,
                                                   const int* __restrict__ counts,
                                                   const int* __restrict__ csr_src,
                                                   float* __restrict__ agg,
                                                   int N, int E) {
    const int b = blockIdx.y;
    const int dst = blockIdx.x * 4 + (threadIdx.x >> 6);
    const int lane = threadIdx.x & 63;
    const float* Pb = P + (size_t)b * N * 64;
    const float* Qb = Q + (size_t)b * N * 64;
    const int start = offs[b * N + dst];
    const int cnt = counts[b * N + dst];
    const int* sl = csr_src + (size_t)b * E + start;
    const float q = Qb[(size_t)dst * 64 + lane] + bias[lane];
    float a = 0.0f;
    for (int i = 0; i < cnt; ++i) {
        int src = sl[i];
        float m = Pb[(size_t)src * 64 + lane] + q; m = m > 0.0f ? m : 0.01f * m;
        a += m;
    }
    agg[(size_t)b * N * 64 + (size_t)dst * 64 + lane] = a;
}

// ---------------------------------------------------------------- edge message + aggregate (fine, bf16 io, C=128)
__global__ __launch_bounds__(256) void agg_csr_b16(const ushort* __restrict__ P,
                                                   const ushort* __restrict__ Q,
                                                   const float* __restrict__ bias,
                                                   const int* __restrict__ offs,
                                                   const int* __restrict__ counts,
                                                   const int* __restrict__ csr_src,
                                                   ushort* __restrict__ agg,
                                                   int N, int E) {
    const int b = blockIdx.y;
    const int dst = blockIdx.x * 4 + (threadIdx.x >> 6);
    const int lane = threadIdx.x & 63;
    const ushort* Pb = P + (size_t)b * N * 128;
    const ushort* Qb = Q + (size_t)b * N * 128;
    const int start = offs[b * N + dst];
    const int cnt = counts[b * N + dst];
    const int* sl = csr_src + (size_t)b * E + start;
    const int c0 = lane, c1 = lane + 64;
    const float q0 = b2f(Qb[(size_t)dst * 128 + c0]) + bias[c0];
    const float q1 = b2f(Qb[(size_t)dst * 128 + c1]) + bias[c1];
    float a0 = 0.0f, a1 = 0.0f;
    for (int i = 0; i < cnt; ++i) {
        int src = sl[i];
        float m0 = b2f(Pb[(size_t)src * 128 + c0]) + q0; m0 = m0 > 0.0f ? m0 : 0.01f * m0;
        float m1 = b2f(Pb[(size_t)src * 128 + c1]) + q1; m1 = m1 > 0.0f ? m1 : 0.01f * m1;
        a0 += m0; a1 += m1;
    }
    agg[(size_t)b * N * 128 + (size_t)dst * 128 + c0] = f2b(a0);
    agg[(size_t)b * N * 128 + (size_t)dst * 128 + c1] = f2b(a1);
}

// ---------------------------------------------------------------- batch-norm
__global__ void bn_stats(const float* __restrict__ xs, float* __restrict__ stats) {
    const int c = threadIdx.x;
    long r0 = (long)blockIdx.x * 256;
    float s = 0.0f, s2 = 0.0f;
    for (int r = 0; r < 256; ++r) {
        float v = xs[(r0 + r) * COUT + c];
        s += v;
        s2 = fmaf(v, v, s2);
    }
    atomicAdd(&stats[c], s);
    atomicAdd(&stats[COUT + c], s2);
}

__global__ void bn_final(float* __restrict__ xs, const float* __restrict__ stats,
                         const float* __restrict__ gamma, const float* __restrict__ beta,
                         float* __restrict__ wf) {
    long g = (long)blockIdx.x * 256 + threadIdx.x;
    int c = (int)(g & (COUT - 1));
    const float invN = 1.0f / (float)(B * NF);
    float mu = stats[c] * invN;
    float var = stats[COUT + c] * invN - mu * mu;
    float v = (xs[g] - mu) * rsqrtf(var + 1e-5f) * gamma[c] + beta[c];
    xs[g] = v > 0.0f ? v : 0.01f * v;
    if (g < (long)B * NF) wf[g] = 0.0f;      // fold w_fine zeroing in
}

__global__ void wfine_scatter(const float* __restrict__ wts, const int* __restrict__ mask,
                              float* __restrict__ wf) {
    int i = blockIdx.x * 256 + threadIdx.x;
    int b = i / NC;
    wf[(size_t)b * NF + mask[i]] = wts[i];
}

extern "C" void kernel_launch(void* const* d_in, const int* in_sizes, int n_in,
                              void* d_out, int out_size, void* d_ws, size_t ws_size,
                              hipStream_t stream) {
    const float* x    = (const float*)d_in[0];
    const float* wts  = (const float*)d_in[1];
    const float* pos  = (const float*)d_in[2];
    const float* W1e  = (const float*)d_in[3];
    const float* b1e  = (const float*)d_in[4];
    const float* W1n  = (const float*)d_in[5];
    const float* b1n  = (const float*)d_in[6];
    const float* W2e  = (const float*)d_in[7];
    const float* b2e  = (const float*)d_in[8];
    const float* W2n  = (const float*)d_in[9];
    const float* b2n  = (const float*)d_in[10];
    const float* Wse  = (const float*)d_in[11];
    const float* bse  = (const float*)d_in[12];
    const float* Wsn  = (const float*)d_in[13];
    const float* bsn  = (const float*)d_in[14];
    const float* gamma= (const float*)d_in[15];
    const float* beta = (const float*)d_in[16];
    const int*   mask = (const int*)d_in[17];
    const int*   ec   = (const int*)d_in[18];
    const int*   ef   = (const int*)d_in[19];

    float* ws = (float*)d_ws;
    // ---- f32 region
    int*    idxb  = (int*)ws;                              // B*NF*3
    float*  wnb   = ws + 98304;                            // B*NF*3
    float4* sposg = (float4*)(ws + 196608);                // B*NC float4 (z-sorted)
    float*  x1    = ws + 196608 + 32768;                   // B*NC*CH
    float*  PbC   = x1  + (size_t)B * NC * CH;
    float*  QbC   = PbC + (size_t)B * NC * CH;
    float*  aggC  = QbC + (size_t)B * NC * CH;
    float*  stats = aggC+ (size_t)B * NC * CH;             // 256
    // ---- int region (counts contiguous for single memset)
    int* cntC  = (int*)(stats + 256);                      // B*NC
    int* cntF  = cntC + B * NC;                            // B*NF
    int* cntZ  = cntF + B * NF;                            // B*ZB
    int* offC  = cntZ + B * ZB;                            // B*NC
    int* curC  = offC + B * NC;
    int* offF  = curC + B * NC;                            // B*NF
    int* curF  = offF + B * NF;
    int* offZ  = curF + B * NF;                            // B*(ZB+1)
    int* curZ  = offZ + B * (ZB + 1);
    int* csrC  = curZ + B * (ZB + 1);                      // B*EC
    int* csrF  = csrC + B * EC;                            // B*EF
    // ---- bf16 region (32B aligned)
    size_t foff = (size_t)(csrF + (size_t)B * EF - (int*)ws);
    foff = (foff + 7) & ~(size_t)7;
    ushort* xupb  = (ushort*)(ws + foff);                  // B*NF*128
    ushort* x1upb = xupb  + (size_t)B * NF * 128;          // B*NF*64
    ushort* Pb    = x1upb + (size_t)B * NF * 64;           // B*NF*128
    ushort* Qb    = Pb    + (size_t)B * NF * 128;          // B*NF*128
    ushort* agg2b = Qb    + (size_t)B * NF * 128;          // B*NF*128  (mpl2 agg)
    ushort* aggSb = agg2b + (size_t)B * NF * 128;          // B*NF*128  (skip agg)
    ushort* W2eT  = aggSb + (size_t)B * NF * 128;          // 128*128
    ushort* W2nT  = W2eT  + 128 * 128;                     // 128*192
    ushort* WseT  = W2nT  + 128 * 192;                     // 128*256
    ushort* WsnT  = WseT  + 128 * 256;                     // 128*256

    float* y  = (float*)d_out;                             // B*NF*128
    float* wf = y + (size_t)B * NF * COUT;                 // B*NF

    // ---- prep: weights, counts (one memset), scans, fills
    conv_wt<<<dim3(128, 4), 256, 0, stream>>>(W2e, W2n, Wse, Wsn, W2eT, W2nT, WseT, WsnT);
    hipMemsetAsync(cntC, 0, (size_t)B * (NC + NF + ZB) * 4, stream);
    count_all<<<dim3(EF / 256, B, 3), 256, 0, stream>>>(ec, ef, mask, pos, cntC, cntF, cntZ);
    scan_all<<<dim3(3 * B), 1024, 0, stream>>>(cntC, offC, curC, cntF, offF, curF, cntZ, offZ, curZ);
    fill_all<<<dim3(EF / 256, B, 3), 256, 0, stream>>>(ec, ef, mask, pos, curC, curF, curZ,
                                                       csrC, csrF, sposg);

    // ---- knn (z-window brute force, exact with fallback)
    knn_bf<<<dim3(NF / 8, B), 256, 0, stream>>>(pos, sposg, offZ, idxb, wnb);

    // ---- x_up = interp(x) -> bf16  (C=128: 32 lanes/node)
    interp_b16<5><<<dim3(NF / 8, B), 256, 0, stream>>>(x, idxb, wnb, xupb);

    // ---- main branch: mpl1 on coarse graph (f32 path)
    gemm_pq64<<<dim3(NC / 64, 1, B * 2), 256, 0, stream>>>(x, W1e, PbC, QbC);
    agg_csr_f32<<<dim3(NC / 4, B), 256, 0, stream>>>(
        PbC, QbC, b1e, offC, cntC, csrC, aggC, NC, EC);
    gemm_kernel<<<dim3(1, NC / 64, B), 256, 0, stream>>>(
        x, CIN, aggC, CH, W1n, b1n, x1, NC, CH, 1, (long)NC * CIN, (long)NC * CH, (long)NC * CH);

    // ---- x1_up = interp(x1) -> bf16  (C=64: 16 lanes/node)
    interp_b16<4><<<dim3(NF / 16, B), 256, 0, stream>>>(x1, idxb, wnb, x1upb);

    // ---- mpl2 edge phase (MFMA PQ + CSR agg) -> agg2b
    mfma_pq<<<dim3(NF / 128, 1, B * 2), 256, 0, stream>>>(
        x1upb, CH, W2eT, 128, CH, Pb, Qb, (long)NF * CH);
    agg_csr_b16<<<dim3(NF / 4, B), 256, 0, stream>>>(
        Pb, Qb, b2e, offF, cntF, csrF, agg2b, NF, EF);

    // ---- skip edge phase -> aggSb
    mfma_pq<<<dim3(NF / 128, 1, B * 2), 256, 0, stream>>>(
        xupb, CIN, WseT, 256, CIN, Pb, Qb, (long)NF * CIN);
    agg_csr_b16<<<dim3(NF / 4, B), 256, 0, stream>>>(
        Pb, Qb, bse, offF, cntF, csrF, aggSb, NF, EF);

    // ---- fused dual-branch node GEMM -> y (single write, no RMW)
    mfma_node2<<<dim3(NF / 128, 1, B), 256, 0, stream>>>(
        x1upb, agg2b, W2nT, b2n, xupb, aggSb, WsnT, bsn, y);

    // ---- batch norm + lrelu (+ wf zero), then w_fine scatter
    hipMemsetAsync(stats, 0, 256 * 4, stream);
    bn_stats<<<dim3((B * NF) / 256), COUT, 0, stream>>>(y, stats);
    bn_final<<<dim3((long)B * NF * COUT / 256), 256, 0, stream>>>(y, stats, gamma, beta, wf);
    wfine_scatter<<<dim3(B * NC / 256), 256, 0, stream>>>(wts, mask, wf);
}

// Round 9
// 228.174 us; speedup vs baseline: 3.2723x; 1.0913x over previous
//
#include <hip/hip_runtime.h>
#include <hip/hip_bf16.h>
#include <cfloat>

#define B 4
#define NC 2048
#define NF 8192
#define CIN 128
#define CH 64
#define COUT 128
#define EC 16384
#define EF 65536
#define ZB 256          // z-sort bins

typedef __attribute__((ext_vector_type(8))) short short8v;
typedef __attribute__((ext_vector_type(4))) float f32x4;

__device__ __forceinline__ ushort f2b(float v) {
    __hip_bfloat16 h = __float2bfloat16(v);
    return *reinterpret_cast<ushort*>(&h);
}
__device__ __forceinline__ float b2f(ushort u) {
    __hip_bfloat16 h = *reinterpret_cast<__hip_bfloat16*>(&u);
    return __bfloat162float(h);
}

// ---------------------------------------------------------------- combined count: coarse hist / fine hist / z-bin hist
__global__ void count_all(const int* __restrict__ ec, const int* __restrict__ ef,
                          const int* __restrict__ mask, const float* __restrict__ pos,
                          int* __restrict__ cntC, int* __restrict__ cntF, int* __restrict__ cntZ) {
    const int b = blockIdx.y, z = blockIdx.z;
    const int i = blockIdx.x * 256 + threadIdx.x;
    if (z == 0) {
        if (i < EC) atomicAdd(&cntC[b * NC + ec[(size_t)b * 2 * EC + EC + i]], 1);
    } else if (z == 1) {
        if (i < EF) atomicAdd(&cntF[b * NF + ef[(size_t)b * 2 * EF + EF + i]], 1);
    } else {
        if (i < NC) {
            int m = mask[b * NC + i];
            float pz = pos[((size_t)b * NF + m) * 3 + 2];
            int zb = min(max((int)(pz * (float)ZB), 0), ZB - 1);
            atomicAdd(&cntZ[b * ZB + zb], 1);
        }
    }
}

// ---------------------------------------------------------------- combined exclusive scan (grid = 3*B blocks)
template<int N, int OSTR, bool EXTRA>
__device__ __forceinline__ void scan_body(const int* __restrict__ cnt, int* __restrict__ offs,
                                          int* __restrict__ cur, int b, int* part) {
    const int tid = threadIdx.x;
    constexpr int PER = (N + 1023) / 1024;
    int local[PER];
    int s = 0;
    #pragma unroll
    for (int i = 0; i < PER; ++i) {
        int id = tid * PER + i;
        local[i] = s;
        if (id < N) s += cnt[b * N + id];
    }
    part[tid] = s;
    __syncthreads();
    for (int off = 1; off < 1024; off <<= 1) {
        int v = (tid >= off) ? part[tid - off] : 0;
        __syncthreads();
        part[tid] += v;
        __syncthreads();
    }
    int pre = tid ? part[tid - 1] : 0;
    #pragma unroll
    for (int i = 0; i < PER; ++i) {
        int id = tid * PER + i;
        if (id < N) {
            int o = pre + local[i];
            offs[b * OSTR + id] = o;
            cur[b * OSTR + id] = o;
        }
    }
    if (EXTRA && tid == 1023) offs[b * OSTR + N] = part[1023];
}

__global__ __launch_bounds__(1024) void scan_all(
    const int* __restrict__ cntC, int* __restrict__ offC, int* __restrict__ curC,
    const int* __restrict__ cntF, int* __restrict__ offF, int* __restrict__ curF,
    const int* __restrict__ cntZ, int* __restrict__ offZ, int* __restrict__ curZ) {
    __shared__ int part[1024];
    const int cfg = blockIdx.x >> 2;   // B == 4
    const int b = blockIdx.x & 3;
    if (cfg == 0)      scan_body<NC, NC, false>(cntC, offC, curC, b, part);
    else if (cfg == 1) scan_body<NF, NF, false>(cntF, offF, curF, b, part);
    else               scan_body<ZB, ZB + 1, true>(cntZ, offZ, curZ, b, part);
}

// ---------------------------------------------------------------- combined fill: CSRs / z-sorted coarse positions
__global__ void fill_all(const int* __restrict__ ec, const int* __restrict__ ef,
                         const int* __restrict__ mask, const float* __restrict__ pos,
                         int* __restrict__ curC, int* __restrict__ curF, int* __restrict__ curZ,
                         int* __restrict__ csrC, int* __restrict__ csrF,
                         float4* __restrict__ sposg) {
    const int b = blockIdx.y, z = blockIdx.z;
    const int i = blockIdx.x * 256 + threadIdx.x;
    if (z == 0) {
        if (i < EC) {
            const int* eb = ec + (size_t)b * 2 * EC;
            int src = eb[i], dst = eb[EC + i];
            int p = atomicAdd(&curC[b * NC + dst], 1);
            csrC[(size_t)b * EC + p] = src;
        }
    } else if (z == 1) {
        if (i < EF) {
            const int* eb = ef + (size_t)b * 2 * EF;
            int src = eb[i], dst = eb[EF + i];
            int p = atomicAdd(&curF[b * NF + dst], 1);
            csrF[(size_t)b * EF + p] = src;
        }
    } else {
        if (i < NC) {
            int m = mask[b * NC + i];
            const float* p = pos + ((size_t)b * NF + m) * 3;
            float px = p[0], py = p[1], pz = p[2];
            int zb = min(max((int)(pz * (float)ZB), 0), ZB - 1);
            int slot = atomicAdd(&curZ[b * (ZB + 1) + zb], 1);
            sposg[(size_t)b * NC + slot] = make_float4(px, py, pz, __int_as_float(i));
        }
    }
}

// ---------------------------------------------------------------- top-3 insert helper
__device__ __forceinline__ void ins3(float d, int c, float& d0, float& d1, float& d2,
                                     int& i0, int& i1, int& i2) {
    bool lt0 = d < d0, lt1 = d < d1, lt2 = d < d2;
    d2 = lt1 ? d1 : (lt2 ? d : d2);  i2 = lt1 ? i1 : (lt2 ? c : i2);
    d1 = lt0 ? d0 : (lt1 ? d : d1);  i1 = lt0 ? i0 : (lt1 ? c : i1);
    d0 = lt0 ? d  : d0;              i0 = lt0 ? c  : i0;
}
__device__ __forceinline__ void merge32(float& d0, float& d1, float& d2,
                                        int& i0, int& i1, int& i2) {
    #pragma unroll
    for (int off = 1; off <= 16; off <<= 1) {
        float od[3]; int oi[3];
        od[0] = __shfl_xor(d0, off); oi[0] = __shfl_xor(i0, off);
        od[1] = __shfl_xor(d1, off); oi[1] = __shfl_xor(i1, off);
        od[2] = __shfl_xor(d2, off); oi[2] = __shfl_xor(i2, off);
        #pragma unroll
        for (int j = 0; j < 3; ++j) ins3(od[j], oi[j], d0, d1, d2, i0, i1, i2);
    }
}

// ---------------------------------------------------------------- fused knn (z-window) + x_up interpolation (C=128)
__global__ __launch_bounds__(256) void knn_interp(const float* __restrict__ pos,
                                                  const float4* __restrict__ sposg,
                                                  const int* __restrict__ offZ,
                                                  const float* __restrict__ xc,
                                                  int* __restrict__ idx,
                                                  float* __restrict__ wn,
                                                  ushort* __restrict__ xup) {
    const int b = blockIdx.y;
    const int tid = threadIdx.x;
    const int node = blockIdx.x * 8 + (tid >> 5);
    const int lane = tid & 31;
    const float* pf = pos + ((size_t)b * NF + node) * 3;
    const float px = pf[0], py = pf[1], pz = pf[2];
    const float4* sp = sposg + (size_t)b * NC;
    const int zb = min(max((int)(pz * (float)ZB), 0), ZB - 1);
    const int zlo = max(zb - 32, 0), zhi = min(zb + 32, ZB - 1);
    const int j0 = offZ[b * (ZB + 1) + zlo];
    const int j1 = offZ[b * (ZB + 1) + zhi + 1];
    float d0 = FLT_MAX, d1 = FLT_MAX, d2 = FLT_MAX;
    int i0 = 0, i1 = 0, i2 = 0;
    for (int j = j0 + lane; j < j1; j += 32) {
        float4 s = sp[j];
        // match numpy: diff, square, sequential sum — no FMA contraction
        float ddx = __fsub_rn(px, s.x);
        float ddy = __fsub_rn(py, s.y);
        float ddz = __fsub_rn(pz, s.z);
        float d = __fadd_rn(__fadd_rn(__fmul_rn(ddx, ddx), __fmul_rn(ddy, ddy)),
                            __fmul_rn(ddz, ddz));
        ins3(d, __float_as_int(s.w), d0, d1, d2, i0, i1, i2);
    }
    merge32(d0, d1, d2, i0, i1, i2);
    // exact bound vs. the unsearched z-slabs
    float bd = 1e30f;
    if (zlo > 0)      bd = fminf(bd, pz - (float)zlo * (1.0f / ZB));
    if (zhi < ZB - 1) bd = fminf(bd, (float)(zhi + 1) * (1.0f / ZB) - pz);
    bd *= 0.9999f;
    if (__any(d2 > bd * bd)) {
        // rare: full exact rescan (wave-coherent)
        d0 = d1 = d2 = FLT_MAX; i0 = i1 = i2 = 0;
        for (int j = lane; j < NC; j += 32) {
            float4 s = sp[j];
            float ddx = __fsub_rn(px, s.x);
            float ddy = __fsub_rn(py, s.y);
            float ddz = __fsub_rn(pz, s.z);
            float d = __fadd_rn(__fadd_rn(__fmul_rn(ddx, ddx), __fmul_rn(ddy, ddy)),
                                __fmul_rn(ddz, ddz));
            ins3(d, __float_as_int(s.w), d0, d1, d2, i0, i1, i2);
        }
        merge32(d0, d1, d2, i0, i1, i2);
    }
    // all 32 lanes now hold the merged top-3
    float w0 = 1.0f / (d0 + 1e-16f);
    float w1 = 1.0f / (d1 + 1e-16f);
    float w2 = 1.0f / (d2 + 1e-16f);
    float inv = 1.0f / (w0 + w1 + w2);
    w0 *= inv; w1 *= inv; w2 *= inv;
    if (lane == 0) {
        size_t o = ((size_t)b * NF + node) * 3;
        idx[o] = i0; idx[o + 1] = i1; idx[o + 2] = i2;
        wn[o] = w0; wn[o + 1] = w1; wn[o + 2] = w2;
    }
    // fused x_up interpolation: lane owns 4 channels
    const float* xb = xc + (size_t)b * NC * CIN;
    float4 a = *(const float4*)&xb[(size_t)i0 * CIN + lane * 4];
    float4 bb = *(const float4*)&xb[(size_t)i1 * CIN + lane * 4];
    float4 cc = *(const float4*)&xb[(size_t)i2 * CIN + lane * 4];
    ushort4 u;
    u.x = f2b(w0 * a.x + w1 * bb.x + w2 * cc.x);
    u.y = f2b(w0 * a.y + w1 * bb.y + w2 * cc.y);
    u.z = f2b(w0 * a.z + w1 * bb.z + w2 * cc.z);
    u.w = f2b(w0 * a.w + w1 * bb.w + w2 * cc.w);
    *(ushort4*)&xup[((size_t)b * NF + node) * CIN + lane * 4] = u;
}

// ---------------------------------------------------------------- weighted 3-NN gather, bf16 out (vectorized)
template<int S>
__global__ __launch_bounds__(256) void interp_b16(const float* __restrict__ xc,
                                                  const int* __restrict__ idx,
                                                  const float* __restrict__ wn,
                                                  ushort* __restrict__ out) {
    constexpr int C = 4 << S;
    const int b = blockIdx.y;
    const int node = blockIdx.x * (256 >> S) + (threadIdx.x >> S);
    const int lane = threadIdx.x & ((1 << S) - 1);
    size_t o = ((size_t)b * NF + node) * 3;
    int i0 = idx[o], i1 = idx[o + 1], i2 = idx[o + 2];
    float w0 = wn[o], w1 = wn[o + 1], w2 = wn[o + 2];
    const float* xb = xc + (size_t)b * NC * C;
    float4 a = *(const float4*)&xb[(size_t)i0 * C + lane * 4];
    float4 bb = *(const float4*)&xb[(size_t)i1 * C + lane * 4];
    float4 cc = *(const float4*)&xb[(size_t)i2 * C + lane * 4];
    ushort4 u;
    u.x = f2b(w0 * a.x + w1 * bb.x + w2 * cc.x);
    u.y = f2b(w0 * a.y + w1 * bb.y + w2 * cc.y);
    u.z = f2b(w0 * a.z + w1 * bb.z + w2 * cc.z);
    u.w = f2b(w0 * a.w + w1 * bb.w + w2 * cc.w);
    *(ushort4*)&out[((size_t)b * NF + node) * C + lane * 4] = u;
}

// ---------------------------------------------------------------- f32 GEMM (coarse node MLP)
__global__ __launch_bounds__(256) void gemm_kernel(
    const float* __restrict__ A1, int K1, const float* __restrict__ A2, int K2,
    const float* __restrict__ W, const float* __restrict__ bias,
    float* __restrict__ Cmat, int M, int N, int flags,
    long sA1, long sA2, long sC) {
    __shared__ float As[16][64];
    __shared__ float Wsh[16][64];
    const int b = blockIdx.z;
    const int m0 = blockIdx.y * 64, n0 = blockIdx.x * 64;
    const int t = threadIdx.x;
    const int tx = t & 15, ty = t >> 4;
    float acc[4][4] = {};
    int kOff = 0;
    for (int s = 0; s < 2; ++s) {
        const float* A = (s == 0) ? A1 : A2;
        const int K = (s == 0) ? K1 : K2;
        const long sA = (s == 0) ? sA1 : sA2;
        if (A == nullptr || K == 0) continue;
        const float* Ab = A + (size_t)b * sA;
        const int lm = t >> 2;
        const int lk = (t & 3) << 2;
        const int wk = t >> 4;
        const int wng = (t & 15) << 2;
        for (int k0 = 0; k0 < K; k0 += 16) {
            float4 av = *(const float4*)&Ab[(size_t)(m0 + lm) * K + k0 + lk];
            As[lk + 0][lm] = av.x; As[lk + 1][lm] = av.y;
            As[lk + 2][lm] = av.z; As[lk + 3][lm] = av.w;
            float4 wv = *(const float4*)&W[(size_t)(kOff + k0 + wk) * N + n0 + wng];
            *(float4*)&Wsh[wk][wng] = wv;
            __syncthreads();
            #pragma unroll
            for (int k = 0; k < 16; ++k) {
                float4 a4 = *(const float4*)&As[k][ty << 2];
                float4 w4 = *(const float4*)&Wsh[k][tx << 2];
                float aa[4] = {a4.x, a4.y, a4.z, a4.w};
                float ww[4] = {w4.x, w4.y, w4.z, w4.w};
                #pragma unroll
                for (int i = 0; i < 4; ++i)
                    #pragma unroll
                    for (int j = 0; j < 4; ++j)
                        acc[i][j] = fmaf(aa[i], ww[j], acc[i][j]);
            }
            __syncthreads();
        }
        kOff += K;
    }
    float* Cb = Cmat + (size_t)b * sC;
    #pragma unroll
    for (int i = 0; i < 4; ++i) {
        int m = m0 + (ty << 2) + i;
        #pragma unroll
        for (int j = 0; j < 4; ++j) {
            int n = n0 + (tx << 2) + j;
            float v = acc[i][j];
            if (bias) v += bias[n];
            if (flags & 1) v = v > 0.0f ? v : 0.01f * v;
            float* cp = &Cb[(size_t)m * N + n];
            if (flags & 2) v += *cp;
            *cp = v;
        }
    }
}

// ---------------------------------------------------------------- coarse P/Q GEMM merged (M=NC, N=64, K=128)
__global__ __launch_bounds__(256) void gemm_pq64(const float* __restrict__ x,
                                                 const float* __restrict__ W1e,
                                                 float* __restrict__ Pb,
                                                 float* __restrict__ Qb) {
    __shared__ float As[16][64];
    __shared__ float Wsh[16][64];
    const int z = blockIdx.z;
    const int b = z >> 1, pq = z & 1;
    const int m0 = blockIdx.x * 64;
    const float* Ab = x + (size_t)b * NC * CIN;
    const float* W = W1e + pq * CIN * CH;
    float* Cb = (pq ? Qb : Pb) + (size_t)b * NC * CH;
    const int t = threadIdx.x;
    const int tx = t & 15, ty = t >> 4;
    const int lm = t >> 2, lk = (t & 3) << 2;
    const int wk = t >> 4, wng = (t & 15) << 2;
    float acc[4][4] = {};
    for (int k0 = 0; k0 < CIN; k0 += 16) {
        float4 av = *(const float4*)&Ab[(size_t)(m0 + lm) * CIN + k0 + lk];
        As[lk + 0][lm] = av.x; As[lk + 1][lm] = av.y;
        As[lk + 2][lm] = av.z; As[lk + 3][lm] = av.w;
        float4 wv = *(const float4*)&W[(size_t)(k0 + wk) * CH + wng];
        *(float4*)&Wsh[wk][wng] = wv;
        __syncthreads();
        #pragma unroll
        for (int k = 0; k < 16; ++k) {
            float4 a4 = *(const float4*)&As[k][ty << 2];
            float4 w4 = *(const float4*)&Wsh[k][tx << 2];
            float aa[4] = {a4.x, a4.y, a4.z, a4.w};
            float ww[4] = {w4.x, w4.y, w4.z, w4.w};
            #pragma unroll
            for (int i = 0; i < 4; ++i)
                #pragma unroll
                for (int j = 0; j < 4; ++j)
                    acc[i][j] = fmaf(aa[i], ww[j], acc[i][j]);
        }
        __syncthreads();
    }
    #pragma unroll
    for (int i = 0; i < 4; ++i) {
        int m = m0 + (ty << 2) + i;
        #pragma unroll
        for (int j = 0; j < 4; ++j)
            Cb[(size_t)m * CH + (tx << 2) + j] = acc[i][j];
    }
}

// ---------------------------------------------------------------- MFMA staged-segment inner loop
#define LDK 40
__device__ __forceinline__ void mfma_seg(const ushort* __restrict__ Ab, int K, int m0,
                                         const ushort* __restrict__ Wt, int ldW, int wcol0,
                                         ushort* As, ushort* Wsm,
                                         int t, int wr, int wc, int fr, int fq,
                                         f32x4 (&acc)[4][4]) {
    const int sr = t >> 2, sk = (t & 3) * 8;
    for (int k0 = 0; k0 < K; k0 += 32) {
        #pragma unroll
        for (int p = 0; p < 2; ++p) {
            int r = sr + p * 64;
            *reinterpret_cast<int4*>(&As[r * LDK + sk]) =
                *reinterpret_cast<const int4*>(&Ab[(size_t)(m0 + r) * K + k0 + sk]);
            *reinterpret_cast<int4*>(&Wsm[r * LDK + sk]) =
                *reinterpret_cast<const int4*>(&Wt[(size_t)r * ldW + wcol0 + k0 + sk]);
        }
        __syncthreads();
        short8v af[4], wf[4];
        #pragma unroll
        for (int m = 0; m < 4; ++m)
            af[m] = *reinterpret_cast<const short8v*>(&As[(wr * 64 + m * 16 + fr) * LDK + fq * 8]);
        #pragma unroll
        for (int n = 0; n < 4; ++n)
            wf[n] = *reinterpret_cast<const short8v*>(&Wsm[(wc * 64 + n * 16 + fr) * LDK + fq * 8]);
        #pragma unroll
        for (int m = 0; m < 4; ++m)
            #pragma unroll
            for (int n = 0; n < 4; ++n)
                acc[m][n] = __builtin_amdgcn_mfma_f32_16x16x32_bf16(af[m], wf[n], acc[m][n], 0, 0, 0);
        __syncthreads();
    }
}

// ---------------------------------------------------------------- both branches' PQ GEMMs in one launch
__global__ __launch_bounds__(256) void mfma_pq_both(
    const ushort* __restrict__ x1upb, const ushort* __restrict__ xupb,
    const ushort* __restrict__ W2eT, const ushort* __restrict__ WseT,
    ushort* __restrict__ P2, ushort* __restrict__ Q2,
    ushort* __restrict__ PS, ushort* __restrict__ QS) {
    __shared__ ushort As[128 * LDK];
    __shared__ ushort Wsm[128 * LDK];
    const int t = threadIdx.x;
    const int lane = t & 63, wid = t >> 6;
    const int wr = wid >> 1, wc = wid & 1;
    const int fr = lane & 15, fq = lane >> 4;
    const int z = blockIdx.z;
    const int b = z >> 2, sel = z & 3;
    const int br = sel >> 1, pq = sel & 1;
    const int m0 = blockIdx.x * 128;
    f32x4 acc[4][4];
    #pragma unroll
    for (int m = 0; m < 4; ++m)
        #pragma unroll
        for (int n = 0; n < 4; ++n) acc[m][n] = (f32x4){0.f, 0.f, 0.f, 0.f};
    ushort* outp;
    if (br == 0) {
        mfma_seg(x1upb + (size_t)b * NF * 64, 64, m0, W2eT, 128, pq * 64,
                 As, Wsm, t, wr, wc, fr, fq, acc);
        outp = pq ? Q2 : P2;
    } else {
        mfma_seg(xupb + (size_t)b * NF * 128, 128, m0, WseT, 256, pq * 128,
                 As, Wsm, t, wr, wc, fr, fq, acc);
        outp = pq ? QS : PS;
    }
    ushort* Cb = outp + (size_t)b * NF * 128;
    #pragma unroll
    for (int m = 0; m < 4; ++m)
        #pragma unroll
        for (int n = 0; n < 4; ++n) {
            int col = wc * 64 + n * 16 + fr;
            #pragma unroll
            for (int r = 0; r < 4; ++r) {
                int row = m0 + wr * 64 + m * 16 + fq * 4 + r;
                Cb[(size_t)row * 128 + col] = f2b(acc[m][n][r]);
            }
        }
}

// ---------------------------------------------------------------- fused dual-branch node GEMM + BN stats:
// y = lrelu([x1up|agg2]@W2n + b2n) + lrelu([xup|aggS]@Wsn + bsn); stats += (sum, sumsq)
__global__ __launch_bounds__(256) void mfma_node2(
    const ushort* __restrict__ A1, const ushort* __restrict__ A2,
    const ushort* __restrict__ Wt1, const float* __restrict__ bias1,
    const ushort* __restrict__ A3, const ushort* __restrict__ A4,
    const ushort* __restrict__ Wt2, const float* __restrict__ bias2,
    float* __restrict__ y, float* __restrict__ stats) {
    __shared__ ushort As[128 * LDK];
    __shared__ ushort Wsm[128 * LDK];
    const int t = threadIdx.x;
    const int lane = t & 63, wid = t >> 6;
    const int wr = wid >> 1, wc = wid & 1;
    const int fr = lane & 15, fq = lane >> 4;
    const int b = blockIdx.z;
    const int m0 = blockIdx.x * 128;
    f32x4 acc1[4][4], acc2[4][4];
    #pragma unroll
    for (int m = 0; m < 4; ++m)
        #pragma unroll
        for (int n = 0; n < 4; ++n) {
            acc1[m][n] = (f32x4){0.f, 0.f, 0.f, 0.f};
            acc2[m][n] = (f32x4){0.f, 0.f, 0.f, 0.f};
        }
    mfma_seg(A1 + (size_t)b * NF * 64,  64,  m0, Wt1, 192, 0,   As, Wsm, t, wr, wc, fr, fq, acc1);
    mfma_seg(A2 + (size_t)b * NF * 128, 128, m0, Wt1, 192, 64,  As, Wsm, t, wr, wc, fr, fq, acc1);
    mfma_seg(A3 + (size_t)b * NF * 128, 128, m0, Wt2, 256, 0,   As, Wsm, t, wr, wc, fr, fq, acc2);
    mfma_seg(A4 + (size_t)b * NF * 128, 128, m0, Wt2, 256, 128, As, Wsm, t, wr, wc, fr, fq, acc2);
    float* Yb = y + (size_t)b * NF * 128;
    float lsum[4] = {0.f, 0.f, 0.f, 0.f}, lsq[4] = {0.f, 0.f, 0.f, 0.f};
    #pragma unroll
    for (int m = 0; m < 4; ++m)
        #pragma unroll
        for (int n = 0; n < 4; ++n) {
            int col = wc * 64 + n * 16 + fr;
            float bv1 = bias1[col], bv2 = bias2[col];
            #pragma unroll
            for (int r = 0; r < 4; ++r) {
                int row = m0 + wr * 64 + m * 16 + fq * 4 + r;
                float v1 = acc1[m][n][r] + bv1; v1 = v1 > 0.0f ? v1 : 0.01f * v1;
                float v2 = acc2[m][n][r] + bv2; v2 = v2 > 0.0f ? v2 : 0.01f * v2;
                float v = v1 + v2;
                Yb[(size_t)row * 128 + col] = v;
                lsum[n] += v;
                lsq[n] = fmaf(v, v, lsq[n]);
            }
        }
    // block-level BN stat reduction (reuse As LDS as float scratch)
    __syncthreads();
    float* ssum = reinterpret_cast<float*>(As);
    float* ssq  = ssum + 128;
    if (t < 128) { ssum[t] = 0.0f; ssq[t] = 0.0f; }
    __syncthreads();
    #pragma unroll
    for (int n = 0; n < 4; ++n) {
        int col = wc * 64 + n * 16 + fr;
        atomicAdd(&ssum[col], lsum[n]);
        atomicAdd(&ssq[col], lsq[n]);
    }
    __syncthreads();
    if (t < 128) {
        atomicAdd(&stats[t], ssum[t]);
        atomicAdd(&stats[128 + t], ssq[t]);
    }
}

// ---------------------------------------------------------------- fine weight transpose+bf16: Wt[n][k] = bf16(W[k][n])
__global__ void conv_wt(const float* __restrict__ W2e, const float* __restrict__ W2n,
                        const float* __restrict__ Wse, const float* __restrict__ Wsn,
                        ushort* __restrict__ W2eT, ushort* __restrict__ W2nT,
                        ushort* __restrict__ WseT, ushort* __restrict__ WsnT) {
    const float* src; ushort* dst; int K2;
    switch (blockIdx.y) {
        case 0: src = W2e; dst = W2eT; K2 = 128; break;
        case 1: src = W2n; dst = W2nT; K2 = 192; break;
        case 2: src = Wse; dst = WseT; K2 = 256; break;
        default: src = Wsn; dst = WsnT; K2 = 256; break;
    }
    int id = blockIdx.x * 256 + threadIdx.x;
    if (id >= K2 * 128) return;
    int n = id & 127, k = id >> 7;
    dst[(size_t)n * K2 + k] = f2b(src[id]);
}

// ---------------------------------------------------------------- edge message + aggregate (coarse, f32, C=64)
__global__ __launch_bounds__(256) void agg_csr_f32(const float* __restrict__ P,
                                                   const float* __restrict__ Q,
                                                   const float* __restrict__ bias,
                                                   const int* __restrict__ offs,
                                                   const int* __restrict__ counts,
                                                   const int* __restrict__ csr_src,
                                                   float* __restrict__ agg,
                                                   int N, int E) {
    const int b = blockIdx.y;
    const int dst = blockIdx.x * 4 + (threadIdx.x >> 6);
    const int lane = threadIdx.x & 63;
    const float* Pb = P + (size_t)b * N * 64;
    const float* Qb = Q + (size_t)b * N * 64;
    const int start = offs[b * N + dst];
    const int cnt = counts[b * N + dst];
    const int* sl = csr_src + (size_t)b * E + start;
    const float q = Qb[(size_t)dst * 64 + lane] + bias[lane];
    float a = 0.0f;
    for (int i = 0; i < cnt; ++i) {
        int src = sl[i];
        float m = Pb[(size_t)src * 64 + lane] + q; m = m > 0.0f ? m : 0.01f * m;
        a += m;
    }
    agg[(size_t)b * N * 64 + (size_t)dst * 64 + lane] = a;
}

// ---------------------------------------------------------------- both fine agg passes in one launch (bf16 io, C=128)
__global__ __launch_bounds__(256) void agg_csr_b16(const ushort* __restrict__ P2,
                                                   const ushort* __restrict__ Q2,
                                                   const float* __restrict__ b2,
                                                   const ushort* __restrict__ PS,
                                                   const ushort* __restrict__ QS,
                                                   const float* __restrict__ bS,
                                                   const int* __restrict__ offs,
                                                   const int* __restrict__ counts,
                                                   const int* __restrict__ csr_src,
                                                   ushort* __restrict__ agg2,
                                                   ushort* __restrict__ aggS) {
    const int b = blockIdx.y, br = blockIdx.z;
    const ushort* P = br ? PS : P2;
    const ushort* Q = br ? QS : Q2;
    const float* bias = br ? bS : b2;
    ushort* agg = br ? aggS : agg2;
    const int dst = blockIdx.x * 4 + (threadIdx.x >> 6);
    const int lane = threadIdx.x & 63;
    const ushort* Pb = P + (size_t)b * NF * 128;
    const ushort* Qb = Q + (size_t)b * NF * 128;
    const int start = offs[b * NF + dst];
    const int cnt = counts[b * NF + dst];
    const int* sl = csr_src + (size_t)b * EF + start;
    const int c0 = lane, c1 = lane + 64;
    const float q0 = b2f(Qb[(size_t)dst * 128 + c0]) + bias[c0];
    const float q1 = b2f(Qb[(size_t)dst * 128 + c1]) + bias[c1];
    float a0 = 0.0f, a1 = 0.0f;
    for (int i = 0; i < cnt; ++i) {
        int src = sl[i];
        float m0 = b2f(Pb[(size_t)src * 128 + c0]) + q0; m0 = m0 > 0.0f ? m0 : 0.01f * m0;
        float m1 = b2f(Pb[(size_t)src * 128 + c1]) + q1; m1 = m1 > 0.0f ? m1 : 0.01f * m1;
        a0 += m0; a1 += m1;
    }
    agg[(size_t)b * NF * 128 + (size_t)dst * 128 + c0] = f2b(a0);
    agg[(size_t)b * NF * 128 + (size_t)dst * 128 + c1] = f2b(a1);
}

// ---------------------------------------------------------------- batch-norm finalize (vectorized) + wf zero
__global__ __launch_bounds__(256) void bn_final(float* __restrict__ xs,
                                                const float* __restrict__ stats,
                                                const float* __restrict__ gamma,
                                                const float* __restrict__ beta,
                                                float* __restrict__ wf) {
    const long i = (long)blockIdx.x * 256 + threadIdx.x;   // float4 index
    const long g4 = i * 4;
    const int c = (int)(g4 & (COUT - 1));
    const float invN = 1.0f / (float)(B * NF);
    float4 v = *(float4*)&xs[g4];
    float vv[4] = {v.x, v.y, v.z, v.w};
    #pragma unroll
    for (int k = 0; k < 4; ++k) {
        int ck = c + k;
        float mu = stats[ck] * invN;
        float var = stats[COUT + ck] * invN - mu * mu;
        float t = (vv[k] - mu) * rsqrtf(var + 1e-5f) * gamma[ck] + beta[ck];
        vv[k] = t > 0.0f ? t : 0.01f * t;
    }
    *(float4*)&xs[g4] = make_float4(vv[0], vv[1], vv[2], vv[3]);
    if (i < (long)B * NF / 4)
        *(float4*)&wf[g4 >> 5 << 2] = make_float4(0.f, 0.f, 0.f, 0.f);
}

__global__ void wfine_scatter(const float* __restrict__ wts, const int* __restrict__ mask,
                              float* __restrict__ wf) {
    int i = blockIdx.x * 256 + threadIdx.x;
    int b = i / NC;
    wf[(size_t)b * NF + mask[i]] = wts[i];
}

extern "C" void kernel_launch(void* const* d_in, const int* in_sizes, int n_in,
                              void* d_out, int out_size, void* d_ws, size_t ws_size,
                              hipStream_t stream) {
    const float* x    = (const float*)d_in[0];
    const float* wts  = (const float*)d_in[1];
    const float* pos  = (const float*)d_in[2];
    const float* W1e  = (const float*)d_in[3];
    const float* b1e  = (const float*)d_in[4];
    const float* W1n  = (const float*)d_in[5];
    const float* b1n  = (const float*)d_in[6];
    const float* W2e  = (const float*)d_in[7];
    const float* b2e  = (const float*)d_in[8];
    const float* W2n  = (const float*)d_in[9];
    const float* b2n  = (const float*)d_in[10];
    const float* Wse  = (const float*)d_in[11];
    const float* bse  = (const float*)d_in[12];
    const float* Wsn  = (const float*)d_in[13];
    const float* bsn  = (const float*)d_in[14];
    const float* gamma= (const float*)d_in[15];
    const float* beta = (const float*)d_in[16];
    const int*   mask = (const int*)d_in[17];
    const int*   ec   = (const int*)d_in[18];
    const int*   ef   = (const int*)d_in[19];

    float* ws = (float*)d_ws;
    // ---- f32 region
    int*    idxb  = (int*)ws;                              // B*NF*3
    float*  wnb   = ws + 98304;                            // B*NF*3
    float4* sposg = (float4*)(ws + 196608);                // B*NC float4 (z-sorted)
    float*  x1    = ws + 196608 + 32768;                   // B*NC*CH
    float*  PbC   = x1  + (size_t)B * NC * CH;
    float*  QbC   = PbC + (size_t)B * NC * CH;
    float*  aggC  = QbC + (size_t)B * NC * CH;
    float*  stats = aggC+ (size_t)B * NC * CH;             // 256 (contiguous with counts below)
    // ---- int region (stats+counts contiguous for single memset)
    int* cntC  = (int*)(stats + 256);                      // B*NC
    int* cntF  = cntC + B * NC;                            // B*NF
    int* cntZ  = cntF + B * NF;                            // B*ZB
    int* offC  = cntZ + B * ZB;                            // B*NC
    int* curC  = offC + B * NC;
    int* offF  = curC + B * NC;                            // B*NF
    int* curF  = offF + B * NF;
    int* offZ  = curF + B * NF;                            // B*(ZB+1)
    int* curZ  = offZ + B * (ZB + 1);
    int* csrC  = curZ + B * (ZB + 1);                      // B*EC
    int* csrF  = csrC + B * EC;                            // B*EF
    // ---- bf16 region (32B aligned)
    size_t foff = (size_t)(csrF + (size_t)B * EF - (int*)ws);
    foff = (foff + 7) & ~(size_t)7;
    ushort* xupb  = (ushort*)(ws + foff);                  // B*NF*128
    ushort* x1upb = xupb  + (size_t)B * NF * 128;          // B*NF*64
    ushort* P2b   = x1upb + (size_t)B * NF * 64;           // B*NF*128
    ushort* Q2b   = P2b   + (size_t)B * NF * 128;          // B*NF*128
    ushort* PSb   = Q2b   + (size_t)B * NF * 128;          // B*NF*128
    ushort* QSb   = PSb   + (size_t)B * NF * 128;          // B*NF*128
    ushort* agg2b = QSb   + (size_t)B * NF * 128;          // B*NF*128
    ushort* aggSb = agg2b + (size_t)B * NF * 128;          // B*NF*128
    ushort* W2eT  = aggSb + (size_t)B * NF * 128;          // 128*128
    ushort* W2nT  = W2eT  + 128 * 128;                     // 128*192
    ushort* WseT  = W2nT  + 128 * 192;                     // 128*256
    ushort* WsnT  = WseT  + 128 * 256;                     // 128*256

    float* y  = (float*)d_out;                             // B*NF*128
    float* wf = y + (size_t)B * NF * COUT;                 // B*NF

    // ---- prep: weights, one memset (stats + all counts), count, scan, fill
    conv_wt<<<dim3(128, 4), 256, 0, stream>>>(W2e, W2n, Wse, Wsn, W2eT, W2nT, WseT, WsnT);
    hipMemsetAsync(stats, 0, 256 * 4 + (size_t)B * (NC + NF + ZB) * 4, stream);
    count_all<<<dim3(EF / 256, B, 3), 256, 0, stream>>>(ec, ef, mask, pos, cntC, cntF, cntZ);
    scan_all<<<dim3(3 * B), 1024, 0, stream>>>(cntC, offC, curC, cntF, offF, curF, cntZ, offZ, curZ);
    fill_all<<<dim3(EF / 256, B, 3), 256, 0, stream>>>(ec, ef, mask, pos, curC, curF, curZ,
                                                       csrC, csrF, sposg);

    // ---- fused knn + x_up interpolation
    knn_interp<<<dim3(NF / 8, B), 256, 0, stream>>>(pos, sposg, offZ, x, idxb, wnb, xupb);

    // ---- main branch: mpl1 on coarse graph (f32 path)
    gemm_pq64<<<dim3(NC / 64, 1, B * 2), 256, 0, stream>>>(x, W1e, PbC, QbC);
    agg_csr_f32<<<dim3(NC / 4, B), 256, 0, stream>>>(
        PbC, QbC, b1e, offC, cntC, csrC, aggC, NC, EC);
    gemm_kernel<<<dim3(1, NC / 64, B), 256, 0, stream>>>(
        x, CIN, aggC, CH, W1n, b1n, x1, NC, CH, 1, (long)NC * CIN, (long)NC * CH, (long)NC * CH);

    // ---- x1_up = interp(x1) -> bf16  (C=64: 16 lanes/node)
    interp_b16<4><<<dim3(NF / 16, B), 256, 0, stream>>>(x1, idxb, wnb, x1upb);

    // ---- both branches' edge PQ GEMMs, then both agg passes
    mfma_pq_both<<<dim3(NF / 128, 1, B * 4), 256, 0, stream>>>(
        x1upb, xupb, W2eT, WseT, P2b, Q2b, PSb, QSb);
    agg_csr_b16<<<dim3(NF / 4, B, 2), 256, 0, stream>>>(
        P2b, Q2b, b2e, PSb, QSb, bse, offF, cntF, csrF, agg2b, aggSb);

    // ---- fused dual-branch node GEMM + BN stats -> y
    mfma_node2<<<dim3(NF / 128, 1, B), 256, 0, stream>>>(
        x1upb, agg2b, W2nT, b2n, xupb, aggSb, WsnT, bsn, y, stats);

    // ---- batch norm finalize + lrelu (+ wf zero), then w_fine scatter
    bn_final<<<dim3((long)B * NF * COUT / 1024), 256, 0, stream>>>(y, stats, gamma, beta, wf);
    wfine_scatter<<<dim3(B * NC / 256), 256, 0, stream>>>(wts, mask, wf);
}

// Round 10
// 197.163 us; speedup vs baseline: 3.7869x; 1.1573x over previous
//
#include <hip/hip_runtime.h>
#include <hip/hip_bf16.h>
#include <cfloat>

#define B 4
#define NC 2048
#define NF 8192
#define CIN 128
#define CH 64
#define COUT 128
#define EC 16384
#define EF 65536
#define ZB 256          // z-sort bins

typedef __attribute__((ext_vector_type(8))) short short8v;
typedef __attribute__((ext_vector_type(4))) float f32x4;

__device__ __forceinline__ ushort f2b(float v) {
    __hip_bfloat16 h = __float2bfloat16(v);
    return *reinterpret_cast<ushort*>(&h);
}
__device__ __forceinline__ float b2f(ushort u) {
    __hip_bfloat16 h = *reinterpret_cast<__hip_bfloat16*>(&u);
    return __bfloat162float(h);
}

// ---------------------------------------------------------------- combined count: coarse hist / fine hist / z-bin hist
__global__ void count_all(const int* __restrict__ ec, const int* __restrict__ ef,
                          const int* __restrict__ mask, const float* __restrict__ pos,
                          int* __restrict__ cntC, int* __restrict__ cntF, int* __restrict__ cntZ) {
    const int b = blockIdx.y, z = blockIdx.z;
    const int i = blockIdx.x * 256 + threadIdx.x;
    if (z == 0) {
        if (i < EC) atomicAdd(&cntC[b * NC + ec[(size_t)b * 2 * EC + EC + i]], 1);
    } else if (z == 1) {
        if (i < EF) atomicAdd(&cntF[b * NF + ef[(size_t)b * 2 * EF + EF + i]], 1);
    } else {
        if (i < NC) {
            int m = mask[b * NC + i];
            float pz = pos[((size_t)b * NF + m) * 3 + 2];
            int zb = min(max((int)(pz * (float)ZB), 0), ZB - 1);
            atomicAdd(&cntZ[b * ZB + zb], 1);
        }
    }
}

// ---------------------------------------------------------------- combined exclusive scan (grid = 3*B blocks)
template<int N, int OSTR, bool EXTRA>
__device__ __forceinline__ void scan_body(const int* __restrict__ cnt, int* __restrict__ offs,
                                          int* __restrict__ cur, int b, int* part) {
    const int tid = threadIdx.x;
    constexpr int PER = (N + 1023) / 1024;
    int local[PER];
    int s = 0;
    #pragma unroll
    for (int i = 0; i < PER; ++i) {
        int id = tid * PER + i;
        local[i] = s;
        if (id < N) s += cnt[b * N + id];
    }
    part[tid] = s;
    __syncthreads();
    for (int off = 1; off < 1024; off <<= 1) {
        int v = (tid >= off) ? part[tid - off] : 0;
        __syncthreads();
        part[tid] += v;
        __syncthreads();
    }
    int pre = tid ? part[tid - 1] : 0;
    #pragma unroll
    for (int i = 0; i < PER; ++i) {
        int id = tid * PER + i;
        if (id < N) {
            int o = pre + local[i];
            offs[b * OSTR + id] = o;
            cur[b * OSTR + id] = o;
        }
    }
    if (EXTRA && tid == 1023) offs[b * OSTR + N] = part[1023];
}

__global__ __launch_bounds__(1024) void scan_all(
    const int* __restrict__ cntC, int* __restrict__ offC, int* __restrict__ curC,
    const int* __restrict__ cntF, int* __restrict__ offF, int* __restrict__ curF,
    const int* __restrict__ cntZ, int* __restrict__ offZ, int* __restrict__ curZ) {
    __shared__ int part[1024];
    const int cfg = blockIdx.x >> 2;   // B == 4
    const int b = blockIdx.x & 3;
    if (cfg == 0)      scan_body<NC, NC, false>(cntC, offC, curC, b, part);
    else if (cfg == 1) scan_body<NF, NF, false>(cntF, offF, curF, b, part);
    else               scan_body<ZB, ZB + 1, true>(cntZ, offZ, curZ, b, part);
}

// ---------------------------------------------------------------- combined fill: CSRs / z-sorted coarse positions
__global__ void fill_all(const int* __restrict__ ec, const int* __restrict__ ef,
                         const int* __restrict__ mask, const float* __restrict__ pos,
                         int* __restrict__ curC, int* __restrict__ curF, int* __restrict__ curZ,
                         int* __restrict__ csrC, int* __restrict__ csrF,
                         float4* __restrict__ sposg) {
    const int b = blockIdx.y, z = blockIdx.z;
    const int i = blockIdx.x * 256 + threadIdx.x;
    if (z == 0) {
        if (i < EC) {
            const int* eb = ec + (size_t)b * 2 * EC;
            int src = eb[i], dst = eb[EC + i];
            int p = atomicAdd(&curC[b * NC + dst], 1);
            csrC[(size_t)b * EC + p] = src;
        }
    } else if (z == 1) {
        if (i < EF) {
            const int* eb = ef + (size_t)b * 2 * EF;
            int src = eb[i], dst = eb[EF + i];
            int p = atomicAdd(&curF[b * NF + dst], 1);
            csrF[(size_t)b * EF + p] = src;
        }
    } else {
        if (i < NC) {
            int m = mask[b * NC + i];
            const float* p = pos + ((size_t)b * NF + m) * 3;
            float px = p[0], py = p[1], pz = p[2];
            int zb = min(max((int)(pz * (float)ZB), 0), ZB - 1);
            int slot = atomicAdd(&curZ[b * (ZB + 1) + zb], 1);
            sposg[(size_t)b * NC + slot] = make_float4(px, py, pz, __int_as_float(i));
        }
    }
}

// ---------------------------------------------------------------- top-3 insert helper
__device__ __forceinline__ void ins3(float d, int c, float& d0, float& d1, float& d2,
                                     int& i0, int& i1, int& i2) {
    bool lt0 = d < d0, lt1 = d < d1, lt2 = d < d2;
    d2 = lt1 ? d1 : (lt2 ? d : d2);  i2 = lt1 ? i1 : (lt2 ? c : i2);
    d1 = lt0 ? d0 : (lt1 ? d : d1);  i1 = lt0 ? i0 : (lt1 ? c : i1);
    d0 = lt0 ? d  : d0;              i0 = lt0 ? c  : i0;
}
__device__ __forceinline__ void merge32(float& d0, float& d1, float& d2,
                                        int& i0, int& i1, int& i2) {
    #pragma unroll
    for (int off = 1; off <= 16; off <<= 1) {
        float od[3]; int oi[3];
        od[0] = __shfl_xor(d0, off); oi[0] = __shfl_xor(i0, off);
        od[1] = __shfl_xor(d1, off); oi[1] = __shfl_xor(i1, off);
        od[2] = __shfl_xor(d2, off); oi[2] = __shfl_xor(i2, off);
        #pragma unroll
        for (int j = 0; j < 3; ++j) ins3(od[j], oi[j], d0, d1, d2, i0, i1, i2);
    }
}

// ---------------------------------------------------------------- fused knn (z-window) + x_up interpolation (C=128)
__global__ __launch_bounds__(256) void knn_interp(const float* __restrict__ pos,
                                                  const float4* __restrict__ sposg,
                                                  const int* __restrict__ offZ,
                                                  const float* __restrict__ xc,
                                                  int* __restrict__ idx,
                                                  float* __restrict__ wn,
                                                  ushort* __restrict__ xup) {
    const int b = blockIdx.y;
    const int tid = threadIdx.x;
    const int node = blockIdx.x * 8 + (tid >> 5);
    const int lane = tid & 31;
    const float* pf = pos + ((size_t)b * NF + node) * 3;
    const float px = pf[0], py = pf[1], pz = pf[2];
    const float4* sp = sposg + (size_t)b * NC;
    const int zb = min(max((int)(pz * (float)ZB), 0), ZB - 1);
    const int zlo = max(zb - 32, 0), zhi = min(zb + 32, ZB - 1);
    const int j0 = offZ[b * (ZB + 1) + zlo];
    const int j1 = offZ[b * (ZB + 1) + zhi + 1];
    float d0 = FLT_MAX, d1 = FLT_MAX, d2 = FLT_MAX;
    int i0 = 0, i1 = 0, i2 = 0;
    for (int j = j0 + lane; j < j1; j += 32) {
        float4 s = sp[j];
        // match numpy: diff, square, sequential sum — no FMA contraction
        float ddx = __fsub_rn(px, s.x);
        float ddy = __fsub_rn(py, s.y);
        float ddz = __fsub_rn(pz, s.z);
        float d = __fadd_rn(__fadd_rn(__fmul_rn(ddx, ddx), __fmul_rn(ddy, ddy)),
                            __fmul_rn(ddz, ddz));
        ins3(d, __float_as_int(s.w), d0, d1, d2, i0, i1, i2);
    }
    merge32(d0, d1, d2, i0, i1, i2);
    // exact bound vs. the unsearched z-slabs
    float bd = 1e30f;
    if (zlo > 0)      bd = fminf(bd, pz - (float)zlo * (1.0f / ZB));
    if (zhi < ZB - 1) bd = fminf(bd, (float)(zhi + 1) * (1.0f / ZB) - pz);
    bd *= 0.9999f;
    if (__any(d2 > bd * bd)) {
        // rare: full exact rescan (wave-coherent)
        d0 = d1 = d2 = FLT_MAX; i0 = i1 = i2 = 0;
        for (int j = lane; j < NC; j += 32) {
            float4 s = sp[j];
            float ddx = __fsub_rn(px, s.x);
            float ddy = __fsub_rn(py, s.y);
            float ddz = __fsub_rn(pz, s.z);
            float d = __fadd_rn(__fadd_rn(__fmul_rn(ddx, ddx), __fmul_rn(ddy, ddy)),
                                __fmul_rn(ddz, ddz));
            ins3(d, __float_as_int(s.w), d0, d1, d2, i0, i1, i2);
        }
        merge32(d0, d1, d2, i0, i1, i2);
    }
    // all 32 lanes now hold the merged top-3
    float w0 = 1.0f / (d0 + 1e-16f);
    float w1 = 1.0f / (d1 + 1e-16f);
    float w2 = 1.0f / (d2 + 1e-16f);
    float inv = 1.0f / (w0 + w1 + w2);
    w0 *= inv; w1 *= inv; w2 *= inv;
    if (lane == 0) {
        size_t o = ((size_t)b * NF + node) * 3;
        idx[o] = i0; idx[o + 1] = i1; idx[o + 2] = i2;
        wn[o] = w0; wn[o + 1] = w1; wn[o + 2] = w2;
    }
    // fused x_up interpolation: lane owns 4 channels
    const float* xb = xc + (size_t)b * NC * CIN;
    float4 a = *(const float4*)&xb[(size_t)i0 * CIN + lane * 4];
    float4 bb = *(const float4*)&xb[(size_t)i1 * CIN + lane * 4];
    float4 cc = *(const float4*)&xb[(size_t)i2 * CIN + lane * 4];
    ushort4 u;
    u.x = f2b(w0 * a.x + w1 * bb.x + w2 * cc.x);
    u.y = f2b(w0 * a.y + w1 * bb.y + w2 * cc.y);
    u.z = f2b(w0 * a.z + w1 * bb.z + w2 * cc.z);
    u.w = f2b(w0 * a.w + w1 * bb.w + w2 * cc.w);
    *(ushort4*)&xup[((size_t)b * NF + node) * CIN + lane * 4] = u;
}

// ---------------------------------------------------------------- weighted 3-NN gather, bf16 out (vectorized)
template<int S>
__global__ __launch_bounds__(256) void interp_b16(const float* __restrict__ xc,
                                                  const int* __restrict__ idx,
                                                  const float* __restrict__ wn,
                                                  ushort* __restrict__ out) {
    constexpr int C = 4 << S;
    const int b = blockIdx.y;
    const int node = blockIdx.x * (256 >> S) + (threadIdx.x >> S);
    const int lane = threadIdx.x & ((1 << S) - 1);
    size_t o = ((size_t)b * NF + node) * 3;
    int i0 = idx[o], i1 = idx[o + 1], i2 = idx[o + 2];
    float w0 = wn[o], w1 = wn[o + 1], w2 = wn[o + 2];
    const float* xb = xc + (size_t)b * NC * C;
    float4 a = *(const float4*)&xb[(size_t)i0 * C + lane * 4];
    float4 bb = *(const float4*)&xb[(size_t)i1 * C + lane * 4];
    float4 cc = *(const float4*)&xb[(size_t)i2 * C + lane * 4];
    ushort4 u;
    u.x = f2b(w0 * a.x + w1 * bb.x + w2 * cc.x);
    u.y = f2b(w0 * a.y + w1 * bb.y + w2 * cc.y);
    u.z = f2b(w0 * a.z + w1 * bb.z + w2 * cc.z);
    u.w = f2b(w0 * a.w + w1 * bb.w + w2 * cc.w);
    *(ushort4*)&out[((size_t)b * NF + node) * C + lane * 4] = u;
}

// ---------------------------------------------------------------- f32 GEMM (coarse node MLP)
__global__ __launch_bounds__(256) void gemm_kernel(
    const float* __restrict__ A1, int K1, const float* __restrict__ A2, int K2,
    const float* __restrict__ W, const float* __restrict__ bias,
    float* __restrict__ Cmat, int M, int N, int flags,
    long sA1, long sA2, long sC) {
    __shared__ float As[16][64];
    __shared__ float Wsh[16][64];
    const int b = blockIdx.z;
    const int m0 = blockIdx.y * 64, n0 = blockIdx.x * 64;
    const int t = threadIdx.x;
    const int tx = t & 15, ty = t >> 4;
    float acc[4][4] = {};
    int kOff = 0;
    for (int s = 0; s < 2; ++s) {
        const float* A = (s == 0) ? A1 : A2;
        const int K = (s == 0) ? K1 : K2;
        const long sA = (s == 0) ? sA1 : sA2;
        if (A == nullptr || K == 0) continue;
        const float* Ab = A + (size_t)b * sA;
        const int lm = t >> 2;
        const int lk = (t & 3) << 2;
        const int wk = t >> 4;
        const int wng = (t & 15) << 2;
        for (int k0 = 0; k0 < K; k0 += 16) {
            float4 av = *(const float4*)&Ab[(size_t)(m0 + lm) * K + k0 + lk];
            As[lk + 0][lm] = av.x; As[lk + 1][lm] = av.y;
            As[lk + 2][lm] = av.z; As[lk + 3][lm] = av.w;
            float4 wv = *(const float4*)&W[(size_t)(kOff + k0 + wk) * N + n0 + wng];
            *(float4*)&Wsh[wk][wng] = wv;
            __syncthreads();
            #pragma unroll
            for (int k = 0; k < 16; ++k) {
                float4 a4 = *(const float4*)&As[k][ty << 2];
                float4 w4 = *(const float4*)&Wsh[k][tx << 2];
                float aa[4] = {a4.x, a4.y, a4.z, a4.w};
                float ww[4] = {w4.x, w4.y, w4.z, w4.w};
                #pragma unroll
                for (int i = 0; i < 4; ++i)
                    #pragma unroll
                    for (int j = 0; j < 4; ++j)
                        acc[i][j] = fmaf(aa[i], ww[j], acc[i][j]);
            }
            __syncthreads();
        }
        kOff += K;
    }
    float* Cb = Cmat + (size_t)b * sC;
    #pragma unroll
    for (int i = 0; i < 4; ++i) {
        int m = m0 + (ty << 2) + i;
        #pragma unroll
        for (int j = 0; j < 4; ++j) {
            int n = n0 + (tx << 2) + j;
            float v = acc[i][j];
            if (bias) v += bias[n];
            if (flags & 1) v = v > 0.0f ? v : 0.01f * v;
            float* cp = &Cb[(size_t)m * N + n];
            if (flags & 2) v += *cp;
            *cp = v;
        }
    }
}

// ---------------------------------------------------------------- coarse P/Q GEMM merged (M=NC, N=64, K=128)
__global__ __launch_bounds__(256) void gemm_pq64(const float* __restrict__ x,
                                                 const float* __restrict__ W1e,
                                                 float* __restrict__ Pb,
                                                 float* __restrict__ Qb) {
    __shared__ float As[16][64];
    __shared__ float Wsh[16][64];
    const int z = blockIdx.z;
    const int b = z >> 1, pq = z & 1;
    const int m0 = blockIdx.x * 64;
    const float* Ab = x + (size_t)b * NC * CIN;
    const float* W = W1e + pq * CIN * CH;
    float* Cb = (pq ? Qb : Pb) + (size_t)b * NC * CH;
    const int t = threadIdx.x;
    const int tx = t & 15, ty = t >> 4;
    const int lm = t >> 2, lk = (t & 3) << 2;
    const int wk = t >> 4, wng = (t & 15) << 2;
    float acc[4][4] = {};
    for (int k0 = 0; k0 < CIN; k0 += 16) {
        float4 av = *(const float4*)&Ab[(size_t)(m0 + lm) * CIN + k0 + lk];
        As[lk + 0][lm] = av.x; As[lk + 1][lm] = av.y;
        As[lk + 2][lm] = av.z; As[lk + 3][lm] = av.w;
        float4 wv = *(const float4*)&W[(size_t)(k0 + wk) * CH + wng];
        *(float4*)&Wsh[wk][wng] = wv;
        __syncthreads();
        #pragma unroll
        for (int k = 0; k < 16; ++k) {
            float4 a4 = *(const float4*)&As[k][ty << 2];
            float4 w4 = *(const float4*)&Wsh[k][tx << 2];
            float aa[4] = {a4.x, a4.y, a4.z, a4.w};
            float ww[4] = {w4.x, w4.y, w4.z, w4.w};
            #pragma unroll
            for (int i = 0; i < 4; ++i)
                #pragma unroll
                for (int j = 0; j < 4; ++j)
                    acc[i][j] = fmaf(aa[i], ww[j], acc[i][j]);
        }
        __syncthreads();
    }
    #pragma unroll
    for (int i = 0; i < 4; ++i) {
        int m = m0 + (ty << 2) + i;
        #pragma unroll
        for (int j = 0; j < 4; ++j)
            Cb[(size_t)m * CH + (tx << 2) + j] = acc[i][j];
    }
}

// ---------------------------------------------------------------- MFMA staged-segment inner loop
#define LDK 40
__device__ __forceinline__ void mfma_seg(const ushort* __restrict__ Ab, int K, int m0,
                                         const ushort* __restrict__ Wt, int ldW, int wcol0,
                                         ushort* As, ushort* Wsm,
                                         int t, int wr, int wc, int fr, int fq,
                                         f32x4 (&acc)[4][4]) {
    const int sr = t >> 2, sk = (t & 3) * 8;
    for (int k0 = 0; k0 < K; k0 += 32) {
        #pragma unroll
        for (int p = 0; p < 2; ++p) {
            int r = sr + p * 64;
            *reinterpret_cast<int4*>(&As[r * LDK + sk]) =
                *reinterpret_cast<const int4*>(&Ab[(size_t)(m0 + r) * K + k0 + sk]);
            *reinterpret_cast<int4*>(&Wsm[r * LDK + sk]) =
                *reinterpret_cast<const int4*>(&Wt[(size_t)r * ldW + wcol0 + k0 + sk]);
        }
        __syncthreads();
        short8v af[4], wf[4];
        #pragma unroll
        for (int m = 0; m < 4; ++m)
            af[m] = *reinterpret_cast<const short8v*>(&As[(wr * 64 + m * 16 + fr) * LDK + fq * 8]);
        #pragma unroll
        for (int n = 0; n < 4; ++n)
            wf[n] = *reinterpret_cast<const short8v*>(&Wsm[(wc * 64 + n * 16 + fr) * LDK + fq * 8]);
        #pragma unroll
        for (int m = 0; m < 4; ++m)
            #pragma unroll
            for (int n = 0; n < 4; ++n)
                acc[m][n] = __builtin_amdgcn_mfma_f32_16x16x32_bf16(af[m], wf[n], acc[m][n], 0, 0, 0);
        __syncthreads();
    }
}

// ---------------------------------------------------------------- both branches' PQ GEMMs in one launch
__global__ __launch_bounds__(256) void mfma_pq_both(
    const ushort* __restrict__ x1upb, const ushort* __restrict__ xupb,
    const ushort* __restrict__ W2eT, const ushort* __restrict__ WseT,
    ushort* __restrict__ P2, ushort* __restrict__ Q2,
    ushort* __restrict__ PS, ushort* __restrict__ QS) {
    __shared__ ushort As[128 * LDK];
    __shared__ ushort Wsm[128 * LDK];
    const int t = threadIdx.x;
    const int lane = t & 63, wid = t >> 6;
    const int wr = wid >> 1, wc = wid & 1;
    const int fr = lane & 15, fq = lane >> 4;
    const int z = blockIdx.z;
    const int b = z >> 2, sel = z & 3;
    const int br = sel >> 1, pq = sel & 1;
    const int m0 = blockIdx.x * 128;
    f32x4 acc[4][4];
    #pragma unroll
    for (int m = 0; m < 4; ++m)
        #pragma unroll
        for (int n = 0; n < 4; ++n) acc[m][n] = (f32x4){0.f, 0.f, 0.f, 0.f};
    ushort* outp;
    if (br == 0) {
        mfma_seg(x1upb + (size_t)b * NF * 64, 64, m0, W2eT, 128, pq * 64,
                 As, Wsm, t, wr, wc, fr, fq, acc);
        outp = pq ? Q2 : P2;
    } else {
        mfma_seg(xupb + (size_t)b * NF * 128, 128, m0, WseT, 256, pq * 128,
                 As, Wsm, t, wr, wc, fr, fq, acc);
        outp = pq ? QS : PS;
    }
    ushort* Cb = outp + (size_t)b * NF * 128;
    #pragma unroll
    for (int m = 0; m < 4; ++m)
        #pragma unroll
        for (int n = 0; n < 4; ++n) {
            int col = wc * 64 + n * 16 + fr;
            #pragma unroll
            for (int r = 0; r < 4; ++r) {
                int row = m0 + wr * 64 + m * 16 + fq * 4 + r;
                Cb[(size_t)row * 128 + col] = f2b(acc[m][n][r]);
            }
        }
}

// ---------------------------------------------------------------- fused dual-branch node GEMM + BN stats
__global__ __launch_bounds__(256) void mfma_node2(
    const ushort* __restrict__ A1, const ushort* __restrict__ A2,
    const ushort* __restrict__ Wt1, const float* __restrict__ bias1,
    const ushort* __restrict__ A3, const ushort* __restrict__ A4,
    const ushort* __restrict__ Wt2, const float* __restrict__ bias2,
    float* __restrict__ y, float* __restrict__ stats) {
    __shared__ ushort As[128 * LDK];
    __shared__ ushort Wsm[128 * LDK];
    const int t = threadIdx.x;
    const int lane = t & 63, wid = t >> 6;
    const int wr = wid >> 1, wc = wid & 1;
    const int fr = lane & 15, fq = lane >> 4;
    const int b = blockIdx.z;
    const int m0 = blockIdx.x * 128;
    f32x4 acc1[4][4], acc2[4][4];
    #pragma unroll
    for (int m = 0; m < 4; ++m)
        #pragma unroll
        for (int n = 0; n < 4; ++n) {
            acc1[m][n] = (f32x4){0.f, 0.f, 0.f, 0.f};
            acc2[m][n] = (f32x4){0.f, 0.f, 0.f, 0.f};
        }
    mfma_seg(A1 + (size_t)b * NF * 64,  64,  m0, Wt1, 192, 0,   As, Wsm, t, wr, wc, fr, fq, acc1);
    mfma_seg(A2 + (size_t)b * NF * 128, 128, m0, Wt1, 192, 64,  As, Wsm, t, wr, wc, fr, fq, acc1);
    mfma_seg(A3 + (size_t)b * NF * 128, 128, m0, Wt2, 256, 0,   As, Wsm, t, wr, wc, fr, fq, acc2);
    mfma_seg(A4 + (size_t)b * NF * 128, 128, m0, Wt2, 256, 128, As, Wsm, t, wr, wc, fr, fq, acc2);
    float* Yb = y + (size_t)b * NF * 128;
    float lsum[4] = {0.f, 0.f, 0.f, 0.f}, lsq[4] = {0.f, 0.f, 0.f, 0.f};
    #pragma unroll
    for (int m = 0; m < 4; ++m)
        #pragma unroll
        for (int n = 0; n < 4; ++n) {
            int col = wc * 64 + n * 16 + fr;
            float bv1 = bias1[col], bv2 = bias2[col];
            #pragma unroll
            for (int r = 0; r < 4; ++r) {
                int row = m0 + wr * 64 + m * 16 + fq * 4 + r;
                float v1 = acc1[m][n][r] + bv1; v1 = v1 > 0.0f ? v1 : 0.01f * v1;
                float v2 = acc2[m][n][r] + bv2; v2 = v2 > 0.0f ? v2 : 0.01f * v2;
                float v = v1 + v2;
                Yb[(size_t)row * 128 + col] = v;
                lsum[n] += v;
                lsq[n] = fmaf(v, v, lsq[n]);
            }
        }
    __syncthreads();
    float* ssum = reinterpret_cast<float*>(As);
    float* ssq  = ssum + 128;
    if (t < 128) { ssum[t] = 0.0f; ssq[t] = 0.0f; }
    __syncthreads();
    #pragma unroll
    for (int n = 0; n < 4; ++n) {
        int col = wc * 64 + n * 16 + fr;
        atomicAdd(&ssum[col], lsum[n]);
        atomicAdd(&ssq[col], lsq[n]);
    }
    __syncthreads();
    if (t < 128) {
        atomicAdd(&stats[t], ssum[t]);
        atomicAdd(&stats[128 + t], ssq[t]);
    }
}

// ---------------------------------------------------------------- fine weight transpose+bf16: Wt[n][k] = bf16(W[k][n])
__global__ void conv_wt(const float* __restrict__ W2e, const float* __restrict__ W2n,
                        const float* __restrict__ Wse, const float* __restrict__ Wsn,
                        ushort* __restrict__ W2eT, ushort* __restrict__ W2nT,
                        ushort* __restrict__ WseT, ushort* __restrict__ WsnT) {
    const float* src; ushort* dst; int K2;
    switch (blockIdx.y) {
        case 0: src = W2e; dst = W2eT; K2 = 128; break;
        case 1: src = W2n; dst = W2nT; K2 = 192; break;
        case 2: src = Wse; dst = WseT; K2 = 256; break;
        default: src = Wsn; dst = WsnT; K2 = 256; break;
    }
    int id = blockIdx.x * 256 + threadIdx.x;
    if (id >= K2 * 128) return;
    int n = id & 127, k = id >> 7;
    dst[(size_t)n * K2 + k] = f2b(src[id]);
}

// ---------------------------------------------------------------- edge message + aggregate (coarse, f32, C=64)
__global__ __launch_bounds__(256) void agg_csr_f32(const float* __restrict__ P,
                                                   const float* __restrict__ Q,
                                                   const float* __restrict__ bias,
                                                   const int* __restrict__ offs,
                                                   const int* __restrict__ counts,
                                                   const int* __restrict__ csr_src,
                                                   float* __restrict__ agg,
                                                   int N, int E) {
    const int b = blockIdx.y;
    const int dst = blockIdx.x * 4 + (threadIdx.x >> 6);
    const int lane = threadIdx.x & 63;
    const float* Pb = P + (size_t)b * N * 64;
    const float* Qb = Q + (size_t)b * N * 64;
    const int start = offs[b * N + dst];
    const int cnt = counts[b * N + dst];
    const int* sl = csr_src + (size_t)b * E + start;
    const float q = Qb[(size_t)dst * 64 + lane] + bias[lane];
    float a = 0.0f;
    for (int i = 0; i < cnt; ++i) {
        int src = sl[i];
        float m = Pb[(size_t)src * 64 + lane] + q; m = m > 0.0f ? m : 0.01f * m;
        a += m;
    }
    agg[(size_t)b * N * 64 + (size_t)dst * 64 + lane] = a;
}

// ---------------------------------------------------------------- fine agg, XCD-paired: pair = blockIdx.x & 7 -> one XCD
// (8 (graph,branch) pairs == 8 XCDs; each pair's P+Q = 4 MB fits one XCD L2)
__global__ __launch_bounds__(256) void agg_csr_b16(const ushort* __restrict__ P2,
                                                   const ushort* __restrict__ Q2,
                                                   const float* __restrict__ b2,
                                                   const ushort* __restrict__ PS,
                                                   const ushort* __restrict__ QS,
                                                   const float* __restrict__ bS,
                                                   const int* __restrict__ offs,
                                                   const int* __restrict__ counts,
                                                   const int* __restrict__ csr_src,
                                                   ushort* __restrict__ agg2,
                                                   ushort* __restrict__ aggS) {
    const int lin = blockIdx.x;
    const int pair = lin & 7;               // consecutive blocks round-robin XCDs
    const int b = pair >> 1, br = pair & 1;
    const int chunk = lin >> 3;
    const ushort* P = br ? PS : P2;
    const ushort* Q = br ? QS : Q2;
    const float* bias = br ? bS : b2;
    ushort* agg = br ? aggS : agg2;
    const int dst = chunk * 4 + (threadIdx.x >> 6);
    const int lane = threadIdx.x & 63;
    const ushort* Pb = P + (size_t)b * NF * 128;
    const ushort* Qb = Q + (size_t)b * NF * 128;
    const int start = offs[b * NF + dst];
    const int cnt = counts[b * NF + dst];
    const int* sl = csr_src + (size_t)b * EF + start;
    const int c0 = lane, c1 = lane + 64;
    const float q0 = b2f(Qb[(size_t)dst * 128 + c0]) + bias[c0];
    const float q1 = b2f(Qb[(size_t)dst * 128 + c1]) + bias[c1];
    float a0 = 0.0f, a1 = 0.0f;
    int i = 0;
    for (; i + 4 <= cnt; i += 4) {
        int s0 = sl[i], s1 = sl[i + 1], s2 = sl[i + 2], s3 = sl[i + 3];
        ushort p00 = Pb[(size_t)s0 * 128 + c0], p01 = Pb[(size_t)s0 * 128 + c1];
        ushort p10 = Pb[(size_t)s1 * 128 + c0], p11 = Pb[(size_t)s1 * 128 + c1];
        ushort p20 = Pb[(size_t)s2 * 128 + c0], p21 = Pb[(size_t)s2 * 128 + c1];
        ushort p30 = Pb[(size_t)s3 * 128 + c0], p31 = Pb[(size_t)s3 * 128 + c1];
        float m;
        m = b2f(p00) + q0; m = m > 0.0f ? m : 0.01f * m; a0 += m;
        m = b2f(p01) + q1; m = m > 0.0f ? m : 0.01f * m; a1 += m;
        m = b2f(p10) + q0; m = m > 0.0f ? m : 0.01f * m; a0 += m;
        m = b2f(p11) + q1; m = m > 0.0f ? m : 0.01f * m; a1 += m;
        m = b2f(p20) + q0; m = m > 0.0f ? m : 0.01f * m; a0 += m;
        m = b2f(p21) + q1; m = m > 0.0f ? m : 0.01f * m; a1 += m;
        m = b2f(p30) + q0; m = m > 0.0f ? m : 0.01f * m; a0 += m;
        m = b2f(p31) + q1; m = m > 0.0f ? m : 0.01f * m; a1 += m;
    }
    for (; i < cnt; ++i) {
        int src = sl[i];
        float m0 = b2f(Pb[(size_t)src * 128 + c0]) + q0; m0 = m0 > 0.0f ? m0 : 0.01f * m0;
        float m1 = b2f(Pb[(size_t)src * 128 + c1]) + q1; m1 = m1 > 0.0f ? m1 : 0.01f * m1;
        a0 += m0; a1 += m1;
    }
    // non-temporal stores: don't evict the cached P rows
    __builtin_nontemporal_store(f2b(a0), &agg[(size_t)b * NF * 128 + (size_t)dst * 128 + c0]);
    __builtin_nontemporal_store(f2b(a1), &agg[(size_t)b * NF * 128 + (size_t)dst * 128 + c1]);
}

// ---------------------------------------------------------------- batch-norm finalize (vectorized) + wf zero
__global__ __launch_bounds__(256) void bn_final(float* __restrict__ xs,
                                                const float* __restrict__ stats,
                                                const float* __restrict__ gamma,
                                                const float* __restrict__ beta,
                                                float* __restrict__ wf) {
    const long i = (long)blockIdx.x * 256 + threadIdx.x;   // float4 index
    const long g4 = i * 4;
    const int c = (int)(g4 & (COUT - 1));
    const float invN = 1.0f / (float)(B * NF);
    float4 v = *(float4*)&xs[g4];
    float vv[4] = {v.x, v.y, v.z, v.w};
    #pragma unroll
    for (int k = 0; k < 4; ++k) {
        int ck = c + k;
        float mu = stats[ck] * invN;
        float var = stats[COUT + ck] * invN - mu * mu;
        float t = (vv[k] - mu) * rsqrtf(var + 1e-5f) * gamma[ck] + beta[ck];
        vv[k] = t > 0.0f ? t : 0.01f * t;
    }
    *(float4*)&xs[g4] = make_float4(vv[0], vv[1], vv[2], vv[3]);
    if (i < (long)B * NF / 4)
        *(float4*)&wf[i * 4] = make_float4(0.f, 0.f, 0.f, 0.f);   // covers all B*NF floats
}

__global__ void wfine_scatter(const float* __restrict__ wts, const int* __restrict__ mask,
                              float* __restrict__ wf) {
    int i = blockIdx.x * 256 + threadIdx.x;
    int b = i / NC;
    wf[(size_t)b * NF + mask[i]] = wts[i];
}

extern "C" void kernel_launch(void* const* d_in, const int* in_sizes, int n_in,
                              void* d_out, int out_size, void* d_ws, size_t ws_size,
                              hipStream_t stream) {
    const float* x    = (const float*)d_in[0];
    const float* wts  = (const float*)d_in[1];
    const float* pos  = (const float*)d_in[2];
    const float* W1e  = (const float*)d_in[3];
    const float* b1e  = (const float*)d_in[4];
    const float* W1n  = (const float*)d_in[5];
    const float* b1n  = (const float*)d_in[6];
    const float* W2e  = (const float*)d_in[7];
    const float* b2e  = (const float*)d_in[8];
    const float* W2n  = (const float*)d_in[9];
    const float* b2n  = (const float*)d_in[10];
    const float* Wse  = (const float*)d_in[11];
    const float* bse  = (const float*)d_in[12];
    const float* Wsn  = (const float*)d_in[13];
    const float* bsn  = (const float*)d_in[14];
    const float* gamma= (const float*)d_in[15];
    const float* beta = (const float*)d_in[16];
    const int*   mask = (const int*)d_in[17];
    const int*   ec   = (const int*)d_in[18];
    const int*   ef   = (const int*)d_in[19];

    float* ws = (float*)d_ws;
    // ---- f32 region
    int*    idxb  = (int*)ws;                              // B*NF*3
    float*  wnb   = ws + 98304;                            // B*NF*3
    float4* sposg = (float4*)(ws + 196608);                // B*NC float4 (z-sorted)
    float*  x1    = ws + 196608 + 32768;                   // B*NC*CH
    float*  PbC   = x1  + (size_t)B * NC * CH;
    float*  QbC   = PbC + (size_t)B * NC * CH;
    float*  aggC  = QbC + (size_t)B * NC * CH;
    float*  stats = aggC+ (size_t)B * NC * CH;             // 256 (contiguous with counts below)
    // ---- int region (stats+counts contiguous for single memset)
    int* cntC  = (int*)(stats + 256);                      // B*NC
    int* cntF  = cntC + B * NC;                            // B*NF
    int* cntZ  = cntF + B * NF;                            // B*ZB
    int* offC  = cntZ + B * ZB;                            // B*NC
    int* curC  = offC + B * NC;
    int* offF  = curC + B * NC;                            // B*NF
    int* curF  = offF + B * NF;
    int* offZ  = curF + B * NF;                            // B*(ZB+1)
    int* curZ  = offZ + B * (ZB + 1);
    int* csrC  = curZ + B * (ZB + 1);                      // B*EC
    int* csrF  = csrC + B * EC;                            // B*EF
    // ---- bf16 region (32B aligned)
    size_t foff = (size_t)(csrF + (size_t)B * EF - (int*)ws);
    foff = (foff + 7) & ~(size_t)7;
    ushort* xupb  = (ushort*)(ws + foff);                  // B*NF*128
    ushort* x1upb = xupb  + (size_t)B * NF * 128;          // B*NF*64
    ushort* P2b   = x1upb + (size_t)B * NF * 64;           // B*NF*128
    ushort* Q2b   = P2b   + (size_t)B * NF * 128;          // B*NF*128
    ushort* PSb   = Q2b   + (size_t)B * NF * 128;          // B*NF*128
    ushort* QSb   = PSb   + (size_t)B * NF * 128;          // B*NF*128
    ushort* agg2b = QSb   + (size_t)B * NF * 128;          // B*NF*128
    ushort* aggSb = agg2b + (size_t)B * NF * 128;          // B*NF*128
    ushort* W2eT  = aggSb + (size_t)B * NF * 128;          // 128*128
    ushort* W2nT  = W2eT  + 128 * 128;                     // 128*192
    ushort* WseT  = W2nT  + 128 * 192;                     // 128*256
    ushort* WsnT  = WseT  + 128 * 256;                     // 128*256

    float* y  = (float*)d_out;                             // B*NF*128
    float* wf = y + (size_t)B * NF * COUT;                 // B*NF

    // ---- prep: weights, one memset (stats + all counts), count, scan, fill
    conv_wt<<<dim3(128, 4), 256, 0, stream>>>(W2e, W2n, Wse, Wsn, W2eT, W2nT, WseT, WsnT);
    hipMemsetAsync(stats, 0, 256 * 4 + (size_t)B * (NC + NF + ZB) * 4, stream);
    count_all<<<dim3(EF / 256, B, 3), 256, 0, stream>>>(ec, ef, mask, pos, cntC, cntF, cntZ);
    scan_all<<<dim3(3 * B), 1024, 0, stream>>>(cntC, offC, curC, cntF, offF, curF, cntZ, offZ, curZ);
    fill_all<<<dim3(EF / 256, B, 3), 256, 0, stream>>>(ec, ef, mask, pos, curC, curF, curZ,
                                                       csrC, csrF, sposg);

    // ---- fused knn + x_up interpolation
    knn_interp<<<dim3(NF / 8, B), 256, 0, stream>>>(pos, sposg, offZ, x, idxb, wnb, xupb);

    // ---- main branch: mpl1 on coarse graph (f32 path)
    gemm_pq64<<<dim3(NC / 64, 1, B * 2), 256, 0, stream>>>(x, W1e, PbC, QbC);
    agg_csr_f32<<<dim3(NC / 4, B), 256, 0, stream>>>(
        PbC, QbC, b1e, offC, cntC, csrC, aggC, NC, EC);
    gemm_kernel<<<dim3(1, NC / 64, B), 256, 0, stream>>>(
        x, CIN, aggC, CH, W1n, b1n, x1, NC, CH, 1, (long)NC * CIN, (long)NC * CH, (long)NC * CH);

    // ---- x1_up = interp(x1) -> bf16  (C=64: 16 lanes/node)
    interp_b16<4><<<dim3(NF / 16, B), 256, 0, stream>>>(x1, idxb, wnb, x1upb);

    // ---- both branches' edge PQ GEMMs, then both agg passes (XCD-paired 1-D grid)
    mfma_pq_both<<<dim3(NF / 128, 1, B * 4), 256, 0, stream>>>(
        x1upb, xupb, W2eT, WseT, P2b, Q2b, PSb, QSb);
    agg_csr_b16<<<dim3((NF / 4) * B * 2), 256, 0, stream>>>(
        P2b, Q2b, b2e, PSb, QSb, bse, offF, cntF, csrF, agg2b, aggSb);

    // ---- fused dual-branch node GEMM + BN stats -> y
    mfma_node2<<<dim3(NF / 128, 1, B), 256, 0, stream>>>(
        x1upb, agg2b, W2nT, b2n, xupb, aggSb, WsnT, bsn, y, stats);

    // ---- batch norm finalize + lrelu (+ wf zero), then w_fine scatter
    bn_final<<<dim3((long)B * NF * COUT / 1024), 256, 0, stream>>>(y, stats, gamma, beta, wf);
    wfine_scatter<<<dim3(B * NC / 256), 256, 0, stream>>>(wts, mask, wf);
}